// Round 9
// baseline (271.469 us; speedup 1.0000x reference)
//
#include <hip/hip_runtime.h>
#include <math.h>

#define BB 4
#define CC 64
#define DI 128
#define NS 16
#define LL 9216
#define NT (LL / 64)

// scan decomposition
#define GCH 576
#define LCH 16
#define NSEQ 8192      // B*DI*NS
#define SD  512        // B*DI
#define NG 24
#define GS 24          // NG*GS == GCH

typedef __attribute__((ext_vector_type(8))) short bf16x8;
typedef __attribute__((ext_vector_type(4))) float fx4;
#define MFMA16 __builtin_amdgcn_mfma_f32_16x16x32_bf16

static __device__ __forceinline__ unsigned short f2b(float f) {
  unsigned u = __float_as_uint(f);
  u += 0x7fffu + ((u >> 16) & 1u);
  return (unsigned short)(u >> 16);
}
static __device__ __forceinline__ float b2f(unsigned short s) {
  return __uint_as_float(((unsigned)s) << 16);
}
static __device__ __forceinline__ float silu_f(float x) {
  return x / (1.f + __expf(-x));
}
static __device__ __forceinline__ float softplus_f(float v) {
  return fmaxf(v, 0.f) + __logf(1.f + __expf(-fabsf(v)));
}

// ---------------- weight bf16 conversion (once) ----------------
__global__ __launch_bounds__(256) void k_cvt(const float* __restrict__ inw1, const float* __restrict__ xpw1,
                                             const float* __restrict__ ow1, const float* __restrict__ pw1,
                                             const float* __restrict__ inw2, const float* __restrict__ xpw2,
                                             const float* __restrict__ ow2, const float* __restrict__ pw2,
                                             unsigned short* __restrict__ wb) {
  int idx = blockIdx.x * 256 + threadIdx.x;   // < 69632
  int layer = idx >= 34816;
  int e = idx - layer * 34816;
  const float* inw = layer ? inw2 : inw1;
  const float* xpw = layer ? xpw2 : xpw1;
  const float* ow = layer ? ow2 : ow1;
  const float* pw = layer ? pw2 : pw1;
  float v;
  if (e < 16384) v = inw[e];
  else if (e < 22528) { int t = e - 16384; int r = t >> 7, c = t & 127; v = (r < 36) ? xpw[r * 128 + c] : 0.f; }
  else if (e < 30720) v = ow[e - 22528];
  else v = pw[e - 30720];
  wb[idx] = f2b(v);
}

// ---------------- instance-norm moments per (b,c) ----------------
__global__ __launch_bounds__(256) void k_stats(const float* __restrict__ p,
                                               float* __restrict__ stats) {
  int bc = blockIdx.x;
  const float* row = p + (size_t)bc * LL;
  float s = 0.f, s2 = 0.f;
  for (int i = threadIdx.x; i < LL; i += 256) {
    float v = row[i];
    s += v; s2 += v * v;
  }
  #pragma unroll
  for (int o = 32; o > 0; o >>= 1) {
    s += __shfl_down(s, o);
    s2 += __shfl_down(s2, o);
  }
  __shared__ float red[8];
  int w = threadIdx.x >> 6;
  if ((threadIdx.x & 63) == 0) { red[w] = s; red[4 + w] = s2; }
  __syncthreads();
  if (threadIdx.x == 0) {
    float S = red[0] + red[1] + red[2] + red[3];
    float S2 = red[4] + red[5] + red[6] + red[7];
    float m = S * (1.f / LL);
    float var = S2 * (1.f / LL) - m * m;
    stats[bc * 2] = m;
    stats[bc * 2 + 1] = rsqrtf(var + 1e-5f);
  }
}

// ---- fused: transpose + IN + relu + LN + in-proj MFMA -> xf, xin_b, sz_b=silu(z) ----
__global__ __launch_bounds__(256) void k_fusein(const float* __restrict__ p,
                                                const float* __restrict__ stats,
                                                const float* __restrict__ g,
                                                const float* __restrict__ be,
                                                const unsigned short* __restrict__ w_b,
                                                float* __restrict__ xf,
                                                unsigned short* __restrict__ xin_b,
                                                unsigned short* __restrict__ sz_b) {
  int b = blockIdx.x / NT;
  int l0 = (blockIdx.x % NT) * 64;
  __shared__ float T[64][65];
  __shared__ unsigned short Tb[64][72];
  int li = threadIdx.x & 63;
  int c0 = threadIdx.x >> 6;
  #pragma unroll
  for (int j = 0; j < 16; ++j) {
    int c = c0 * 16 + j;
    float m = stats[(b * CC + c) * 2];
    float rs = stats[(b * CC + c) * 2 + 1];
    float v = p[((size_t)(b * CC + c)) * LL + l0 + li];
    T[li][c] = fmaxf((v - m) * rs, 0.f);
  }
  __syncthreads();
  int lane = threadIdx.x & 63;
  int w = threadIdx.x >> 6;
  float gv = g[lane], bv = be[lane];
  for (int j = 0; j < 16; ++j) {
    int row = w * 16 + j;
    float v = T[row][lane];
    float s = v, s2 = v * v;
    #pragma unroll
    for (int o = 32; o > 0; o >>= 1) { s += __shfl_xor(s, o); s2 += __shfl_xor(s2, o); }
    float m = s * (1.f / 64.f);
    float var = s2 * (1.f / 64.f) - m * m;
    float rs = rsqrtf(var + 1e-5f);
    size_t off = ((size_t)b * LL + l0 + row) * CC + lane;
    xf[off] = v;
    Tb[row][lane] = f2b((v - m) * rs * gv + bv);
  }
  __syncthreads();
  int wv = threadIdx.x >> 6;
  int lr = lane & 15, kg = lane >> 4;
  int m0 = wv * 16;
  int rowg0 = blockIdx.x * 64 + m0;
  bf16x8 a0 = *(const bf16x8*)&Tb[m0 + lr][kg * 8];
  bf16x8 a1 = *(const bf16x8*)&Tb[m0 + lr][32 + kg * 8];
  #pragma unroll
  for (int nt = 0; nt < 16; ++nt) {
    bf16x8 b0 = *(const bf16x8*)&w_b[(size_t)(nt * 16 + lr) * CC + kg * 8];
    bf16x8 b1 = *(const bf16x8*)&w_b[(size_t)(nt * 16 + lr) * CC + 32 + kg * 8];
    fx4 c = {0.f, 0.f, 0.f, 0.f};
    c = MFMA16(a0, b0, c, 0, 0, 0);
    c = MFMA16(a1, b1, c, 0, 0, 0);
    #pragma unroll
    for (int r = 0; r < 4; ++r) {
      int row = rowg0 + kg * 4 + r, col = nt * 16 + lr;
      if (col < 128) xin_b[(size_t)row * DI + col] = f2b(c[r]);
      else           sz_b[(size_t)row * DI + col - 128] = f2b(silu_f(c[r]));
    }
  }
}

// ---- per-wave full-K x-proj tile for chunk g (conv+silu on the fly from xin_b) ----
static __device__ __forceinline__ void xp_tile_full(const unsigned short* __restrict__ xin_b,
                                                    const float* __restrict__ cw,
                                                    const float* __restrict__ cb,
                                                    const unsigned short* __restrict__ xpw_b,
                                                    int b, int g, int lr, int kg,
                                                    float (*dblS)[40]) {
  int lloc = g * LCH + lr;
  size_t row = (size_t)b * LL + lloc;
  const bf16x8 zv8 = {0, 0, 0, 0, 0, 0, 0, 0};
  fx4 acc[3];
  #pragma unroll
  for (int nt = 0; nt < 3; ++nt) acc[nt] = (fx4){0.f, 0.f, 0.f, 0.f};
  #pragma unroll
  for (int ks = 0; ks < 4; ++ks) {
    int cbase = ks * 32 + kg * 8;
    bf16x8 x3 = *(const bf16x8*)&xin_b[row * DI + cbase];
    bf16x8 x2 = (lloc >= 1) ? *(const bf16x8*)&xin_b[(row - 1) * DI + cbase] : zv8;
    bf16x8 x1 = (lloc >= 2) ? *(const bf16x8*)&xin_b[(row - 2) * DI + cbase] : zv8;
    bf16x8 x0 = (lloc >= 3) ? *(const bf16x8*)&xin_b[(row - 3) * DI + cbase] : zv8;
    bf16x8 a;
    #pragma unroll
    for (int e = 0; e < 8; ++e) {
      int dd = cbase + e;
      float4 w4 = *(const float4*)&cw[dd * 4];
      float v = cb[dd] + b2f((unsigned short)x0[e]) * w4.x + b2f((unsigned short)x1[e]) * w4.y
              + b2f((unsigned short)x2[e]) * w4.z + b2f((unsigned short)x3[e]) * w4.w;
      a[e] = (short)f2b(silu_f(v));
    }
    #pragma unroll
    for (int nt = 0; nt < 3; ++nt) {
      bf16x8 bfr = *(const bf16x8*)&xpw_b[(size_t)(nt * 16 + lr) * DI + cbase];
      acc[nt] = MFMA16(a, bfr, acc[nt], 0, 0, 0);
    }
  }
  #pragma unroll
  for (int nt = 0; nt < 3; ++nt)
    #pragma unroll
    for (int r = 0; r < 4; ++r) {
      int col = nt * 16 + lr;
      if (col < 36) dblS[kg * 4 + r][col] = acc[nt][r];
    }
}

// ---- e1-power a[16] (A_log = log(1..16) broadcast fast path) ----
static __device__ __forceinline__ void a_powers(float dtv, float A0, bool afast,
                                                const float* __restrict__ Alog, int d,
                                                float* a) {
  if (afast) {
    float e1 = __expf(dtv * A0);
    float p2 = e1 * e1, p4 = p2 * p2, p8 = p4 * p4;
    a[0] = e1;      a[1] = p2;      a[2] = p2 * e1;      a[3] = p4;
    a[4] = p4 * e1; a[5] = p4 * p2; a[6] = p4 * p2 * e1; a[7] = p8;
    a[8] = p8 * e1; a[9] = p8 * p2; a[10] = p8 * p2 * e1; a[11] = p8 * p4;
    a[12] = p8 * p4 * e1; a[13] = p8 * p4 * p2; a[14] = p8 * p4 * p2 * e1; a[15] = p8 * p8;
  } else {
    #pragma unroll
    for (int n = 0; n < 16; ++n) a[n] = __expf(dtv * -__expf(Alog[d * NS + n]));
  }
}

// ---- scanAX: 2 chunks/block; per-wave xp tile; per-thread dual interleaved scan ----
__global__ __launch_bounds__(128) void k_scanAX(const unsigned short* __restrict__ xin_b,
                                                const float* __restrict__ cw,
                                                const float* __restrict__ cb,
                                                const unsigned short* __restrict__ xpw_b,
                                                const float* __restrict__ Alog,
                                                const float* __restrict__ dtw,
                                                const float* __restrict__ dtbp,
                                                float* __restrict__ dts,
                                                float* __restrict__ hl) {
  int q = blockIdx.x % (GCH / 2);
  int b = blockIdx.x / (GCH / 2);
  int gA = q * 2, gB = gA + 1;
  __shared__ float dblS[2][16][40];
  int wv = threadIdx.x >> 6, lane = threadIdx.x & 63;
  int lr = lane & 15, kg = lane >> 4;
  xp_tile_full(xin_b, cw, cb, xpw_b, b, gA + wv, lr, kg, dblS[wv]);
  int d = threadIdx.x;
  float A0 = -__expf(Alog[d * NS]);
  bool afast = true;
  #pragma unroll
  for (int n = 1; n < 16; ++n) {
    float An = -__expf(Alog[d * NS + n]);
    afast = afast && (fabsf(An - A0 * (float)(n + 1)) <= 1e-3f * (float)(n + 1) * fabsf(A0));
  }
  float4 w4 = *(const float4*)&dtw[d * 4];
  float dtbv = dtbp[d];
  float4 cw4 = *(const float4*)&cw[d * 4];
  float cbv = cb[d];
  __syncthreads();
  const unsigned short* xipA = xin_b + ((size_t)b * LL + gA * LCH) * DI + d;
  const unsigned short* xipB = xipA + LCH * DI;
  float w0A = 0.f, w1A = 0.f, w2A = 0.f;
  if (gA > 0) { w0A = b2f(xipA[-3 * DI]); w1A = b2f(xipA[-2 * DI]); w2A = b2f(xipA[-DI]); }
  float w0B = b2f(xipB[-3 * DI]), w1B = b2f(xipB[-2 * DI]), w2B = b2f(xipB[-DI]);
  float hA[16], hB[16];
  #pragma unroll
  for (int n = 0; n < 16; ++n) { hA[n] = 0.f; hB[n] = 0.f; }
  float dtsumA = 0.f, dtsumB = 0.f;
  for (int l = 0; l < LCH; ++l) {
    float xvA = b2f(xipA[(size_t)l * DI]);
    float xvB = b2f(xipB[(size_t)l * DI]);
    float caA = cbv + w0A * cw4.x + w1A * cw4.y + w2A * cw4.z + xvA * cw4.w;
    float caB = cbv + w0B * cw4.x + w1B * cw4.y + w2B * cw4.z + xvB * cw4.w;
    float xcA = silu_f(caA), xcB = silu_f(caB);
    w0A = w1A; w1A = w2A; w2A = xvA;
    w0B = w1B; w1B = w2B; w2B = xvB;
    float4 qA = *(float4*)&dblS[0][l][0];
    float4 qB = *(float4*)&dblS[1][l][0];
    float dtvA = softplus_f(dtbv + qA.x * w4.x + qA.y * w4.y + qA.z * w4.z + qA.w * w4.w);
    float dtvB = softplus_f(dtbv + qB.x * w4.x + qB.y * w4.y + qB.z * w4.z + qB.w * w4.w);
    dtsumA += dtvA; dtsumB += dtvB;
    float dxA = dtvA * xcA, dxB = dtvB * xcB;
    float aA[16], aB[16];
    a_powers(dtvA, A0, afast, Alog, d, aA);
    a_powers(dtvB, A0, afast, Alog, d, aB);
    #pragma unroll
    for (int j = 0; j < 4; ++j) {
      float4 bA = *(float4*)&dblS[0][l][4 + j * 4];
      float4 bB = *(float4*)&dblS[1][l][4 + j * 4];
      hA[j*4+0] = aA[j*4+0] * hA[j*4+0] + dxA * bA.x;
      hA[j*4+1] = aA[j*4+1] * hA[j*4+1] + dxA * bA.y;
      hA[j*4+2] = aA[j*4+2] * hA[j*4+2] + dxA * bA.z;
      hA[j*4+3] = aA[j*4+3] * hA[j*4+3] + dxA * bA.w;
      hB[j*4+0] = aB[j*4+0] * hB[j*4+0] + dxB * bB.x;
      hB[j*4+1] = aB[j*4+1] * hB[j*4+1] + dxB * bB.y;
      hB[j*4+2] = aB[j*4+2] * hB[j*4+2] + dxB * bB.z;
      hB[j*4+3] = aB[j*4+3] * hB[j*4+3] + dxB * bB.w;
    }
  }
  dts[(size_t)gA * SD + b * DI + d] = dtsumA;
  dts[(size_t)gB * SD + b * DI + d] = dtsumB;
  size_t oA = (size_t)gA * NSEQ + ((size_t)b * DI + d) * NS;
  size_t oB = oA + NSEQ;
  #pragma unroll
  for (int j = 0; j < 4; ++j) {
    *(float4*)&hl[oA + j * 4] = make_float4(hA[j*4], hA[j*4+1], hA[j*4+2], hA[j*4+3]);
    *(float4*)&hl[oB + j * 4] = make_float4(hB[j*4], hB[j*4+1], hB[j*4+2], hB[j*4+3]);
  }
}

// ---- scan2a: per-group aggregates (a recomputed from dtsum — exact) ----
__global__ __launch_bounds__(256) void k_scan2a(const float* __restrict__ dts,
                                                const float* __restrict__ hl,
                                                const float* __restrict__ Alog,
                                                float* __restrict__ gap,
                                                float* __restrict__ ghl) {
  int t = blockIdx.x * 256 + threadIdx.x;   // < NG*NSEQ
  int grp = t >> 13, seq = t & (NSEQ - 1);
  int sd = seq >> 4;
  float An = -__expf(Alog[seq & (DI * NS - 1)]);
  float A = 1.f, H = 0.f;
  int c0 = grp * GS;
  #pragma unroll 4
  for (int c = 0; c < GS; ++c) {
    float a = __expf(An * dts[(size_t)(c0 + c) * SD + sd]);
    H = a * H + hl[(size_t)(c0 + c) * NSEQ + seq];
    A *= a;
  }
  gap[t] = A;
  ghl[t] = H;
}

// ---- scan2bc: redundant group-prefix + chunk carries ----
__global__ __launch_bounds__(256) void k_scan2bc(const float* __restrict__ dts,
                                                 const float* __restrict__ hl,
                                                 const float* __restrict__ gap,
                                                 const float* __restrict__ ghl,
                                                 const float* __restrict__ Alog,
                                                 float* __restrict__ hi) {
  int t = blockIdx.x * 256 + threadIdx.x;   // < NG*NSEQ
  int grp = t >> 13, seq = t & (NSEQ - 1);
  int sd = seq >> 4;
  float An = -__expf(Alog[seq & (DI * NS - 1)]);
  float h = 0.f;
  for (int gg = 0; gg < grp; ++gg)
    h = gap[gg * NSEQ + seq] * h + ghl[gg * NSEQ + seq];
  int c0 = grp * GS;
  #pragma unroll 4
  for (int c = 0; c < GS; ++c) {
    float a = __expf(An * dts[(size_t)(c0 + c) * SD + sd]);
    hi[(size_t)(c0 + c) * NSEQ + seq] = h;
    h = a * h + hl[(size_t)(c0 + c) * NSEQ + seq];
  }
}

// ---- scanCO: 2 chunks/block; dual interleaved replay; per-wave out/pr-proj ----
__global__ __launch_bounds__(128) void k_scanCO(const unsigned short* __restrict__ xin_b,
                                                const float* __restrict__ cw,
                                                const float* __restrict__ cb,
                                                const unsigned short* __restrict__ xpw_b,
                                                const unsigned short* __restrict__ sz_b,
                                                const float* __restrict__ Alog,
                                                const float* __restrict__ dtw,
                                                const float* __restrict__ dtbp,
                                                const float* __restrict__ Dp,
                                                const float* __restrict__ hi,
                                                const unsigned short* __restrict__ ow_b,
                                                const float* __restrict__ xf,
                                                const float* __restrict__ skipv,
                                                const unsigned short* __restrict__ pw_b,
                                                const float* __restrict__ pb,
                                                const float* __restrict__ ident,
                                                float* __restrict__ dst, int addid) {
  int q = blockIdx.x % (GCH / 2);
  int b = blockIdx.x / (GCH / 2);
  int gA = q * 2, gB = gA + 1;
  __shared__ float dblS[2][16][40];
  __shared__ unsigned short yS[2][16][136];
  __shared__ unsigned short tmpS[32][72];
  int wv = threadIdx.x >> 6, lane = threadIdx.x & 63;
  int lr = lane & 15, kg = lane >> 4;
  xp_tile_full(xin_b, cw, cb, xpw_b, b, gA + wv, lr, kg, dblS[wv]);
  int d = threadIdx.x;
  float A0 = -__expf(Alog[d * NS]);
  bool afast = true;
  #pragma unroll
  for (int n = 1; n < 16; ++n) {
    float An = -__expf(Alog[d * NS + n]);
    afast = afast && (fabsf(An - A0 * (float)(n + 1)) <= 1e-3f * (float)(n + 1) * fabsf(A0));
  }
  float4 w4 = *(const float4*)&dtw[d * 4];
  float dtbv = dtbp[d];
  float Dv = Dp[d];
  float4 cw4 = *(const float4*)&cw[d * 4];
  float cbv = cb[d];
  __syncthreads();
  size_t oA = (size_t)gA * NSEQ + ((size_t)b * DI + d) * NS;
  size_t oB = oA + NSEQ;
  float hA[16], hB[16];
  #pragma unroll
  for (int j = 0; j < 4; ++j) {
    float4 hvA = *(const float4*)&hi[oA + j * 4];
    float4 hvB = *(const float4*)&hi[oB + j * 4];
    hA[j*4+0] = hvA.x; hA[j*4+1] = hvA.y; hA[j*4+2] = hvA.z; hA[j*4+3] = hvA.w;
    hB[j*4+0] = hvB.x; hB[j*4+1] = hvB.y; hB[j*4+2] = hvB.z; hB[j*4+3] = hvB.w;
  }
  size_t baseA = ((size_t)b * LL + gA * LCH) * DI + d;
  size_t baseB = baseA + LCH * DI;
  const unsigned short* xipA = xin_b + baseA;
  const unsigned short* xipB = xin_b + baseB;
  float w0A = 0.f, w1A = 0.f, w2A = 0.f;
  if (gA > 0) { w0A = b2f(xipA[-3 * DI]); w1A = b2f(xipA[-2 * DI]); w2A = b2f(xipA[-DI]); }
  float w0B = b2f(xipB[-3 * DI]), w1B = b2f(xipB[-2 * DI]), w2B = b2f(xipB[-DI]);
  for (int l = 0; l < LCH; ++l) {
    float xvA = b2f(xipA[(size_t)l * DI]);
    float xvB = b2f(xipB[(size_t)l * DI]);
    float sgA = b2f(sz_b[baseA + (size_t)l * DI]);
    float sgB = b2f(sz_b[baseB + (size_t)l * DI]);
    float caA = cbv + w0A * cw4.x + w1A * cw4.y + w2A * cw4.z + xvA * cw4.w;
    float caB = cbv + w0B * cw4.x + w1B * cw4.y + w2B * cw4.z + xvB * cw4.w;
    float xcA = silu_f(caA), xcB = silu_f(caB);
    w0A = w1A; w1A = w2A; w2A = xvA;
    w0B = w1B; w1B = w2B; w2B = xvB;
    float4 qA = *(float4*)&dblS[0][l][0];
    float4 qB = *(float4*)&dblS[1][l][0];
    float dtvA = softplus_f(dtbv + qA.x * w4.x + qA.y * w4.y + qA.z * w4.z + qA.w * w4.w);
    float dtvB = softplus_f(dtbv + qB.x * w4.x + qB.y * w4.y + qB.z * w4.z + qB.w * w4.w);
    float dxA = dtvA * xcA, dxB = dtvB * xcB;
    float aA[16], aB[16];
    a_powers(dtvA, A0, afast, Alog, d, aA);
    a_powers(dtvB, A0, afast, Alog, d, aB);
    float yA0 = 0.f, yA1 = 0.f, yA2 = 0.f, yA3 = 0.f;
    float yB0 = 0.f, yB1 = 0.f, yB2 = 0.f, yB3 = 0.f;
    {
      float4 bA = *(float4*)&dblS[0][l][4];
      float4 cA = *(float4*)&dblS[0][l][20];
      hA[0] = aA[0] * hA[0] + dxA * bA.x;  yA0 += hA[0] * cA.x;
      hA[1] = aA[1] * hA[1] + dxA * bA.y;  yA1 += hA[1] * cA.y;
      hA[2] = aA[2] * hA[2] + dxA * bA.z;  yA2 += hA[2] * cA.z;
      hA[3] = aA[3] * hA[3] + dxA * bA.w;  yA3 += hA[3] * cA.w;
      float4 bB = *(float4*)&dblS[1][l][4];
      float4 cB = *(float4*)&dblS[1][l][20];
      hB[0] = aB[0] * hB[0] + dxB * bB.x;  yB0 += hB[0] * cB.x;
      hB[1] = aB[1] * hB[1] + dxB * bB.y;  yB1 += hB[1] * cB.y;
      hB[2] = aB[2] * hB[2] + dxB * bB.z;  yB2 += hB[2] * cB.z;
      hB[3] = aB[3] * hB[3] + dxB * bB.w;  yB3 += hB[3] * cB.w;
    }
    {
      float4 bA = *(float4*)&dblS[0][l][8];
      float4 cA = *(float4*)&dblS[0][l][24];
      hA[4] = aA[4] * hA[4] + dxA * bA.x;  yA0 += hA[4] * cA.x;
      hA[5] = aA[5] * hA[5] + dxA * bA.y;  yA1 += hA[5] * cA.y;
      hA[6] = aA[6] * hA[6] + dxA * bA.z;  yA2 += hA[6] * cA.z;
      hA[7] = aA[7] * hA[7] + dxA * bA.w;  yA3 += hA[7] * cA.w;
      float4 bB = *(float4*)&dblS[1][l][8];
      float4 cB = *(float4*)&dblS[1][l][24];
      hB[4] = aB[4] * hB[4] + dxB * bB.x;  yB0 += hB[4] * cB.x;
      hB[5] = aB[5] * hB[5] + dxB * bB.y;  yB1 += hB[5] * cB.y;
      hB[6] = aB[6] * hB[6] + dxB * bB.z;  yB2 += hB[6] * cB.z;
      hB[7] = aB[7] * hB[7] + dxB * bB.w;  yB3 += hB[7] * cB.w;
    }
    {
      float4 bA = *(float4*)&dblS[0][l][12];
      float4 cA = *(float4*)&dblS[0][l][28];
      hA[8]  = aA[8]  * hA[8]  + dxA * bA.x;  yA0 += hA[8]  * cA.x;
      hA[9]  = aA[9]  * hA[9]  + dxA * bA.y;  yA1 += hA[9]  * cA.y;
      hA[10] = aA[10] * hA[10] + dxA * bA.z;  yA2 += hA[10] * cA.z;
      hA[11] = aA[11] * hA[11] + dxA * bA.w;  yA3 += hA[11] * cA.w;
      float4 bB = *(float4*)&dblS[1][l][12];
      float4 cB = *(float4*)&dblS[1][l][28];
      hB[8]  = aB[8]  * hB[8]  + dxB * bB.x;  yB0 += hB[8]  * cB.x;
      hB[9]  = aB[9]  * hB[9]  + dxB * bB.y;  yB1 += hB[9]  * cB.y;
      hB[10] = aB[10] * hB[10] + dxB * bB.z;  yB2 += hB[10] * cB.z;
      hB[11] = aB[11] * hB[11] + dxB * bB.w;  yB3 += hB[11] * cB.w;
    }
    {
      float4 bA = *(float4*)&dblS[0][l][16];
      float4 cA = *(float4*)&dblS[0][l][32];
      hA[12] = aA[12] * hA[12] + dxA * bA.x;  yA0 += hA[12] * cA.x;
      hA[13] = aA[13] * hA[13] + dxA * bA.y;  yA1 += hA[13] * cA.y;
      hA[14] = aA[14] * hA[14] + dxA * bA.z;  yA2 += hA[14] * cA.z;
      hA[15] = aA[15] * hA[15] + dxA * bA.w;  yA3 += hA[15] * cA.w;
      float4 bB = *(float4*)&dblS[1][l][16];
      float4 cB = *(float4*)&dblS[1][l][32];
      hB[12] = aB[12] * hB[12] + dxB * bB.x;  yB0 += hB[12] * cB.x;
      hB[13] = aB[13] * hB[13] + dxB * bB.y;  yB1 += hB[13] * cB.y;
      hB[14] = aB[14] * hB[14] + dxB * bB.z;  yB2 += hB[14] * cB.z;
      hB[15] = aB[15] * hB[15] + dxB * bB.w;  yB3 += hB[15] * cB.w;
    }
    float yvA = ((yA0 + yA1) + (yA2 + yA3)) + Dv * xcA;
    float yvB = ((yB0 + yB1) + (yB2 + yB3)) + Dv * xcB;
    yS[0][l][d] = f2b(yvA * sgA);
    yS[1][l][d] = f2b(yvB * sgB);
  }
  __syncthreads();
  // phase O: out-proj, wave wv handles chunk gA+wv, all 64 cols, full K
  {
    fx4 oacc[4];
    #pragma unroll
    for (int nt = 0; nt < 4; ++nt) oacc[nt] = (fx4){0.f, 0.f, 0.f, 0.f};
    #pragma unroll
    for (int ks = 0; ks < 4; ++ks) {
      int cbase = ks * 32 + kg * 8;
      bf16x8 a = *(const bf16x8*)&yS[wv][lr][cbase];
      #pragma unroll
      for (int nt = 0; nt < 4; ++nt) {
        bf16x8 bfr = *(const bf16x8*)&ow_b[(size_t)(nt * 16 + lr) * DI + cbase];
        oacc[nt] = MFMA16(a, bfr, oacc[nt], 0, 0, 0);
      }
    }
    float sk = skipv[0];
    #pragma unroll
    for (int nt = 0; nt < 4; ++nt) {
      #pragma unroll
      for (int r = 0; r < 4; ++r) {
        int rowl = kg * 4 + r, col = nt * 16 + lr;
        size_t grow = (size_t)b * LL + (gA + wv) * LCH + rowl;
        tmpS[wv * 16 + rowl][col] = f2b(oacc[nt][r] + sk * xf[grow * CC + col]);
      }
    }
  }
  __syncthreads();
  // phase P: pr-proj, wave wv handles its chunk's 16 l-positions, all 64 channels
  {
    fx4 pacc[4];
    #pragma unroll
    for (int ct = 0; ct < 4; ++ct) pacc[ct] = (fx4){0.f, 0.f, 0.f, 0.f};
    #pragma unroll
    for (int ks = 0; ks < 2; ++ks) {
      int cbase = ks * 32 + kg * 8;
      bf16x8 bfrag = *(const bf16x8*)&tmpS[wv * 16 + lr][cbase];
      #pragma unroll
      for (int ct = 0; ct < 4; ++ct) {
        bf16x8 a = *(const bf16x8*)&pw_b[(size_t)(ct * 16 + lr) * CC + cbase];
        pacc[ct] = MFMA16(a, bfrag, pacc[ct], 0, 0, 0);
      }
    }
    #pragma unroll
    for (int ct = 0; ct < 4; ++ct) {
      #pragma unroll
      for (int r = 0; r < 4; ++r) {
        int c = ct * 16 + kg * 4 + r;
        int lpos = (gA + wv) * LCH + lr;
        size_t off = ((size_t)(b * CC + c)) * LL + lpos;
        float val = pacc[ct][r] + pb[c];
        if (addid) val += ident[off];
        dst[off] = val;
      }
    }
  }
}

extern "C" void kernel_launch(void* const* d_in, const int* in_sizes, int n_in,
                              void* d_out, int out_size, void* d_ws, size_t ws_size,
                              hipStream_t stream) {
  const float* x = (const float*)d_in[0];
  float* ws = (float*)d_ws;
  float* stats = ws;                                        //      1024 floats
  float* xf    = ws + 1024;                                 //  2359296
  unsigned short* xin_b = (unsigned short*)(ws + 2360320);  //  4718592 shorts
  unsigned short* sz_b  = (unsigned short*)(ws + 4719616);  //  4718592 shorts
  float* dts   = ws + 7078912;                              //   294912
  float* hl    = ws + 7373824;                              //  4718592 (dead after scan2bc -> inter)
  float* hi    = ws + 12092416;                             //  4718592
  float* gap   = ws + 16811008;                             //   196608
  float* ghl   = ws + 17007616;                             //   196608
  unsigned short* wb = (unsigned short*)(ws + 17204224);    //    69632 shorts
  float* inter = hl;   // hl dead after k_scan2bc; scanCO(L0) writes it; L1 consumes it
                       // in stats/fusein BEFORE scanAX(L1) rewrites hl.
  float* outp  = (float*)d_out;

  k_cvt<<<272, 256, 0, stream>>>((const float*)d_in[3], (const float*)d_in[6],
                                 (const float*)d_in[11], (const float*)d_in[13],
                                 (const float*)d_in[17], (const float*)d_in[20],
                                 (const float*)d_in[25], (const float*)d_in[27], wb);

  const float* cur = x;
  for (int layer = 0; layer < 2; ++layer) {
    const int p0 = 1 + 14 * layer;
    const float* ln_g   = (const float*)d_in[p0 + 0];
    const float* ln_b   = (const float*)d_in[p0 + 1];
    const float* conv_w = (const float*)d_in[p0 + 3];
    const float* conv_b = (const float*)d_in[p0 + 4];
    const float* dt_w   = (const float*)d_in[p0 + 6];
    const float* dt_b   = (const float*)d_in[p0 + 7];
    const float* A_log  = (const float*)d_in[p0 + 8];
    const float* Dp     = (const float*)d_in[p0 + 9];
    const float* skip   = (const float*)d_in[p0 + 11];
    const float* pr_b   = (const float*)d_in[p0 + 13];
    const unsigned short* inw_b = wb + (size_t)layer * 34816;
    const unsigned short* xpw_b = inw_b + 16384;
    const unsigned short* ow_b  = inw_b + 22528;
    const unsigned short* pw_b  = inw_b + 30720;
    float* dst = (layer == 0) ? inter : outp;

    k_stats  <<<BB * CC, 256, 0, stream>>>(cur, stats);
    k_fusein <<<BB * NT, 256, 0, stream>>>(cur, stats, ln_g, ln_b, inw_b, xf, xin_b, sz_b);
    k_scanAX <<<BB * (GCH / 2), 128, 0, stream>>>(xin_b, conv_w, conv_b, xpw_b, A_log,
                                                  dt_w, dt_b, dts, hl);
    k_scan2a <<<(NG * NSEQ) / 256, 256, 0, stream>>>(dts, hl, A_log, gap, ghl);
    k_scan2bc<<<(NG * NSEQ) / 256, 256, 0, stream>>>(dts, hl, gap, ghl, A_log, hi);
    k_scanCO <<<BB * (GCH / 2), 128, 0, stream>>>(xin_b, conv_w, conv_b, xpw_b, sz_b,
                                                  A_log, dt_w, dt_b, Dp, hi, ow_b, xf,
                                                  skip, pw_b, pr_b, x, dst, layer);
    cur = inter;
  }
}

// Round 10
// 265.186 us; speedup vs baseline: 1.0237x; 1.0237x over previous
//
#include <hip/hip_runtime.h>
#include <math.h>

#define BB 4
#define CC 64
#define DI 128
#define NS 16
#define LL 9216
#define NT (LL / 64)

// scan decomposition
#define GCH 576
#define LCH 16
#define NSEQ 8192      // B*DI*NS
#define SD  512        // B*DI
#define NG 24
#define GS 24          // NG*GS == GCH

typedef __attribute__((ext_vector_type(8))) short bf16x8;
typedef __attribute__((ext_vector_type(4))) float fx4;
#define MFMA16 __builtin_amdgcn_mfma_f32_16x16x32_bf16

static __device__ __forceinline__ unsigned short f2b(float f) {
  unsigned u = __float_as_uint(f);
  u += 0x7fffu + ((u >> 16) & 1u);
  return (unsigned short)(u >> 16);
}
static __device__ __forceinline__ float b2f(unsigned short s) {
  return __uint_as_float(((unsigned)s) << 16);
}
static __device__ __forceinline__ float silu_f(float x) {
  return x / (1.f + __expf(-x));
}

// powers of e1: a[n] = e1^(n+1)
static __device__ __forceinline__ void powers16(float e1, float* a) {
  float p2 = e1 * e1, p4 = p2 * p2, p8 = p4 * p4;
  a[0] = e1;      a[1] = p2;      a[2] = p2 * e1;      a[3] = p4;
  a[4] = p4 * e1; a[5] = p4 * p2; a[6] = p4 * p2 * e1; a[7] = p8;
  a[8] = p8 * e1; a[9] = p8 * p2; a[10] = p8 * p2 * e1; a[11] = p8 * p4;
  a[12] = p8 * p4 * e1; a[13] = p8 * p4 * p2; a[14] = p8 * p4 * p2 * e1; a[15] = p8 * p8;
}

// dtv = softplus(v); a[16] decay factors. aone: A0==-1 -> e1=sigmoid(-v) free.
static __device__ __forceinline__ float dt_and_a(float v, float A0, bool aone, bool afast,
                                                 const float* __restrict__ Alog, int d,
                                                 float* a) {
  float em = __expf(-fabsf(v));
  float t = 1.f + em;
  float dtv = fmaxf(v, 0.f) + __logf(t);
  if (aone) {
    float e1 = ((v >= 0.f) ? em : 1.f) / t;   // == exp(-dtv)
    powers16(e1, a);
  } else if (afast) {
    powers16(__expf(dtv * A0), a);
  } else {
    #pragma unroll
    for (int n = 0; n < 16; ++n) a[n] = __expf(dtv * -__expf(Alog[d * NS + n]));
  }
  return dtv;
}

// ---------------- weight bf16 conversion (once) ----------------
__global__ __launch_bounds__(256) void k_cvt(const float* __restrict__ inw1, const float* __restrict__ xpw1,
                                             const float* __restrict__ ow1, const float* __restrict__ pw1,
                                             const float* __restrict__ inw2, const float* __restrict__ xpw2,
                                             const float* __restrict__ ow2, const float* __restrict__ pw2,
                                             unsigned short* __restrict__ wb) {
  int idx = blockIdx.x * 256 + threadIdx.x;   // < 69632
  int layer = idx >= 34816;
  int e = idx - layer * 34816;
  const float* inw = layer ? inw2 : inw1;
  const float* xpw = layer ? xpw2 : xpw1;
  const float* ow = layer ? ow2 : ow1;
  const float* pw = layer ? pw2 : pw1;
  float v;
  if (e < 16384) v = inw[e];
  else if (e < 22528) { int t = e - 16384; int r = t >> 7, c = t & 127; v = (r < 36) ? xpw[r * 128 + c] : 0.f; }
  else if (e < 30720) v = ow[e - 22528];
  else v = pw[e - 30720];
  wb[idx] = f2b(v);
}

// ---------------- instance-norm moments per (b,c) ----------------
__global__ __launch_bounds__(256) void k_stats(const float* __restrict__ p,
                                               float* __restrict__ stats) {
  int bc = blockIdx.x;
  const float* row = p + (size_t)bc * LL;
  float s = 0.f, s2 = 0.f;
  for (int i = threadIdx.x; i < LL; i += 256) {
    float v = row[i];
    s += v; s2 += v * v;
  }
  #pragma unroll
  for (int o = 32; o > 0; o >>= 1) {
    s += __shfl_down(s, o);
    s2 += __shfl_down(s2, o);
  }
  __shared__ float red[8];
  int w = threadIdx.x >> 6;
  if ((threadIdx.x & 63) == 0) { red[w] = s; red[4 + w] = s2; }
  __syncthreads();
  if (threadIdx.x == 0) {
    float S = red[0] + red[1] + red[2] + red[3];
    float S2 = red[4] + red[5] + red[6] + red[7];
    float m = S * (1.f / LL);
    float var = S2 * (1.f / LL) - m * m;
    stats[bc * 2] = m;
    stats[bc * 2 + 1] = rsqrtf(var + 1e-5f);
  }
}

// ---- fused: transpose + IN + relu + LN + in-proj MFMA -> xf, xin_b, sz_b=silu(z) ----
__global__ __launch_bounds__(256) void k_fusein(const float* __restrict__ p,
                                                const float* __restrict__ stats,
                                                const float* __restrict__ g,
                                                const float* __restrict__ be,
                                                const unsigned short* __restrict__ w_b,
                                                float* __restrict__ xf,
                                                unsigned short* __restrict__ xin_b,
                                                unsigned short* __restrict__ sz_b) {
  int b = blockIdx.x / NT;
  int l0 = (blockIdx.x % NT) * 64;
  __shared__ float T[64][65];
  __shared__ unsigned short Tb[64][72];
  int li = threadIdx.x & 63;
  int c0 = threadIdx.x >> 6;
  #pragma unroll
  for (int j = 0; j < 16; ++j) {
    int c = c0 * 16 + j;
    float m = stats[(b * CC + c) * 2];
    float rs = stats[(b * CC + c) * 2 + 1];
    float v = p[((size_t)(b * CC + c)) * LL + l0 + li];
    T[li][c] = fmaxf((v - m) * rs, 0.f);
  }
  __syncthreads();
  int lane = threadIdx.x & 63;
  int w = threadIdx.x >> 6;
  float gv = g[lane], bv = be[lane];
  for (int j = 0; j < 16; ++j) {
    int row = w * 16 + j;
    float v = T[row][lane];
    float s = v, s2 = v * v;
    #pragma unroll
    for (int o = 32; o > 0; o >>= 1) { s += __shfl_xor(s, o); s2 += __shfl_xor(s2, o); }
    float m = s * (1.f / 64.f);
    float var = s2 * (1.f / 64.f) - m * m;
    float rs = rsqrtf(var + 1e-5f);
    size_t off = ((size_t)b * LL + l0 + row) * CC + lane;
    xf[off] = v;
    Tb[row][lane] = f2b((v - m) * rs * gv + bv);
  }
  __syncthreads();
  int wv = threadIdx.x >> 6;
  int lr = lane & 15, kg = lane >> 4;
  int m0 = wv * 16;
  int rowg0 = blockIdx.x * 64 + m0;
  bf16x8 a0 = *(const bf16x8*)&Tb[m0 + lr][kg * 8];
  bf16x8 a1 = *(const bf16x8*)&Tb[m0 + lr][32 + kg * 8];
  #pragma unroll
  for (int nt = 0; nt < 16; ++nt) {
    bf16x8 b0 = *(const bf16x8*)&w_b[(size_t)(nt * 16 + lr) * CC + kg * 8];
    bf16x8 b1 = *(const bf16x8*)&w_b[(size_t)(nt * 16 + lr) * CC + 32 + kg * 8];
    fx4 c = {0.f, 0.f, 0.f, 0.f};
    c = MFMA16(a0, b0, c, 0, 0, 0);
    c = MFMA16(a1, b1, c, 0, 0, 0);
    #pragma unroll
    for (int r = 0; r < 4; ++r) {
      int row = rowg0 + kg * 4 + r, col = nt * 16 + lr;
      if (col < 128) xin_b[(size_t)row * DI + col] = f2b(c[r]);
      else           sz_b[(size_t)row * DI + col - 128] = f2b(silu_f(c[r]));
    }
  }
}

// ---- scanAX (256t, 2 chunks/block): split-K x-proj tiles + per-half local scan ----
__global__ __launch_bounds__(256) void k_scanAX(const unsigned short* __restrict__ xin_b,
                                                const float* __restrict__ cw,
                                                const float* __restrict__ cb,
                                                const unsigned short* __restrict__ xpw_b,
                                                const float* __restrict__ Alog,
                                                const float* __restrict__ dtw,
                                                const float* __restrict__ dtbp,
                                                float* __restrict__ dbl,
                                                float* __restrict__ dts,
                                                float* __restrict__ hl) {
  int q = blockIdx.x % (GCH / 2);
  int b = blockIdx.x / (GCH / 2);
  int gA = q * 2;
  __shared__ float dblP[4][16][40];   // [chunk*2 + ksplit]
  int wave = threadIdx.x >> 6;        // 0..3
  int hw = wave >> 1;                 // chunk of this wave
  int lw = wave & 1;                  // k-split within chunk
  int lane = threadIdx.x & 63;
  int lr = lane & 15, kg = lane >> 4;
  {
    int gw = gA + hw;
    int lloc = gw * LCH + lr;
    size_t row = (size_t)b * LL + lloc;
    const bf16x8 zv8 = {0, 0, 0, 0, 0, 0, 0, 0};
    fx4 acc[3];
    #pragma unroll
    for (int nt = 0; nt < 3; ++nt) acc[nt] = (fx4){0.f, 0.f, 0.f, 0.f};
    #pragma unroll
    for (int kk = 0; kk < 2; ++kk) {
      int cbase = (lw * 2 + kk) * 32 + kg * 8;
      bf16x8 x3 = *(const bf16x8*)&xin_b[row * DI + cbase];
      bf16x8 x2 = (lloc >= 1) ? *(const bf16x8*)&xin_b[(row - 1) * DI + cbase] : zv8;
      bf16x8 x1 = (lloc >= 2) ? *(const bf16x8*)&xin_b[(row - 2) * DI + cbase] : zv8;
      bf16x8 x0 = (lloc >= 3) ? *(const bf16x8*)&xin_b[(row - 3) * DI + cbase] : zv8;
      bf16x8 a;
      #pragma unroll
      for (int e = 0; e < 8; ++e) {
        int dd = cbase + e;
        float4 w4 = *(const float4*)&cw[dd * 4];
        float v = cb[dd] + b2f((unsigned short)x0[e]) * w4.x + b2f((unsigned short)x1[e]) * w4.y
                + b2f((unsigned short)x2[e]) * w4.z + b2f((unsigned short)x3[e]) * w4.w;
        a[e] = (short)f2b(silu_f(v));
      }
      #pragma unroll
      for (int nt = 0; nt < 3; ++nt) {
        bf16x8 bfr = *(const bf16x8*)&xpw_b[(size_t)(nt * 16 + lr) * DI + cbase];
        acc[nt] = MFMA16(a, bfr, acc[nt], 0, 0, 0);
      }
    }
    #pragma unroll
    for (int nt = 0; nt < 3; ++nt)
      #pragma unroll
      for (int r = 0; r < 4; ++r) {
        int col = nt * 16 + lr;
        if (col < 36) dblP[hw * 2 + lw][kg * 4 + r][col] = acc[nt][r];
      }
  }
  __syncthreads();
  // sum split-K partials into dblP[2h]; coalesced global write (both chunks contiguous)
  {
    size_t dbaseA = ((size_t)b * LL + gA * LCH) * 36;
    for (int e = threadIdx.x; e < 1152; e += 256) {
      int hh = e / 576; int e2 = e - hh * 576;
      int r = e2 / 36, c = e2 - r * 36;
      float v = dblP[hh * 2][r][c] + dblP[hh * 2 + 1][r][c];
      dblP[hh * 2][r][c] = v;
      dbl[dbaseA + e] = v;
    }
  }
  __syncthreads();
  // per-half local scan
  int d = threadIdx.x & 127;
  int hh = threadIdx.x >> 7;
  int g = gA + hh;
  float A0 = -__expf(Alog[d * NS]);
  bool afast = true;
  #pragma unroll
  for (int n = 1; n < 16; ++n) {
    float An = -__expf(Alog[d * NS + n]);
    afast = afast && (fabsf(An - A0 * (float)(n + 1)) <= 1e-3f * (float)(n + 1) * fabsf(A0));
  }
  bool aone = afast && (A0 == -1.0f);
  float4 w4 = *(const float4*)&dtw[d * 4];
  float dtbv = dtbp[d];
  float4 cw4 = *(const float4*)&cw[d * 4];
  float cbv = cb[d];
  const unsigned short* xip = xin_b + ((size_t)b * LL + g * LCH) * DI + d;
  float w0 = 0.f, w1 = 0.f, w2 = 0.f;
  if (g > 0) { w0 = b2f(xip[-3 * DI]); w1 = b2f(xip[-2 * DI]); w2 = b2f(xip[-DI]); }
  float h[16];
  #pragma unroll
  for (int n = 0; n < 16; ++n) h[n] = 0.f;
  float dtsum = 0.f;
  #pragma unroll 4
  for (int l = 0; l < LCH; ++l) {
    float xv = b2f(xip[(size_t)l * DI]);
    float cacc = cbv + w0 * cw4.x + w1 * cw4.y + w2 * cw4.z + xv * cw4.w;
    float xcv = silu_f(cacc);
    w0 = w1; w1 = w2; w2 = xv;
    float4 qv = *(float4*)&dblP[hh * 2][l][0];
    float v = dtbv + qv.x * w4.x + qv.y * w4.y + qv.z * w4.z + qv.w * w4.w;
    float a[16];
    float dtv = dt_and_a(v, A0, aone, afast, Alog, d, a);
    float dx = dtv * xcv;
    dtsum += dtv;
    float4 b0 = *(float4*)&dblP[hh * 2][l][4];
    float4 b1 = *(float4*)&dblP[hh * 2][l][8];
    float4 b2 = *(float4*)&dblP[hh * 2][l][12];
    float4 b3 = *(float4*)&dblP[hh * 2][l][16];
    h[0]  = a[0]  * h[0]  + dx * b0.x;  h[1]  = a[1]  * h[1]  + dx * b0.y;
    h[2]  = a[2]  * h[2]  + dx * b0.z;  h[3]  = a[3]  * h[3]  + dx * b0.w;
    h[4]  = a[4]  * h[4]  + dx * b1.x;  h[5]  = a[5]  * h[5]  + dx * b1.y;
    h[6]  = a[6]  * h[6]  + dx * b1.z;  h[7]  = a[7]  * h[7]  + dx * b1.w;
    h[8]  = a[8]  * h[8]  + dx * b2.x;  h[9]  = a[9]  * h[9]  + dx * b2.y;
    h[10] = a[10] * h[10] + dx * b2.z;  h[11] = a[11] * h[11] + dx * b2.w;
    h[12] = a[12] * h[12] + dx * b3.x;  h[13] = a[13] * h[13] + dx * b3.y;
    h[14] = a[14] * h[14] + dx * b3.z;  h[15] = a[15] * h[15] + dx * b3.w;
  }
  dts[(size_t)g * SD + b * DI + d] = dtsum;
  size_t o = (size_t)g * NSEQ + ((size_t)b * DI + d) * NS;
  #pragma unroll
  for (int j = 0; j < 4; ++j)
    *(float4*)&hl[o + j * 4] = make_float4(h[j * 4], h[j * 4 + 1], h[j * 4 + 2], h[j * 4 + 3]);
}

// ---- scan2a: per-group aggregates (a recomputed from dtsum — exact) ----
__global__ __launch_bounds__(256) void k_scan2a(const float* __restrict__ dts,
                                                const float* __restrict__ hl,
                                                const float* __restrict__ Alog,
                                                float* __restrict__ gap,
                                                float* __restrict__ ghl) {
  int t = blockIdx.x * 256 + threadIdx.x;   // < NG*NSEQ
  int grp = t >> 13, seq = t & (NSEQ - 1);
  int sd = seq >> 4;
  float An = -__expf(Alog[seq & (DI * NS - 1)]);
  float A = 1.f, H = 0.f;
  int c0 = grp * GS;
  #pragma unroll 4
  for (int c = 0; c < GS; ++c) {
    float a = __expf(An * dts[(size_t)(c0 + c) * SD + sd]);
    H = a * H + hl[(size_t)(c0 + c) * NSEQ + seq];
    A *= a;
  }
  gap[t] = A;
  ghl[t] = H;
}

// ---- scan2bc: redundant group-prefix + chunk carries ----
__global__ __launch_bounds__(256) void k_scan2bc(const float* __restrict__ dts,
                                                 const float* __restrict__ hl,
                                                 const float* __restrict__ gap,
                                                 const float* __restrict__ ghl,
                                                 const float* __restrict__ Alog,
                                                 float* __restrict__ hi) {
  int t = blockIdx.x * 256 + threadIdx.x;   // < NG*NSEQ
  int grp = t >> 13, seq = t & (NSEQ - 1);
  int sd = seq >> 4;
  float An = -__expf(Alog[seq & (DI * NS - 1)]);
  float h = 0.f;
  for (int gg = 0; gg < grp; ++gg)
    h = gap[gg * NSEQ + seq] * h + ghl[gg * NSEQ + seq];
  int c0 = grp * GS;
  #pragma unroll 4
  for (int c = 0; c < GS; ++c) {
    float a = __expf(An * dts[(size_t)(c0 + c) * SD + sd]);
    hi[(size_t)(c0 + c) * NSEQ + seq] = h;
    h = a * h + hl[(size_t)(c0 + c) * NSEQ + seq];
  }
}

// ---- scanCO (256t, 2 chunks/block): dbl-load + replay + out/pr-proj full-K split-N ----
__global__ __launch_bounds__(256) void k_scanCO(const float* __restrict__ dbl,
                                                const unsigned short* __restrict__ xin_b,
                                                const float* __restrict__ cw,
                                                const float* __restrict__ cb,
                                                const unsigned short* __restrict__ sz_b,
                                                const float* __restrict__ Alog,
                                                const float* __restrict__ dtw,
                                                const float* __restrict__ dtbp,
                                                const float* __restrict__ Dp,
                                                const float* __restrict__ hi,
                                                const unsigned short* __restrict__ ow_b,
                                                const float* __restrict__ xf,
                                                const float* __restrict__ skipv,
                                                const unsigned short* __restrict__ pw_b,
                                                const float* __restrict__ pb,
                                                const float* __restrict__ ident,
                                                float* __restrict__ dst, int addid) {
  int q = blockIdx.x % (GCH / 2);
  int b = blockIdx.x / (GCH / 2);
  int gA = q * 2;
  int tid128 = threadIdx.x & 127;
  int hh = threadIdx.x >> 7;
  int g = gA + hh;
  __shared__ float Bms[2][LCH * NS];
  __shared__ float Cms[2][LCH * NS];
  __shared__ float Dts[2][LCH][4];
  __shared__ unsigned short yS[2][16][136];
  __shared__ unsigned short tmpS[2][16][72];
  {
    size_t rb0 = ((size_t)b * LL + g * LCH) * 36;
    if (tid128 < 64) {
      int l = tid128 >> 2, n4 = (tid128 & 3) * 4;
      *(float4*)&Bms[hh][l * 16 + n4] = *(const float4*)&dbl[rb0 + (size_t)l * 36 + 4 + n4];
    } else {
      int l = (tid128 - 64) >> 2, n4 = (tid128 & 3) * 4;
      *(float4*)&Cms[hh][l * 16 + n4] = *(const float4*)&dbl[rb0 + (size_t)l * 36 + 20 + n4];
    }
    if (tid128 < 16)
      *(float4*)&Dts[hh][tid128][0] = *(const float4*)&dbl[rb0 + (size_t)tid128 * 36];
  }
  int d = tid128;
  float A0 = -__expf(Alog[d * NS]);
  bool afast = true;
  #pragma unroll
  for (int n = 1; n < 16; ++n) {
    float An = -__expf(Alog[d * NS + n]);
    afast = afast && (fabsf(An - A0 * (float)(n + 1)) <= 1e-3f * (float)(n + 1) * fabsf(A0));
  }
  bool aone = afast && (A0 == -1.0f);
  float4 w4 = *(const float4*)&dtw[d * 4];
  float dtbv = dtbp[d];
  float Dv = Dp[d];
  float4 cw4 = *(const float4*)&cw[d * 4];
  float cbv = cb[d];
  __syncthreads();
  size_t o = (size_t)g * NSEQ + ((size_t)b * DI + d) * NS;
  float h[16];
  #pragma unroll
  for (int j = 0; j < 4; ++j) {
    float4 hv = *(const float4*)&hi[o + j * 4];
    h[j * 4 + 0] = hv.x; h[j * 4 + 1] = hv.y; h[j * 4 + 2] = hv.z; h[j * 4 + 3] = hv.w;
  }
  size_t base = ((size_t)b * LL + g * LCH) * DI + d;
  const unsigned short* xip = xin_b + base;
  float w0 = 0.f, w1 = 0.f, w2 = 0.f;
  if (g > 0) { w0 = b2f(xip[-3 * DI]); w1 = b2f(xip[-2 * DI]); w2 = b2f(xip[-DI]); }
  #pragma unroll 4
  for (int l = 0; l < LCH; ++l) {
    float xv = b2f(xip[(size_t)l * DI]);
    float sg = b2f(sz_b[base + (size_t)l * DI]);
    float cacc = cbv + w0 * cw4.x + w1 * cw4.y + w2 * cw4.z + xv * cw4.w;
    float xcv = silu_f(cacc);
    w0 = w1; w1 = w2; w2 = xv;
    float4 qv = *(float4*)&Dts[hh][l][0];
    float v = dtbv + qv.x * w4.x + qv.y * w4.y + qv.z * w4.z + qv.w * w4.w;
    float a[16];
    float dtv = dt_and_a(v, A0, aone, afast, Alog, d, a);
    float4 b0 = *(float4*)&Bms[hh][l * 16];
    float4 b1 = *(float4*)&Bms[hh][l * 16 + 4];
    float4 b2 = *(float4*)&Bms[hh][l * 16 + 8];
    float4 b3 = *(float4*)&Bms[hh][l * 16 + 12];
    float4 c0 = *(float4*)&Cms[hh][l * 16];
    float4 c1 = *(float4*)&Cms[hh][l * 16 + 4];
    float4 c2 = *(float4*)&Cms[hh][l * 16 + 8];
    float4 c3 = *(float4*)&Cms[hh][l * 16 + 12];
    float dx = dtv * xcv;
    float yv = Dv * xcv;
    h[0]  = a[0]  * h[0]  + dx * b0.x;  yv += h[0]  * c0.x;
    h[1]  = a[1]  * h[1]  + dx * b0.y;  yv += h[1]  * c0.y;
    h[2]  = a[2]  * h[2]  + dx * b0.z;  yv += h[2]  * c0.z;
    h[3]  = a[3]  * h[3]  + dx * b0.w;  yv += h[3]  * c0.w;
    h[4]  = a[4]  * h[4]  + dx * b1.x;  yv += h[4]  * c1.x;
    h[5]  = a[5]  * h[5]  + dx * b1.y;  yv += h[5]  * c1.y;
    h[6]  = a[6]  * h[6]  + dx * b1.z;  yv += h[6]  * c1.z;
    h[7]  = a[7]  * h[7]  + dx * b1.w;  yv += h[7]  * c1.w;
    h[8]  = a[8]  * h[8]  + dx * b2.x;  yv += h[8]  * c2.x;
    h[9]  = a[9]  * h[9]  + dx * b2.y;  yv += h[9]  * c2.y;
    h[10] = a[10] * h[10] + dx * b2.z;  yv += h[10] * c2.z;
    h[11] = a[11] * h[11] + dx * b2.w;  yv += h[11] * c2.w;
    h[12] = a[12] * h[12] + dx * b3.x;  yv += h[12] * c3.x;
    h[13] = a[13] * h[13] + dx * b3.y;  yv += h[13] * c3.y;
    h[14] = a[14] * h[14] + dx * b3.z;  yv += h[14] * c3.z;
    h[15] = a[15] * h[15] + dx * b3.w;  yv += h[15] * c3.w;
    yS[hh][l][d] = f2b(yv * sg);
  }
  __syncthreads();
  // phase O: out-proj, full-K; half hh's wave lw computes cols lw*32..lw*32+31
  int lane = threadIdx.x & 63;
  int lr = lane & 15, kg = lane >> 4;
  int lw = (threadIdx.x >> 6) & 1;
  {
    fx4 oacc[2];
    oacc[0] = (fx4){0.f, 0.f, 0.f, 0.f};
    oacc[1] = (fx4){0.f, 0.f, 0.f, 0.f};
    #pragma unroll
    for (int ks = 0; ks < 4; ++ks) {
      int cbase = ks * 32 + kg * 8;
      bf16x8 a = *(const bf16x8*)&yS[hh][lr][cbase];
      #pragma unroll
      for (int j = 0; j < 2; ++j) {
        int nt = lw * 2 + j;
        bf16x8 bfr = *(const bf16x8*)&ow_b[(size_t)(nt * 16 + lr) * DI + cbase];
        oacc[j] = MFMA16(a, bfr, oacc[j], 0, 0, 0);
      }
    }
    float sk = skipv[0];
    #pragma unroll
    for (int j = 0; j < 2; ++j) {
      int nt = lw * 2 + j;
      #pragma unroll
      for (int r = 0; r < 4; ++r) {
        int rowl = kg * 4 + r, col = nt * 16 + lr;
        size_t grow = (size_t)b * LL + g * LCH + rowl;
        tmpS[hh][rowl][col] = f2b(oacc[j][r] + sk * xf[grow * CC + col]);
      }
    }
  }
  __syncthreads();
  // phase P: pr-proj, full-K; half hh's wave lw computes channels lw*32..lw*32+31
  {
    fx4 pacc[2];
    pacc[0] = (fx4){0.f, 0.f, 0.f, 0.f};
    pacc[1] = (fx4){0.f, 0.f, 0.f, 0.f};
    #pragma unroll
    for (int ks = 0; ks < 2; ++ks) {
      int cbase = ks * 32 + kg * 8;
      bf16x8 bfrag = *(const bf16x8*)&tmpS[hh][lr][cbase];
      #pragma unroll
      for (int j = 0; j < 2; ++j) {
        int ct = lw * 2 + j;
        bf16x8 a = *(const bf16x8*)&pw_b[(size_t)(ct * 16 + lr) * CC + cbase];
        pacc[j] = MFMA16(a, bfrag, pacc[j], 0, 0, 0);
      }
    }
    #pragma unroll
    for (int j = 0; j < 2; ++j) {
      int ct = lw * 2 + j;
      #pragma unroll
      for (int r = 0; r < 4; ++r) {
        int c = ct * 16 + kg * 4 + r;
        int lpos = g * LCH + lr;
        size_t off = ((size_t)(b * CC + c)) * LL + lpos;
        float val = pacc[j][r] + pb[c];
        if (addid) val += ident[off];
        dst[off] = val;
      }
    }
  }
}

extern "C" void kernel_launch(void* const* d_in, const int* in_sizes, int n_in,
                              void* d_out, int out_size, void* d_ws, size_t ws_size,
                              hipStream_t stream) {
  const float* x = (const float*)d_in[0];
  float* ws = (float*)d_ws;
  float* stats = ws;                                        //      1024 floats
  float* xf    = ws + 1024;                                 //  2359296
  unsigned short* xin_b = (unsigned short*)(ws + 2360320);  //  4718592 shorts
  unsigned short* sz_b  = (unsigned short*)(ws + 4719616);  //  4718592 shorts
  float* dbl   = ws + 7078912;                              //  1327104
  float* dts   = ws + 8406016;                              //   294912
  float* hl    = ws + 8700928;                              //  4718592 (dead after scan2bc -> inter)
  float* hi    = ws + 13419520;                             //  4718592
  float* gap   = ws + 18138112;                             //   196608
  float* ghl   = ws + 18334720;                             //   196608
  unsigned short* wb = (unsigned short*)(ws + 18531328);    //    69632 shorts
  float* inter = hl;   // hl dead after k_scan2bc; scanCO(L0) writes it; L1 consumes it
                       // in stats/fusein BEFORE scanAX(L1) rewrites hl.
  float* outp  = (float*)d_out;

  k_cvt<<<272, 256, 0, stream>>>((const float*)d_in[3], (const float*)d_in[6],
                                 (const float*)d_in[11], (const float*)d_in[13],
                                 (const float*)d_in[17], (const float*)d_in[20],
                                 (const float*)d_in[25], (const float*)d_in[27], wb);

  const float* cur = x;
  for (int layer = 0; layer < 2; ++layer) {
    const int p0 = 1 + 14 * layer;
    const float* ln_g   = (const float*)d_in[p0 + 0];
    const float* ln_b   = (const float*)d_in[p0 + 1];
    const float* conv_w = (const float*)d_in[p0 + 3];
    const float* conv_b = (const float*)d_in[p0 + 4];
    const float* dt_w   = (const float*)d_in[p0 + 6];
    const float* dt_b   = (const float*)d_in[p0 + 7];
    const float* A_log  = (const float*)d_in[p0 + 8];
    const float* Dp     = (const float*)d_in[p0 + 9];
    const float* skip   = (const float*)d_in[p0 + 11];
    const float* pr_b   = (const float*)d_in[p0 + 13];
    const unsigned short* inw_b = wb + (size_t)layer * 34816;
    const unsigned short* xpw_b = inw_b + 16384;
    const unsigned short* ow_b  = inw_b + 22528;
    const unsigned short* pw_b  = inw_b + 30720;
    float* dst = (layer == 0) ? inter : outp;

    k_stats  <<<BB * CC, 256, 0, stream>>>(cur, stats);
    k_fusein <<<BB * NT, 256, 0, stream>>>(cur, stats, ln_g, ln_b, inw_b, xf, xin_b, sz_b);
    k_scanAX <<<BB * (GCH / 2), 256, 0, stream>>>(xin_b, conv_w, conv_b, xpw_b, A_log,
                                                  dt_w, dt_b, dbl, dts, hl);
    k_scan2a <<<(NG * NSEQ) / 256, 256, 0, stream>>>(dts, hl, A_log, gap, ghl);
    k_scan2bc<<<(NG * NSEQ) / 256, 256, 0, stream>>>(dts, hl, gap, ghl, A_log, hi);
    k_scanCO <<<BB * (GCH / 2), 256, 0, stream>>>(dbl, xin_b, conv_w, conv_b, sz_b,
                                                  A_log, dt_w, dt_b, Dp, hi, ow_b, xf,
                                                  skip, pw_b, pr_b, x, dst, layer);
    cur = inter;
  }
}

// Round 11
// 251.926 us; speedup vs baseline: 1.0776x; 1.0526x over previous
//
#include <hip/hip_runtime.h>
#include <math.h>

#define BB 4
#define CC 64
#define DI 128
#define NS 16
#define LL 9216
#define NT (LL / 64)

// scan decomposition
#define GCH 576
#define LCH 16
#define NSEQ 8192      // B*DI*NS
#define SD  512        // B*DI
#define NG 24
#define GS 24          // NG*GS == GCH

typedef __attribute__((ext_vector_type(8))) short bf16x8;
typedef __attribute__((ext_vector_type(4))) float fx4;
#define MFMA16 __builtin_amdgcn_mfma_f32_16x16x32_bf16

static __device__ __forceinline__ unsigned short f2b(float f) {
  unsigned u = __float_as_uint(f);
  u += 0x7fffu + ((u >> 16) & 1u);
  return (unsigned short)(u >> 16);
}
static __device__ __forceinline__ float b2f(unsigned short s) {
  return __uint_as_float(((unsigned)s) << 16);
}
static __device__ __forceinline__ float silu_f(float x) {
  return x / (1.f + __expf(-x));
}

// powers of e1: a[n] = e1^(n+1)
static __device__ __forceinline__ void powers16(float e1, float* a) {
  float p2 = e1 * e1, p4 = p2 * p2, p8 = p4 * p4;
  a[0] = e1;      a[1] = p2;      a[2] = p2 * e1;      a[3] = p4;
  a[4] = p4 * e1; a[5] = p4 * p2; a[6] = p4 * p2 * e1; a[7] = p8;
  a[8] = p8 * e1; a[9] = p8 * p2; a[10] = p8 * p2 * e1; a[11] = p8 * p4;
  a[12] = p8 * p4 * e1; a[13] = p8 * p4 * p2; a[14] = p8 * p4 * p2 * e1; a[15] = p8 * p8;
}

// dtv = softplus(v); a[16] decay factors. aone: A0==-1 -> e1=sigmoid(-v) free.
static __device__ __forceinline__ float dt_and_a(float v, float A0, bool aone, bool afast,
                                                 const float* __restrict__ Alog, int d,
                                                 float* a) {
  float em = __expf(-fabsf(v));
  float t = 1.f + em;
  float dtv = fmaxf(v, 0.f) + __logf(t);
  if (aone) {
    float e1 = ((v >= 0.f) ? em : 1.f) / t;   // == exp(-dtv)
    powers16(e1, a);
  } else if (afast) {
    powers16(__expf(dtv * A0), a);
  } else {
    #pragma unroll
    for (int n = 0; n < 16; ++n) a[n] = __expf(dtv * -__expf(Alog[d * NS + n]));
  }
  return dtv;
}

// ---------------- weight bf16 conversion (once) ----------------
__global__ __launch_bounds__(256) void k_cvt(const float* __restrict__ inw1, const float* __restrict__ xpw1,
                                             const float* __restrict__ ow1, const float* __restrict__ pw1,
                                             const float* __restrict__ inw2, const float* __restrict__ xpw2,
                                             const float* __restrict__ ow2, const float* __restrict__ pw2,
                                             unsigned short* __restrict__ wb) {
  int idx = blockIdx.x * 256 + threadIdx.x;   // < 69632
  int layer = idx >= 34816;
  int e = idx - layer * 34816;
  const float* inw = layer ? inw2 : inw1;
  const float* xpw = layer ? xpw2 : xpw1;
  const float* ow = layer ? ow2 : ow1;
  const float* pw = layer ? pw2 : pw1;
  float v;
  if (e < 16384) v = inw[e];
  else if (e < 22528) { int t = e - 16384; int r = t >> 7, c = t & 127; v = (r < 36) ? xpw[r * 128 + c] : 0.f; }
  else if (e < 30720) v = ow[e - 22528];
  else v = pw[e - 30720];
  wb[idx] = f2b(v);
}

// ---------------- instance-norm moments per (b,c) ----------------
__global__ __launch_bounds__(256) void k_stats(const float* __restrict__ p,
                                               float* __restrict__ stats) {
  int bc = blockIdx.x;
  const float* row = p + (size_t)bc * LL;
  float s = 0.f, s2 = 0.f;
  for (int i = threadIdx.x; i < LL; i += 256) {
    float v = row[i];
    s += v; s2 += v * v;
  }
  #pragma unroll
  for (int o = 32; o > 0; o >>= 1) {
    s += __shfl_down(s, o);
    s2 += __shfl_down(s2, o);
  }
  __shared__ float red[8];
  int w = threadIdx.x >> 6;
  if ((threadIdx.x & 63) == 0) { red[w] = s; red[4 + w] = s2; }
  __syncthreads();
  if (threadIdx.x == 0) {
    float S = red[0] + red[1] + red[2] + red[3];
    float S2 = red[4] + red[5] + red[6] + red[7];
    float m = S * (1.f / LL);
    float var = S2 * (1.f / LL) - m * m;
    stats[bc * 2] = m;
    stats[bc * 2 + 1] = rsqrtf(var + 1e-5f);
  }
}

// ---- fused: transpose + IN + relu + LN + in-proj MFMA -> xf, xin_b, sz_b=silu(z) ----
__global__ __launch_bounds__(256) void k_fusein(const float* __restrict__ p,
                                                const float* __restrict__ stats,
                                                const float* __restrict__ g,
                                                const float* __restrict__ be,
                                                const unsigned short* __restrict__ w_b,
                                                float* __restrict__ xf,
                                                unsigned short* __restrict__ xin_b,
                                                unsigned short* __restrict__ sz_b) {
  int b = blockIdx.x / NT;
  int l0 = (blockIdx.x % NT) * 64;
  __shared__ float T[64][65];
  __shared__ unsigned short Tb[64][72];
  int li = threadIdx.x & 63;
  int c0 = threadIdx.x >> 6;
  #pragma unroll
  for (int j = 0; j < 16; ++j) {
    int c = c0 * 16 + j;
    float m = stats[(b * CC + c) * 2];
    float rs = stats[(b * CC + c) * 2 + 1];
    float v = p[((size_t)(b * CC + c)) * LL + l0 + li];
    T[li][c] = fmaxf((v - m) * rs, 0.f);
  }
  __syncthreads();
  int lane = threadIdx.x & 63;
  int w = threadIdx.x >> 6;
  float gv = g[lane], bv = be[lane];
  for (int j = 0; j < 16; ++j) {
    int row = w * 16 + j;
    float v = T[row][lane];
    float s = v, s2 = v * v;
    #pragma unroll
    for (int o = 32; o > 0; o >>= 1) { s += __shfl_xor(s, o); s2 += __shfl_xor(s2, o); }
    float m = s * (1.f / 64.f);
    float var = s2 * (1.f / 64.f) - m * m;
    float rs = rsqrtf(var + 1e-5f);
    size_t off = ((size_t)b * LL + l0 + row) * CC + lane;
    xf[off] = v;
    Tb[row][lane] = f2b((v - m) * rs * gv + bv);
  }
  __syncthreads();
  int wv = threadIdx.x >> 6;
  int lr = lane & 15, kg = lane >> 4;
  int m0 = wv * 16;
  int rowg0 = blockIdx.x * 64 + m0;
  bf16x8 a0 = *(const bf16x8*)&Tb[m0 + lr][kg * 8];
  bf16x8 a1 = *(const bf16x8*)&Tb[m0 + lr][32 + kg * 8];
  #pragma unroll
  for (int nt = 0; nt < 16; ++nt) {
    bf16x8 b0 = *(const bf16x8*)&w_b[(size_t)(nt * 16 + lr) * CC + kg * 8];
    bf16x8 b1 = *(const bf16x8*)&w_b[(size_t)(nt * 16 + lr) * CC + 32 + kg * 8];
    fx4 c = {0.f, 0.f, 0.f, 0.f};
    c = MFMA16(a0, b0, c, 0, 0, 0);
    c = MFMA16(a1, b1, c, 0, 0, 0);
    #pragma unroll
    for (int r = 0; r < 4; ++r) {
      int row = rowg0 + kg * 4 + r, col = nt * 16 + lr;
      if (col < 128) xin_b[(size_t)row * DI + col] = f2b(c[r]);
      else           sz_b[(size_t)row * DI + col - 128] = f2b(silu_f(c[r]));
    }
  }
}

// ---- scanAX (128t, 1 chunk): split-K x-proj MFMA (conv on the fly) + local scan ----
__global__ __launch_bounds__(128) void k_scanAX(const unsigned short* __restrict__ xin_b,
                                                const float* __restrict__ cw,
                                                const float* __restrict__ cb,
                                                const unsigned short* __restrict__ xpw_b,
                                                const float* __restrict__ Alog,
                                                const float* __restrict__ dtw,
                                                const float* __restrict__ dtbp,
                                                float* __restrict__ dbl,
                                                float* __restrict__ dts,
                                                float* __restrict__ hl) {
  int g = blockIdx.x % GCH;
  int b = blockIdx.x / GCH;
  __shared__ float dblP[2][16][40];
  int wv = threadIdx.x >> 6, lane = threadIdx.x & 63;
  int lr = lane & 15, kg = lane >> 4;
  {
    int lloc = g * LCH + lr;
    size_t row = (size_t)b * LL + lloc;
    const bf16x8 zv8 = {0, 0, 0, 0, 0, 0, 0, 0};
    fx4 acc[3];
    #pragma unroll
    for (int nt = 0; nt < 3; ++nt) acc[nt] = (fx4){0.f, 0.f, 0.f, 0.f};
    #pragma unroll
    for (int kk = 0; kk < 2; ++kk) {
      int cbase = (wv * 2 + kk) * 32 + kg * 8;
      bf16x8 x3 = *(const bf16x8*)&xin_b[row * DI + cbase];
      bf16x8 x2 = (lloc >= 1) ? *(const bf16x8*)&xin_b[(row - 1) * DI + cbase] : zv8;
      bf16x8 x1 = (lloc >= 2) ? *(const bf16x8*)&xin_b[(row - 2) * DI + cbase] : zv8;
      bf16x8 x0 = (lloc >= 3) ? *(const bf16x8*)&xin_b[(row - 3) * DI + cbase] : zv8;
      bf16x8 a;
      #pragma unroll
      for (int e = 0; e < 8; ++e) {
        int dd = cbase + e;
        float4 w4 = *(const float4*)&cw[dd * 4];
        float v = cb[dd] + b2f((unsigned short)x0[e]) * w4.x + b2f((unsigned short)x1[e]) * w4.y
                + b2f((unsigned short)x2[e]) * w4.z + b2f((unsigned short)x3[e]) * w4.w;
        a[e] = (short)f2b(silu_f(v));
      }
      #pragma unroll
      for (int nt = 0; nt < 3; ++nt) {
        bf16x8 bfr = *(const bf16x8*)&xpw_b[(size_t)(nt * 16 + lr) * DI + cbase];
        acc[nt] = MFMA16(a, bfr, acc[nt], 0, 0, 0);
      }
    }
    #pragma unroll
    for (int nt = 0; nt < 3; ++nt)
      #pragma unroll
      for (int r = 0; r < 4; ++r) {
        int col = nt * 16 + lr;
        if (col < 36) dblP[wv][kg * 4 + r][col] = acc[nt][r];
      }
  }
  __syncthreads();
  // sum split-K partials into dblP[0] + coalesced global write
  {
    size_t dbase = ((size_t)b * LL + g * LCH) * 36;
    for (int e = threadIdx.x; e < 576; e += 128) {
      int r = e / 36, c = e - r * 36;
      float v = dblP[0][r][c] + dblP[1][r][c];
      dblP[0][r][c] = v;
      dbl[dbase + e] = v;
    }
  }
  __syncthreads();
  // local scan per d
  int d = threadIdx.x;
  float A0 = -__expf(Alog[d * NS]);
  bool afast = true;
  #pragma unroll
  for (int n = 1; n < 16; ++n) {
    float An = -__expf(Alog[d * NS + n]);
    afast = afast && (fabsf(An - A0 * (float)(n + 1)) <= 1e-3f * (float)(n + 1) * fabsf(A0));
  }
  bool aone = afast && (A0 == -1.0f);
  float4 w4 = *(const float4*)&dtw[d * 4];
  float dtbv = dtbp[d];
  float4 cw4 = *(const float4*)&cw[d * 4];
  float cbv = cb[d];
  const unsigned short* xip = xin_b + ((size_t)b * LL + g * LCH) * DI + d;
  float w0 = 0.f, w1 = 0.f, w2 = 0.f;
  if (g > 0) { w0 = b2f(xip[-3 * DI]); w1 = b2f(xip[-2 * DI]); w2 = b2f(xip[-DI]); }
  float h[16];
  #pragma unroll
  for (int n = 0; n < 16; ++n) h[n] = 0.f;
  float dtsum = 0.f;
  #pragma unroll 4
  for (int l = 0; l < LCH; ++l) {
    float xv = b2f(xip[(size_t)l * DI]);
    float cacc = cbv + w0 * cw4.x + w1 * cw4.y + w2 * cw4.z + xv * cw4.w;
    float xcv = silu_f(cacc);
    w0 = w1; w1 = w2; w2 = xv;
    float4 qv = *(float4*)&dblP[0][l][0];
    float v = dtbv + qv.x * w4.x + qv.y * w4.y + qv.z * w4.z + qv.w * w4.w;
    float a[16];
    float dtv = dt_and_a(v, A0, aone, afast, Alog, d, a);
    float dx = dtv * xcv;
    dtsum += dtv;
    float4 b0 = *(float4*)&dblP[0][l][4];
    float4 b1 = *(float4*)&dblP[0][l][8];
    float4 b2 = *(float4*)&dblP[0][l][12];
    float4 b3 = *(float4*)&dblP[0][l][16];
    h[0]  = a[0]  * h[0]  + dx * b0.x;  h[1]  = a[1]  * h[1]  + dx * b0.y;
    h[2]  = a[2]  * h[2]  + dx * b0.z;  h[3]  = a[3]  * h[3]  + dx * b0.w;
    h[4]  = a[4]  * h[4]  + dx * b1.x;  h[5]  = a[5]  * h[5]  + dx * b1.y;
    h[6]  = a[6]  * h[6]  + dx * b1.z;  h[7]  = a[7]  * h[7]  + dx * b1.w;
    h[8]  = a[8]  * h[8]  + dx * b2.x;  h[9]  = a[9]  * h[9]  + dx * b2.y;
    h[10] = a[10] * h[10] + dx * b2.z;  h[11] = a[11] * h[11] + dx * b2.w;
    h[12] = a[12] * h[12] + dx * b3.x;  h[13] = a[13] * h[13] + dx * b3.y;
    h[14] = a[14] * h[14] + dx * b3.z;  h[15] = a[15] * h[15] + dx * b3.w;
  }
  dts[(size_t)g * SD + b * DI + d] = dtsum;
  size_t o = (size_t)g * NSEQ + ((size_t)b * DI + d) * NS;
  #pragma unroll
  for (int j = 0; j < 4; ++j)
    *(float4*)&hl[o + j * 4] = make_float4(h[j * 4], h[j * 4 + 1], h[j * 4 + 2], h[j * 4 + 3]);
}

// ---- scan2a: per-group aggregates (a recomputed from dtsum — exact) ----
__global__ __launch_bounds__(256) void k_scan2a(const float* __restrict__ dts,
                                                const float* __restrict__ hl,
                                                const float* __restrict__ Alog,
                                                float* __restrict__ gap,
                                                float* __restrict__ ghl) {
  int t = blockIdx.x * 256 + threadIdx.x;   // < NG*NSEQ
  int grp = t >> 13, seq = t & (NSEQ - 1);
  int sd = seq >> 4;
  float An = -__expf(Alog[seq & (DI * NS - 1)]);
  float A = 1.f, H = 0.f;
  int c0 = grp * GS;
  #pragma unroll 4
  for (int c = 0; c < GS; ++c) {
    float a = __expf(An * dts[(size_t)(c0 + c) * SD + sd]);
    H = a * H + hl[(size_t)(c0 + c) * NSEQ + seq];
    A *= a;
  }
  gap[t] = A;
  ghl[t] = H;
}

// ---- scan2bc: redundant group-prefix + chunk carries ----
__global__ __launch_bounds__(256) void k_scan2bc(const float* __restrict__ dts,
                                                 const float* __restrict__ hl,
                                                 const float* __restrict__ gap,
                                                 const float* __restrict__ ghl,
                                                 const float* __restrict__ Alog,
                                                 float* __restrict__ hi) {
  int t = blockIdx.x * 256 + threadIdx.x;   // < NG*NSEQ
  int grp = t >> 13, seq = t & (NSEQ - 1);
  int sd = seq >> 4;
  float An = -__expf(Alog[seq & (DI * NS - 1)]);
  float h = 0.f;
  for (int gg = 0; gg < grp; ++gg)
    h = gap[gg * NSEQ + seq] * h + ghl[gg * NSEQ + seq];
  int c0 = grp * GS;
  #pragma unroll 4
  for (int c = 0; c < GS; ++c) {
    float a = __expf(An * dts[(size_t)(c0 + c) * SD + sd]);
    hi[(size_t)(c0 + c) * NSEQ + seq] = h;
    h = a * h + hl[(size_t)(c0 + c) * NSEQ + seq];
  }
}

// ---- scanCO (128t, 1 chunk): dbl-load + replay + out/pr-proj full-K split-N ----
__global__ __launch_bounds__(128) void k_scanCO(const float* __restrict__ dbl,
                                                const unsigned short* __restrict__ xin_b,
                                                const float* __restrict__ cw,
                                                const float* __restrict__ cb,
                                                const unsigned short* __restrict__ sz_b,
                                                const float* __restrict__ Alog,
                                                const float* __restrict__ dtw,
                                                const float* __restrict__ dtbp,
                                                const float* __restrict__ Dp,
                                                const float* __restrict__ hi,
                                                const unsigned short* __restrict__ ow_b,
                                                const float* __restrict__ xf,
                                                const float* __restrict__ skipv,
                                                const unsigned short* __restrict__ pw_b,
                                                const float* __restrict__ pb,
                                                const float* __restrict__ ident,
                                                float* __restrict__ dst, int addid) {
  int g = blockIdx.x % GCH;
  int b = blockIdx.x / GCH;
  int d = threadIdx.x;
  __shared__ float Bms[LCH * NS];
  __shared__ float Cms[LCH * NS];
  __shared__ float Dts[LCH][4];
  __shared__ unsigned short yS[16][136];
  __shared__ unsigned short tmpS[16][72];
  {
    int tid = threadIdx.x;
    size_t rb0 = ((size_t)b * LL + g * LCH) * 36;
    if (tid < 64) {
      int l = tid >> 2, n4 = (tid & 3) * 4;
      *(float4*)&Bms[l * 16 + n4] = *(const float4*)&dbl[rb0 + (size_t)l * 36 + 4 + n4];
    } else {
      int l = (tid - 64) >> 2, n4 = (tid & 3) * 4;
      *(float4*)&Cms[l * 16 + n4] = *(const float4*)&dbl[rb0 + (size_t)l * 36 + 20 + n4];
    }
    if (tid < 16)
      *(float4*)&Dts[tid][0] = *(const float4*)&dbl[rb0 + (size_t)tid * 36];
  }
  float A0 = -__expf(Alog[d * NS]);
  bool afast = true;
  #pragma unroll
  for (int n = 1; n < 16; ++n) {
    float An = -__expf(Alog[d * NS + n]);
    afast = afast && (fabsf(An - A0 * (float)(n + 1)) <= 1e-3f * (float)(n + 1) * fabsf(A0));
  }
  bool aone = afast && (A0 == -1.0f);
  float4 w4 = *(const float4*)&dtw[d * 4];
  float dtbv = dtbp[d];
  float Dv = Dp[d];
  float4 cw4 = *(const float4*)&cw[d * 4];
  float cbv = cb[d];
  __syncthreads();
  size_t o = (size_t)g * NSEQ + ((size_t)b * DI + d) * NS;
  float h[16];
  #pragma unroll
  for (int j = 0; j < 4; ++j) {
    float4 hv = *(const float4*)&hi[o + j * 4];
    h[j * 4 + 0] = hv.x; h[j * 4 + 1] = hv.y; h[j * 4 + 2] = hv.z; h[j * 4 + 3] = hv.w;
  }
  size_t base = ((size_t)b * LL + g * LCH) * DI + d;
  const unsigned short* xip = xin_b + base;
  float w0 = 0.f, w1 = 0.f, w2 = 0.f;
  if (g > 0) { w0 = b2f(xip[-3 * DI]); w1 = b2f(xip[-2 * DI]); w2 = b2f(xip[-DI]); }
  #pragma unroll 4
  for (int l = 0; l < LCH; ++l) {
    float xv = b2f(xip[(size_t)l * DI]);
    float sg = b2f(sz_b[base + (size_t)l * DI]);
    float cacc = cbv + w0 * cw4.x + w1 * cw4.y + w2 * cw4.z + xv * cw4.w;
    float xcv = silu_f(cacc);
    w0 = w1; w1 = w2; w2 = xv;
    float4 qv = *(float4*)&Dts[l][0];
    float v = dtbv + qv.x * w4.x + qv.y * w4.y + qv.z * w4.z + qv.w * w4.w;
    float a[16];
    float dtv = dt_and_a(v, A0, aone, afast, Alog, d, a);
    float4 b0 = *(float4*)&Bms[l * 16];
    float4 b1 = *(float4*)&Bms[l * 16 + 4];
    float4 b2 = *(float4*)&Bms[l * 16 + 8];
    float4 b3 = *(float4*)&Bms[l * 16 + 12];
    float4 c0 = *(float4*)&Cms[l * 16];
    float4 c1 = *(float4*)&Cms[l * 16 + 4];
    float4 c2 = *(float4*)&Cms[l * 16 + 8];
    float4 c3 = *(float4*)&Cms[l * 16 + 12];
    float dx = dtv * xcv;
    float yv = Dv * xcv;
    h[0]  = a[0]  * h[0]  + dx * b0.x;  yv += h[0]  * c0.x;
    h[1]  = a[1]  * h[1]  + dx * b0.y;  yv += h[1]  * c0.y;
    h[2]  = a[2]  * h[2]  + dx * b0.z;  yv += h[2]  * c0.z;
    h[3]  = a[3]  * h[3]  + dx * b0.w;  yv += h[3]  * c0.w;
    h[4]  = a[4]  * h[4]  + dx * b1.x;  yv += h[4]  * c1.x;
    h[5]  = a[5]  * h[5]  + dx * b1.y;  yv += h[5]  * c1.y;
    h[6]  = a[6]  * h[6]  + dx * b1.z;  yv += h[6]  * c1.z;
    h[7]  = a[7]  * h[7]  + dx * b1.w;  yv += h[7]  * c1.w;
    h[8]  = a[8]  * h[8]  + dx * b2.x;  yv += h[8]  * c2.x;
    h[9]  = a[9]  * h[9]  + dx * b2.y;  yv += h[9]  * c2.y;
    h[10] = a[10] * h[10] + dx * b2.z;  yv += h[10] * c2.z;
    h[11] = a[11] * h[11] + dx * b2.w;  yv += h[11] * c2.w;
    h[12] = a[12] * h[12] + dx * b3.x;  yv += h[12] * c3.x;
    h[13] = a[13] * h[13] + dx * b3.y;  yv += h[13] * c3.y;
    h[14] = a[14] * h[14] + dx * b3.z;  yv += h[14] * c3.z;
    h[15] = a[15] * h[15] + dx * b3.w;  yv += h[15] * c3.w;
    yS[l][d] = f2b(yv * sg);
  }
  __syncthreads();
  // phase O: out-proj, full-K; wave lw computes output cols lw*32 .. lw*32+31
  int lane = threadIdx.x & 63;
  int lr = lane & 15, kg = lane >> 4;
  int lw = threadIdx.x >> 6;
  {
    fx4 oacc[2];
    oacc[0] = (fx4){0.f, 0.f, 0.f, 0.f};
    oacc[1] = (fx4){0.f, 0.f, 0.f, 0.f};
    #pragma unroll
    for (int ks = 0; ks < 4; ++ks) {
      int cbase = ks * 32 + kg * 8;
      bf16x8 a = *(const bf16x8*)&yS[lr][cbase];
      #pragma unroll
      for (int j = 0; j < 2; ++j) {
        int nt = lw * 2 + j;
        bf16x8 bfr = *(const bf16x8*)&ow_b[(size_t)(nt * 16 + lr) * DI + cbase];
        oacc[j] = MFMA16(a, bfr, oacc[j], 0, 0, 0);
      }
    }
    float sk = skipv[0];
    #pragma unroll
    for (int j = 0; j < 2; ++j) {
      int nt = lw * 2 + j;
      #pragma unroll
      for (int r = 0; r < 4; ++r) {
        int rowl = kg * 4 + r, col = nt * 16 + lr;
        size_t grow = (size_t)b * LL + g * LCH + rowl;
        tmpS[rowl][col] = f2b(oacc[j][r] + sk * xf[grow * CC + col]);
      }
    }
  }
  __syncthreads();
  // phase P: pr-proj, full-K; wave lw computes output channels lw*32 .. lw*32+31
  {
    fx4 pacc[2];
    pacc[0] = (fx4){0.f, 0.f, 0.f, 0.f};
    pacc[1] = (fx4){0.f, 0.f, 0.f, 0.f};
    #pragma unroll
    for (int ks = 0; ks < 2; ++ks) {
      int cbase = ks * 32 + kg * 8;
      bf16x8 bfrag = *(const bf16x8*)&tmpS[lr][cbase];
      #pragma unroll
      for (int j = 0; j < 2; ++j) {
        int ct = lw * 2 + j;
        bf16x8 a = *(const bf16x8*)&pw_b[(size_t)(ct * 16 + lr) * CC + cbase];
        pacc[j] = MFMA16(a, bfrag, pacc[j], 0, 0, 0);
      }
    }
    #pragma unroll
    for (int j = 0; j < 2; ++j) {
      int ct = lw * 2 + j;
      #pragma unroll
      for (int r = 0; r < 4; ++r) {
        int c = ct * 16 + kg * 4 + r;
        int lpos = g * LCH + lr;
        size_t off = ((size_t)(b * CC + c)) * LL + lpos;
        float val = pacc[j][r] + pb[c];
        if (addid) val += ident[off];
        dst[off] = val;
      }
    }
  }
}

extern "C" void kernel_launch(void* const* d_in, const int* in_sizes, int n_in,
                              void* d_out, int out_size, void* d_ws, size_t ws_size,
                              hipStream_t stream) {
  const float* x = (const float*)d_in[0];
  float* ws = (float*)d_ws;
  float* stats = ws;                                        //      1024 floats
  float* xf    = ws + 1024;                                 //  2359296
  unsigned short* xin_b = (unsigned short*)(ws + 2360320);  //  4718592 shorts
  unsigned short* sz_b  = (unsigned short*)(ws + 4719616);  //  4718592 shorts
  float* dbl   = ws + 7078912;                              //  1327104
  float* dts   = ws + 8406016;                              //   294912
  float* hl    = ws + 8700928;                              //  4718592 (dead after scan2bc -> inter)
  float* hi    = ws + 13419520;                             //  4718592
  float* gap   = ws + 18138112;                             //   196608
  float* ghl   = ws + 18334720;                             //   196608
  unsigned short* wb = (unsigned short*)(ws + 18531328);    //    69632 shorts
  float* inter = hl;   // hl dead after k_scan2bc; scanCO(L0) writes it; L1 consumes it
                       // in stats/fusein BEFORE scanAX(L1) rewrites hl.
  float* outp  = (float*)d_out;

  k_cvt<<<272, 256, 0, stream>>>((const float*)d_in[3], (const float*)d_in[6],
                                 (const float*)d_in[11], (const float*)d_in[13],
                                 (const float*)d_in[17], (const float*)d_in[20],
                                 (const float*)d_in[25], (const float*)d_in[27], wb);

  const float* cur = x;
  for (int layer = 0; layer < 2; ++layer) {
    const int p0 = 1 + 14 * layer;
    const float* ln_g   = (const float*)d_in[p0 + 0];
    const float* ln_b   = (const float*)d_in[p0 + 1];
    const float* conv_w = (const float*)d_in[p0 + 3];
    const float* conv_b = (const float*)d_in[p0 + 4];
    const float* dt_w   = (const float*)d_in[p0 + 6];
    const float* dt_b   = (const float*)d_in[p0 + 7];
    const float* A_log  = (const float*)d_in[p0 + 8];
    const float* Dp     = (const float*)d_in[p0 + 9];
    const float* skip   = (const float*)d_in[p0 + 11];
    const float* pr_b   = (const float*)d_in[p0 + 13];
    const unsigned short* inw_b = wb + (size_t)layer * 34816;
    const unsigned short* xpw_b = inw_b + 16384;
    const unsigned short* ow_b  = inw_b + 22528;
    const unsigned short* pw_b  = inw_b + 30720;
    float* dst = (layer == 0) ? inter : outp;

    k_stats  <<<BB * CC, 256, 0, stream>>>(cur, stats);
    k_fusein <<<BB * NT, 256, 0, stream>>>(cur, stats, ln_g, ln_b, inw_b, xf, xin_b, sz_b);
    k_scanAX <<<BB * GCH, 128, 0, stream>>>(xin_b, conv_w, conv_b, xpw_b, A_log,
                                            dt_w, dt_b, dbl, dts, hl);
    k_scan2a <<<(NG * NSEQ) / 256, 256, 0, stream>>>(dts, hl, A_log, gap, ghl);
    k_scan2bc<<<(NG * NSEQ) / 256, 256, 0, stream>>>(dts, hl, gap, ghl, A_log, hi);
    k_scanCO <<<BB * GCH, 128, 0, stream>>>(dbl, xin_b, conv_w, conv_b, sz_b,
                                            A_log, dt_w, dt_b, Dp, hi, ow_b, xf,
                                            skip, pw_b, pr_b, x, dst, layer);
    cur = inter;
  }
}

// Round 12
// 237.147 us; speedup vs baseline: 1.1447x; 1.0623x over previous
//
#include <hip/hip_runtime.h>
#include <math.h>

#define BB 4
#define CC 64
#define DI 128
#define NS 16
#define LL 9216
#define NT (LL / 64)

// scan decomposition
#define GCH 576
#define LCH 16
#define NSEQ 8192      // B*DI*NS
#define SD  512        // B*DI
#define NG 24
#define GS 24          // NG*GS == GCH

typedef __attribute__((ext_vector_type(8))) short bf16x8;
typedef __attribute__((ext_vector_type(4))) float fx4;
#define MFMA16 __builtin_amdgcn_mfma_f32_16x16x32_bf16

static __device__ __forceinline__ unsigned short f2b(float f) {
  unsigned u = __float_as_uint(f);
  u += 0x7fffu + ((u >> 16) & 1u);
  return (unsigned short)(u >> 16);
}
static __device__ __forceinline__ float b2f(unsigned short s) {
  return __uint_as_float(((unsigned)s) << 16);
}
static __device__ __forceinline__ float silu_f(float x) {
  return x / (1.f + __expf(-x));
}

// powers of e1: a[n] = e1^(n+1)
static __device__ __forceinline__ void powers16(float e1, float* a) {
  float p2 = e1 * e1, p4 = p2 * p2, p8 = p4 * p4;
  a[0] = e1;      a[1] = p2;      a[2] = p2 * e1;      a[3] = p4;
  a[4] = p4 * e1; a[5] = p4 * p2; a[6] = p4 * p2 * e1; a[7] = p8;
  a[8] = p8 * e1; a[9] = p8 * p2; a[10] = p8 * p2 * e1; a[11] = p8 * p4;
  a[12] = p8 * p4 * e1; a[13] = p8 * p4 * p2; a[14] = p8 * p4 * p2 * e1; a[15] = p8 * p8;
}

// dtv = softplus(v); a[16] decay factors. aone: A0==-1 -> e1=sigmoid(-v) free.
static __device__ __forceinline__ float dt_and_a(float v, float A0, bool aone, bool afast,
                                                 const float* __restrict__ Alog, int d,
                                                 float* a) {
  float em = __expf(-fabsf(v));
  float t = 1.f + em;
  float dtv = fmaxf(v, 0.f) + __logf(t);
  if (aone) {
    float e1 = ((v >= 0.f) ? em : 1.f) / t;   // == exp(-dtv)
    powers16(e1, a);
  } else if (afast) {
    powers16(__expf(dtv * A0), a);
  } else {
    #pragma unroll
    for (int n = 0; n < 16; ++n) a[n] = __expf(dtv * -__expf(Alog[d * NS + n]));
  }
  return dtv;
}

// ---------------- weight bf16 conversion (once) ----------------
__global__ __launch_bounds__(256) void k_cvt(const float* __restrict__ inw1, const float* __restrict__ xpw1,
                                             const float* __restrict__ ow1, const float* __restrict__ pw1,
                                             const float* __restrict__ inw2, const float* __restrict__ xpw2,
                                             const float* __restrict__ ow2, const float* __restrict__ pw2,
                                             unsigned short* __restrict__ wb) {
  int idx = blockIdx.x * 256 + threadIdx.x;   // < 69632
  int layer = idx >= 34816;
  int e = idx - layer * 34816;
  const float* inw = layer ? inw2 : inw1;
  const float* xpw = layer ? xpw2 : xpw1;
  const float* ow = layer ? ow2 : ow1;
  const float* pw = layer ? pw2 : pw1;
  float v;
  if (e < 16384) v = inw[e];
  else if (e < 22528) { int t = e - 16384; int r = t >> 7, c = t & 127; v = (r < 36) ? xpw[r * 128 + c] : 0.f; }
  else if (e < 30720) v = ow[e - 22528];
  else v = pw[e - 30720];
  wb[idx] = f2b(v);
}

// ---------------- instance-norm moments per (b,c) ----------------
__global__ __launch_bounds__(256) void k_stats(const float* __restrict__ p,
                                               float* __restrict__ stats) {
  int bc = blockIdx.x;
  const float* row = p + (size_t)bc * LL;
  float s = 0.f, s2 = 0.f;
  for (int i = threadIdx.x; i < LL; i += 256) {
    float v = row[i];
    s += v; s2 += v * v;
  }
  #pragma unroll
  for (int o = 32; o > 0; o >>= 1) {
    s += __shfl_down(s, o);
    s2 += __shfl_down(s2, o);
  }
  __shared__ float red[8];
  int w = threadIdx.x >> 6;
  if ((threadIdx.x & 63) == 0) { red[w] = s; red[4 + w] = s2; }
  __syncthreads();
  if (threadIdx.x == 0) {
    float S = red[0] + red[1] + red[2] + red[3];
    float S2 = red[4] + red[5] + red[6] + red[7];
    float m = S * (1.f / LL);
    float var = S2 * (1.f / LL) - m * m;
    stats[bc * 2] = m;
    stats[bc * 2 + 1] = rsqrtf(var + 1e-5f);
  }
}

// ---- fused: transpose + IN + relu + LN + in-proj MFMA -> xf, xin_b, sz_b=silu(z) ----
__global__ __launch_bounds__(256) void k_fusein(const float* __restrict__ p,
                                                const float* __restrict__ stats,
                                                const float* __restrict__ g,
                                                const float* __restrict__ be,
                                                const unsigned short* __restrict__ w_b,
                                                float* __restrict__ xf,
                                                unsigned short* __restrict__ xin_b,
                                                unsigned short* __restrict__ sz_b) {
  int b = blockIdx.x / NT;
  int l0 = (blockIdx.x % NT) * 64;
  __shared__ float T[64][65];
  __shared__ unsigned short Tb[64][72];
  int li = threadIdx.x & 63;
  int c0 = threadIdx.x >> 6;
  #pragma unroll
  for (int j = 0; j < 16; ++j) {
    int c = c0 * 16 + j;
    float m = stats[(b * CC + c) * 2];
    float rs = stats[(b * CC + c) * 2 + 1];
    float v = p[((size_t)(b * CC + c)) * LL + l0 + li];
    T[li][c] = fmaxf((v - m) * rs, 0.f);
  }
  __syncthreads();
  int lane = threadIdx.x & 63;
  int w = threadIdx.x >> 6;
  float gv = g[lane], bv = be[lane];
  for (int j = 0; j < 16; ++j) {
    int row = w * 16 + j;
    float v = T[row][lane];
    float s = v, s2 = v * v;
    #pragma unroll
    for (int o = 32; o > 0; o >>= 1) { s += __shfl_xor(s, o); s2 += __shfl_xor(s2, o); }
    float m = s * (1.f / 64.f);
    float var = s2 * (1.f / 64.f) - m * m;
    float rs = rsqrtf(var + 1e-5f);
    size_t off = ((size_t)b * LL + l0 + row) * CC + lane;
    xf[off] = v;
    Tb[row][lane] = f2b((v - m) * rs * gv + bv);
  }
  __syncthreads();
  int wv = threadIdx.x >> 6;
  int lr = lane & 15, kg = lane >> 4;
  int m0 = wv * 16;
  int rowg0 = blockIdx.x * 64 + m0;
  bf16x8 a0 = *(const bf16x8*)&Tb[m0 + lr][kg * 8];
  bf16x8 a1 = *(const bf16x8*)&Tb[m0 + lr][32 + kg * 8];
  #pragma unroll
  for (int nt = 0; nt < 16; ++nt) {
    bf16x8 b0 = *(const bf16x8*)&w_b[(size_t)(nt * 16 + lr) * CC + kg * 8];
    bf16x8 b1 = *(const bf16x8*)&w_b[(size_t)(nt * 16 + lr) * CC + 32 + kg * 8];
    fx4 c = {0.f, 0.f, 0.f, 0.f};
    c = MFMA16(a0, b0, c, 0, 0, 0);
    c = MFMA16(a1, b1, c, 0, 0, 0);
    #pragma unroll
    for (int r = 0; r < 4; ++r) {
      int row = rowg0 + kg * 4 + r, col = nt * 16 + lr;
      if (col < 128) xin_b[(size_t)row * DI + col] = f2b(c[r]);
      else           sz_b[(size_t)row * DI + col - 128] = f2b(silu_f(c[r]));
    }
  }
}

// ---- scanAX (128t, 1 chunk): split-K x-proj MFMA (conv once -> xcS/xc_b) + local scan ----
__global__ __launch_bounds__(128) void k_scanAX(const unsigned short* __restrict__ xin_b,
                                                const float* __restrict__ cw,
                                                const float* __restrict__ cb,
                                                const unsigned short* __restrict__ xpw_b,
                                                const float* __restrict__ Alog,
                                                const float* __restrict__ dtw,
                                                const float* __restrict__ dtbp,
                                                float* __restrict__ dbl,
                                                unsigned short* __restrict__ xc_b,
                                                float* __restrict__ dts,
                                                float* __restrict__ hl) {
  int g = blockIdx.x % GCH;
  int b = blockIdx.x / GCH;
  __shared__ float dblP[2][16][40];
  __shared__ unsigned short xcS[16][136];
  int wv = threadIdx.x >> 6, lane = threadIdx.x & 63;
  int lr = lane & 15, kg = lane >> 4;
  {
    int lloc = g * LCH + lr;
    size_t row = (size_t)b * LL + lloc;
    const bf16x8 zv8 = {0, 0, 0, 0, 0, 0, 0, 0};
    fx4 acc[3];
    #pragma unroll
    for (int nt = 0; nt < 3; ++nt) acc[nt] = (fx4){0.f, 0.f, 0.f, 0.f};
    #pragma unroll
    for (int kk = 0; kk < 2; ++kk) {
      int cbase = (wv * 2 + kk) * 32 + kg * 8;
      bf16x8 x3 = *(const bf16x8*)&xin_b[row * DI + cbase];
      bf16x8 x2 = (lloc >= 1) ? *(const bf16x8*)&xin_b[(row - 1) * DI + cbase] : zv8;
      bf16x8 x1 = (lloc >= 2) ? *(const bf16x8*)&xin_b[(row - 2) * DI + cbase] : zv8;
      bf16x8 x0 = (lloc >= 3) ? *(const bf16x8*)&xin_b[(row - 3) * DI + cbase] : zv8;
      bf16x8 a;
      #pragma unroll
      for (int e = 0; e < 8; ++e) {
        int dd = cbase + e;
        float4 w4 = *(const float4*)&cw[dd * 4];
        float v = cb[dd] + b2f((unsigned short)x0[e]) * w4.x + b2f((unsigned short)x1[e]) * w4.y
                + b2f((unsigned short)x2[e]) * w4.z + b2f((unsigned short)x3[e]) * w4.w;
        a[e] = (short)f2b(silu_f(v));
      }
      *(bf16x8*)&xcS[lr][cbase] = a;   // tile-complete across waves/kg/kk
      #pragma unroll
      for (int nt = 0; nt < 3; ++nt) {
        bf16x8 bfr = *(const bf16x8*)&xpw_b[(size_t)(nt * 16 + lr) * DI + cbase];
        acc[nt] = MFMA16(a, bfr, acc[nt], 0, 0, 0);
      }
    }
    #pragma unroll
    for (int nt = 0; nt < 3; ++nt)
      #pragma unroll
      for (int r = 0; r < 4; ++r) {
        int col = nt * 16 + lr;
        if (col < 36) dblP[wv][kg * 4 + r][col] = acc[nt][r];
      }
  }
  __syncthreads();
  // sum split-K partials into dblP[0] + coalesced global writes (dbl, xc_b)
  {
    size_t dbase = ((size_t)b * LL + g * LCH) * 36;
    for (int e = threadIdx.x; e < 576; e += 128) {
      int r = e / 36, c = e - r * 36;
      float v = dblP[0][r][c] + dblP[1][r][c];
      dblP[0][r][c] = v;
      dbl[dbase + e] = v;
    }
    size_t xbase = ((size_t)b * LL + g * LCH) * DI;
    #pragma unroll
    for (int j = 0; j < 2; ++j) {
      int c = threadIdx.x + 128 * j;       // 256 chunks of 8 shorts
      int row = c >> 4, col = (c & 15) * 8;
      *(bf16x8*)&xc_b[xbase + row * DI + col] = *(const bf16x8*)&xcS[row][col];
    }
  }
  __syncthreads();
  // local scan per d (xc from LDS)
  int d = threadIdx.x;
  float A0 = -__expf(Alog[d * NS]);
  bool afast = true;
  #pragma unroll
  for (int n = 1; n < 16; ++n) {
    float An = -__expf(Alog[d * NS + n]);
    afast = afast && (fabsf(An - A0 * (float)(n + 1)) <= 1e-3f * (float)(n + 1) * fabsf(A0));
  }
  bool aone = afast && (A0 == -1.0f);
  float4 w4 = *(const float4*)&dtw[d * 4];
  float dtbv = dtbp[d];
  float h[16];
  #pragma unroll
  for (int n = 0; n < 16; ++n) h[n] = 0.f;
  float dtsum = 0.f;
  #pragma unroll 4
  for (int l = 0; l < LCH; ++l) {
    float xcv = b2f(xcS[l][d]);
    float4 qv = *(float4*)&dblP[0][l][0];
    float v = dtbv + qv.x * w4.x + qv.y * w4.y + qv.z * w4.z + qv.w * w4.w;
    float a[16];
    float dtv = dt_and_a(v, A0, aone, afast, Alog, d, a);
    float dx = dtv * xcv;
    dtsum += dtv;
    float4 b0 = *(float4*)&dblP[0][l][4];
    float4 b1 = *(float4*)&dblP[0][l][8];
    float4 b2 = *(float4*)&dblP[0][l][12];
    float4 b3 = *(float4*)&dblP[0][l][16];
    h[0]  = a[0]  * h[0]  + dx * b0.x;  h[1]  = a[1]  * h[1]  + dx * b0.y;
    h[2]  = a[2]  * h[2]  + dx * b0.z;  h[3]  = a[3]  * h[3]  + dx * b0.w;
    h[4]  = a[4]  * h[4]  + dx * b1.x;  h[5]  = a[5]  * h[5]  + dx * b1.y;
    h[6]  = a[6]  * h[6]  + dx * b1.z;  h[7]  = a[7]  * h[7]  + dx * b1.w;
    h[8]  = a[8]  * h[8]  + dx * b2.x;  h[9]  = a[9]  * h[9]  + dx * b2.y;
    h[10] = a[10] * h[10] + dx * b2.z;  h[11] = a[11] * h[11] + dx * b2.w;
    h[12] = a[12] * h[12] + dx * b3.x;  h[13] = a[13] * h[13] + dx * b3.y;
    h[14] = a[14] * h[14] + dx * b3.z;  h[15] = a[15] * h[15] + dx * b3.w;
  }
  dts[(size_t)g * SD + b * DI + d] = dtsum;
  size_t o = (size_t)g * NSEQ + ((size_t)b * DI + d) * NS;
  #pragma unroll
  for (int j = 0; j < 4; ++j)
    *(float4*)&hl[o + j * 4] = make_float4(h[j * 4], h[j * 4 + 1], h[j * 4 + 2], h[j * 4 + 3]);
}

// ---- scan2a: per-group aggregates (a recomputed from dtsum — exact) ----
__global__ __launch_bounds__(256) void k_scan2a(const float* __restrict__ dts,
                                                const float* __restrict__ hl,
                                                const float* __restrict__ Alog,
                                                float* __restrict__ gap,
                                                float* __restrict__ ghl) {
  int t = blockIdx.x * 256 + threadIdx.x;   // < NG*NSEQ
  int grp = t >> 13, seq = t & (NSEQ - 1);
  int sd = seq >> 4;
  float An = -__expf(Alog[seq & (DI * NS - 1)]);
  float A = 1.f, H = 0.f;
  int c0 = grp * GS;
  #pragma unroll 4
  for (int c = 0; c < GS; ++c) {
    float a = __expf(An * dts[(size_t)(c0 + c) * SD + sd]);
    H = a * H + hl[(size_t)(c0 + c) * NSEQ + seq];
    A *= a;
  }
  gap[t] = A;
  ghl[t] = H;
}

// ---- scan2bc: redundant group-prefix + chunk carries ----
__global__ __launch_bounds__(256) void k_scan2bc(const float* __restrict__ dts,
                                                 const float* __restrict__ hl,
                                                 const float* __restrict__ gap,
                                                 const float* __restrict__ ghl,
                                                 const float* __restrict__ Alog,
                                                 float* __restrict__ hi) {
  int t = blockIdx.x * 256 + threadIdx.x;   // < NG*NSEQ
  int grp = t >> 13, seq = t & (NSEQ - 1);
  int sd = seq >> 4;
  float An = -__expf(Alog[seq & (DI * NS - 1)]);
  float h = 0.f;
  for (int gg = 0; gg < grp; ++gg)
    h = gap[gg * NSEQ + seq] * h + ghl[gg * NSEQ + seq];
  int c0 = grp * GS;
  #pragma unroll 4
  for (int c = 0; c < GS; ++c) {
    float a = __expf(An * dts[(size_t)(c0 + c) * SD + sd]);
    hi[(size_t)(c0 + c) * NSEQ + seq] = h;
    h = a * h + hl[(size_t)(c0 + c) * NSEQ + seq];
  }
}

// ---- scanCO (128t, 1 chunk): dbl+xc load -> replay -> out/pr-proj full-K split-N ----
__global__ __launch_bounds__(128) void k_scanCO(const float* __restrict__ dbl,
                                                const unsigned short* __restrict__ xc_b,
                                                const unsigned short* __restrict__ sz_b,
                                                const float* __restrict__ Alog,
                                                const float* __restrict__ dtw,
                                                const float* __restrict__ dtbp,
                                                const float* __restrict__ Dp,
                                                const float* __restrict__ hi,
                                                const unsigned short* __restrict__ ow_b,
                                                const float* __restrict__ xf,
                                                const float* __restrict__ skipv,
                                                const unsigned short* __restrict__ pw_b,
                                                const float* __restrict__ pb,
                                                const float* __restrict__ ident,
                                                float* __restrict__ dst, int addid) {
  int g = blockIdx.x % GCH;
  int b = blockIdx.x / GCH;
  int d = threadIdx.x;
  __shared__ float Bms[LCH * NS];
  __shared__ float Cms[LCH * NS];
  __shared__ float Dts[LCH][4];
  __shared__ unsigned short xcS[16][136];
  __shared__ unsigned short yS[16][136];
  __shared__ unsigned short tmpS[16][72];
  {
    int tid = threadIdx.x;
    size_t rb0 = ((size_t)b * LL + g * LCH) * 36;
    if (tid < 64) {
      int l = tid >> 2, n4 = (tid & 3) * 4;
      *(float4*)&Bms[l * 16 + n4] = *(const float4*)&dbl[rb0 + (size_t)l * 36 + 4 + n4];
    } else {
      int l = (tid - 64) >> 2, n4 = (tid & 3) * 4;
      *(float4*)&Cms[l * 16 + n4] = *(const float4*)&dbl[rb0 + (size_t)l * 36 + 20 + n4];
    }
    if (tid < 16)
      *(float4*)&Dts[tid][0] = *(const float4*)&dbl[rb0 + (size_t)tid * 36];
    size_t xbase = ((size_t)b * LL + g * LCH) * DI;
    #pragma unroll
    for (int j = 0; j < 2; ++j) {
      int c = tid + 128 * j;
      int row = c >> 4, col = (c & 15) * 8;
      *(bf16x8*)&xcS[row][col] = *(const bf16x8*)&xc_b[xbase + row * DI + col];
    }
  }
  float A0 = -__expf(Alog[d * NS]);
  bool afast = true;
  #pragma unroll
  for (int n = 1; n < 16; ++n) {
    float An = -__expf(Alog[d * NS + n]);
    afast = afast && (fabsf(An - A0 * (float)(n + 1)) <= 1e-3f * (float)(n + 1) * fabsf(A0));
  }
  bool aone = afast && (A0 == -1.0f);
  float4 w4 = *(const float4*)&dtw[d * 4];
  float dtbv = dtbp[d];
  float Dv = Dp[d];
  __syncthreads();
  size_t o = (size_t)g * NSEQ + ((size_t)b * DI + d) * NS;
  float h[16];
  #pragma unroll
  for (int j = 0; j < 4; ++j) {
    float4 hv = *(const float4*)&hi[o + j * 4];
    h[j * 4 + 0] = hv.x; h[j * 4 + 1] = hv.y; h[j * 4 + 2] = hv.z; h[j * 4 + 3] = hv.w;
  }
  size_t base = ((size_t)b * LL + g * LCH) * DI + d;
  #pragma unroll 4
  for (int l = 0; l < LCH; ++l) {
    float xcv = b2f(xcS[l][d]);
    float sg = b2f(sz_b[base + (size_t)l * DI]);
    float4 qv = *(float4*)&Dts[l][0];
    float v = dtbv + qv.x * w4.x + qv.y * w4.y + qv.z * w4.z + qv.w * w4.w;
    float a[16];
    float dtv = dt_and_a(v, A0, aone, afast, Alog, d, a);
    float4 b0 = *(float4*)&Bms[l * 16];
    float4 b1 = *(float4*)&Bms[l * 16 + 4];
    float4 b2 = *(float4*)&Bms[l * 16 + 8];
    float4 b3 = *(float4*)&Bms[l * 16 + 12];
    float4 c0 = *(float4*)&Cms[l * 16];
    float4 c1 = *(float4*)&Cms[l * 16 + 4];
    float4 c2 = *(float4*)&Cms[l * 16 + 8];
    float4 c3 = *(float4*)&Cms[l * 16 + 12];
    float dx = dtv * xcv;
    float yv = Dv * xcv;
    h[0]  = a[0]  * h[0]  + dx * b0.x;  yv += h[0]  * c0.x;
    h[1]  = a[1]  * h[1]  + dx * b0.y;  yv += h[1]  * c0.y;
    h[2]  = a[2]  * h[2]  + dx * b0.z;  yv += h[2]  * c0.z;
    h[3]  = a[3]  * h[3]  + dx * b0.w;  yv += h[3]  * c0.w;
    h[4]  = a[4]  * h[4]  + dx * b1.x;  yv += h[4]  * c1.x;
    h[5]  = a[5]  * h[5]  + dx * b1.y;  yv += h[5]  * c1.y;
    h[6]  = a[6]  * h[6]  + dx * b1.z;  yv += h[6]  * c1.z;
    h[7]  = a[7]  * h[7]  + dx * b1.w;  yv += h[7]  * c1.w;
    h[8]  = a[8]  * h[8]  + dx * b2.x;  yv += h[8]  * c2.x;
    h[9]  = a[9]  * h[9]  + dx * b2.y;  yv += h[9]  * c2.y;
    h[10] = a[10] * h[10] + dx * b2.z;  yv += h[10] * c2.z;
    h[11] = a[11] * h[11] + dx * b2.w;  yv += h[11] * c2.w;
    h[12] = a[12] * h[12] + dx * b3.x;  yv += h[12] * c3.x;
    h[13] = a[13] * h[13] + dx * b3.y;  yv += h[13] * c3.y;
    h[14] = a[14] * h[14] + dx * b3.z;  yv += h[14] * c3.z;
    h[15] = a[15] * h[15] + dx * b3.w;  yv += h[15] * c3.w;
    yS[l][d] = f2b(yv * sg);
  }
  __syncthreads();
  // phase O: out-proj, full-K; wave lw computes output cols lw*32 .. lw*32+31
  int lane = threadIdx.x & 63;
  int lr = lane & 15, kg = lane >> 4;
  int lw = threadIdx.x >> 6;
  {
    fx4 oacc[2];
    oacc[0] = (fx4){0.f, 0.f, 0.f, 0.f};
    oacc[1] = (fx4){0.f, 0.f, 0.f, 0.f};
    #pragma unroll
    for (int ks = 0; ks < 4; ++ks) {
      int cbase = ks * 32 + kg * 8;
      bf16x8 a = *(const bf16x8*)&yS[lr][cbase];
      #pragma unroll
      for (int j = 0; j < 2; ++j) {
        int nt = lw * 2 + j;
        bf16x8 bfr = *(const bf16x8*)&ow_b[(size_t)(nt * 16 + lr) * DI + cbase];
        oacc[j] = MFMA16(a, bfr, oacc[j], 0, 0, 0);
      }
    }
    float sk = skipv[0];
    #pragma unroll
    for (int j = 0; j < 2; ++j) {
      int nt = lw * 2 + j;
      #pragma unroll
      for (int r = 0; r < 4; ++r) {
        int rowl = kg * 4 + r, col = nt * 16 + lr;
        size_t grow = (size_t)b * LL + g * LCH + rowl;
        tmpS[rowl][col] = f2b(oacc[j][r] + sk * xf[grow * CC + col]);
      }
    }
  }
  __syncthreads();
  // phase P: pr-proj, full-K; wave lw computes output channels lw*32 .. lw*32+31
  {
    fx4 pacc[2];
    pacc[0] = (fx4){0.f, 0.f, 0.f, 0.f};
    pacc[1] = (fx4){0.f, 0.f, 0.f, 0.f};
    #pragma unroll
    for (int ks = 0; ks < 2; ++ks) {
      int cbase = ks * 32 + kg * 8;
      bf16x8 bfrag = *(const bf16x8*)&tmpS[lr][cbase];
      #pragma unroll
      for (int j = 0; j < 2; ++j) {
        int ct = lw * 2 + j;
        bf16x8 a = *(const bf16x8*)&pw_b[(size_t)(ct * 16 + lr) * CC + cbase];
        pacc[j] = MFMA16(a, bfrag, pacc[j], 0, 0, 0);
      }
    }
    #pragma unroll
    for (int j = 0; j < 2; ++j) {
      int ct = lw * 2 + j;
      #pragma unroll
      for (int r = 0; r < 4; ++r) {
        int c = ct * 16 + kg * 4 + r;
        int lpos = g * LCH + lr;
        size_t off = ((size_t)(b * CC + c)) * LL + lpos;
        float val = pacc[j][r] + pb[c];
        if (addid) val += ident[off];
        dst[off] = val;
      }
    }
  }
}

extern "C" void kernel_launch(void* const* d_in, const int* in_sizes, int n_in,
                              void* d_out, int out_size, void* d_ws, size_t ws_size,
                              hipStream_t stream) {
  const float* x = (const float*)d_in[0];
  float* ws = (float*)d_ws;
  float* stats = ws;                                        //      1024 floats
  float* xf    = ws + 1024;                                 //  2359296
  unsigned short* xin_b = (unsigned short*)(ws + 2360320);  //  4718592 shorts
  unsigned short* sz_b  = (unsigned short*)(ws + 4719616);  //  4718592 shorts
  float* dbl   = ws + 7078912;                              //  1327104
  float* dts   = ws + 8406016;                              //   294912
  float* hl    = ws + 8700928;                              //  4718592 (dead after scan2bc -> inter)
  float* hi    = ws + 13419520;                             //  4718592
  float* gap   = ws + 18138112;                             //   196608
  float* ghl   = ws + 18334720;                             //   196608
  unsigned short* wb = (unsigned short*)(ws + 18531328);    //    69632 shorts
  unsigned short* xc_b = (unsigned short*)(ws + 18566144);  //  4718592 shorts
  float* inter = hl;   // hl dead after k_scan2bc; scanCO(L0) writes it; L1 consumes it
                       // in stats/fusein BEFORE scanAX(L1) rewrites hl.
  float* outp  = (float*)d_out;

  k_cvt<<<272, 256, 0, stream>>>((const float*)d_in[3], (const float*)d_in[6],
                                 (const float*)d_in[11], (const float*)d_in[13],
                                 (const float*)d_in[17], (const float*)d_in[20],
                                 (const float*)d_in[25], (const float*)d_in[27], wb);

  const float* cur = x;
  for (int layer = 0; layer < 2; ++layer) {
    const int p0 = 1 + 14 * layer;
    const float* ln_g   = (const float*)d_in[p0 + 0];
    const float* ln_b   = (const float*)d_in[p0 + 1];
    const float* conv_w = (const float*)d_in[p0 + 3];
    const float* conv_b = (const float*)d_in[p0 + 4];
    const float* dt_w   = (const float*)d_in[p0 + 6];
    const float* dt_b   = (const float*)d_in[p0 + 7];
    const float* A_log  = (const float*)d_in[p0 + 8];
    const float* Dp     = (const float*)d_in[p0 + 9];
    const float* skip   = (const float*)d_in[p0 + 11];
    const float* pr_b   = (const float*)d_in[p0 + 13];
    const unsigned short* inw_b = wb + (size_t)layer * 34816;
    const unsigned short* xpw_b = inw_b + 16384;
    const unsigned short* ow_b  = inw_b + 22528;
    const unsigned short* pw_b  = inw_b + 30720;
    float* dst = (layer == 0) ? inter : outp;

    k_stats  <<<BB * CC, 256, 0, stream>>>(cur, stats);
    k_fusein <<<BB * NT, 256, 0, stream>>>(cur, stats, ln_g, ln_b, inw_b, xf, xin_b, sz_b);
    k_scanAX <<<BB * GCH, 128, 0, stream>>>(xin_b, conv_w, conv_b, xpw_b, A_log,
                                            dt_w, dt_b, dbl, xc_b, dts, hl);
    k_scan2a <<<(NG * NSEQ) / 256, 256, 0, stream>>>(dts, hl, A_log, gap, ghl);
    k_scan2bc<<<(NG * NSEQ) / 256, 256, 0, stream>>>(dts, hl, gap, ghl, A_log, hi);
    k_scanCO <<<BB * GCH, 128, 0, stream>>>(dbl, xc_b, sz_b, A_log, dt_w, dt_b, Dp,
                                            hi, ow_b, xf, skip, pw_b, pr_b, x, dst, layer);
    cur = inter;
  }
}

// Round 13
// 230.788 us; speedup vs baseline: 1.1763x; 1.0276x over previous
//
#include <hip/hip_runtime.h>
#include <math.h>

#define BB 4
#define CC 64
#define DI 128
#define NS 16
#define LL 9216
#define NT (LL / 64)

// scan decomposition
#define GCH 576
#define LCH 16
#define NSEQ 8192      // B*DI*NS
#define SD  512        // B*DI
#define NG 24
#define GS 24          // NG*GS == GCH

typedef __attribute__((ext_vector_type(8))) short bf16x8;
typedef __attribute__((ext_vector_type(4))) float fx4;
#define MFMA16 __builtin_amdgcn_mfma_f32_16x16x32_bf16

static __device__ __forceinline__ unsigned short f2b(float f) {
  unsigned u = __float_as_uint(f);
  u += 0x7fffu + ((u >> 16) & 1u);
  return (unsigned short)(u >> 16);
}
static __device__ __forceinline__ float b2f(unsigned short s) {
  return __uint_as_float(((unsigned)s) << 16);
}
static __device__ __forceinline__ float silu_f(float x) {
  return x / (1.f + __expf(-x));
}

// powers of e1: a[n] = e1^(n+1)
static __device__ __forceinline__ void powers16(float e1, float* a) {
  float p2 = e1 * e1, p4 = p2 * p2, p8 = p4 * p4;
  a[0] = e1;      a[1] = p2;      a[2] = p2 * e1;      a[3] = p4;
  a[4] = p4 * e1; a[5] = p4 * p2; a[6] = p4 * p2 * e1; a[7] = p8;
  a[8] = p8 * e1; a[9] = p8 * p2; a[10] = p8 * p2 * e1; a[11] = p8 * p4;
  a[12] = p8 * p4 * e1; a[13] = p8 * p4 * p2; a[14] = p8 * p4 * p2 * e1; a[15] = p8 * p8;
}

// dtv = softplus(v); a[16] decay factors. aone: A0==-1 -> e1=sigmoid(-v) free.
static __device__ __forceinline__ float dt_and_a(float v, float A0, bool aone, bool afast,
                                                 const float* __restrict__ Alog, int d,
                                                 float* a) {
  float em = __expf(-fabsf(v));
  float t = 1.f + em;
  float dtv = fmaxf(v, 0.f) + __logf(t);
  if (aone) {
    float e1 = ((v >= 0.f) ? em : 1.f) / t;   // == exp(-dtv)
    powers16(e1, a);
  } else if (afast) {
    powers16(__expf(dtv * A0), a);
  } else {
    #pragma unroll
    for (int n = 0; n < 16; ++n) a[n] = __expf(dtv * -__expf(Alog[d * NS + n]));
  }
  return dtv;
}

// ---------------- weight bf16 conversion (once) ----------------
__global__ __launch_bounds__(256) void k_cvt(const float* __restrict__ inw1, const float* __restrict__ xpw1,
                                             const float* __restrict__ ow1, const float* __restrict__ pw1,
                                             const float* __restrict__ inw2, const float* __restrict__ xpw2,
                                             const float* __restrict__ ow2, const float* __restrict__ pw2,
                                             unsigned short* __restrict__ wb) {
  int idx = blockIdx.x * 256 + threadIdx.x;   // < 69632
  int layer = idx >= 34816;
  int e = idx - layer * 34816;
  const float* inw = layer ? inw2 : inw1;
  const float* xpw = layer ? xpw2 : xpw1;
  const float* ow = layer ? ow2 : ow1;
  const float* pw = layer ? pw2 : pw1;
  float v;
  if (e < 16384) v = inw[e];
  else if (e < 22528) { int t = e - 16384; int r = t >> 7, c = t & 127; v = (r < 36) ? xpw[r * 128 + c] : 0.f; }
  else if (e < 30720) v = ow[e - 22528];
  else v = pw[e - 30720];
  wb[idx] = f2b(v);
}

// ---------------- instance-norm moments per (b,c) ----------------
__global__ __launch_bounds__(256) void k_stats(const float* __restrict__ p,
                                               float* __restrict__ stats) {
  int bc = blockIdx.x;
  const float* row = p + (size_t)bc * LL;
  float s = 0.f, s2 = 0.f;
  for (int i = threadIdx.x; i < LL; i += 256) {
    float v = row[i];
    s += v; s2 += v * v;
  }
  #pragma unroll
  for (int o = 32; o > 0; o >>= 1) {
    s += __shfl_down(s, o);
    s2 += __shfl_down(s2, o);
  }
  __shared__ float red[8];
  int w = threadIdx.x >> 6;
  if ((threadIdx.x & 63) == 0) { red[w] = s; red[4 + w] = s2; }
  __syncthreads();
  if (threadIdx.x == 0) {
    float S = red[0] + red[1] + red[2] + red[3];
    float S2 = red[4] + red[5] + red[6] + red[7];
    float m = S * (1.f / LL);
    float var = S2 * (1.f / LL) - m * m;
    stats[bc * 2] = m;
    stats[bc * 2 + 1] = rsqrtf(var + 1e-5f);
  }
}

// ---- fused: transpose + IN + relu + LN + in-proj MFMA -> xf, xin_b, sz_b=silu(z) ----
__global__ __launch_bounds__(256) void k_fusein(const float* __restrict__ p,
                                                const float* __restrict__ stats,
                                                const float* __restrict__ g,
                                                const float* __restrict__ be,
                                                const unsigned short* __restrict__ w_b,
                                                float* __restrict__ xf,
                                                unsigned short* __restrict__ xin_b,
                                                unsigned short* __restrict__ sz_b) {
  int b = blockIdx.x / NT;
  int l0 = (blockIdx.x % NT) * 64;
  __shared__ float T[64][65];
  __shared__ unsigned short Tb[64][72];
  int li = threadIdx.x & 63;
  int c0 = threadIdx.x >> 6;
  #pragma unroll
  for (int j = 0; j < 16; ++j) {
    int c = c0 * 16 + j;
    float m = stats[(b * CC + c) * 2];
    float rs = stats[(b * CC + c) * 2 + 1];
    float v = p[((size_t)(b * CC + c)) * LL + l0 + li];
    T[li][c] = fmaxf((v - m) * rs, 0.f);
  }
  __syncthreads();
  // LN: 4 threads per row, each sums 16 channels; combine via 2 shfl_xor
  {
    int row = threadIdx.x >> 2, part = threadIdx.x & 3;
    int ch0 = part * 16;
    float s = 0.f, s2 = 0.f;
    #pragma unroll
    for (int j = 0; j < 16; ++j) {
      float v = T[row][ch0 + j];
      s += v; s2 += v * v;
    }
    s += __shfl_xor(s, 1); s2 += __shfl_xor(s2, 1);
    s += __shfl_xor(s, 2); s2 += __shfl_xor(s2, 2);
    float m = s * (1.f / 64.f);
    float var = s2 * (1.f / 64.f) - m * m;
    float rs = rsqrtf(var + 1e-5f);
    size_t off0 = ((size_t)b * LL + l0 + row) * CC + ch0;
    #pragma unroll
    for (int j4 = 0; j4 < 4; ++j4) {
      float4 v4 = *(float4*)&T[row][ch0 + j4 * 4];
      *(float4*)&xf[off0 + j4 * 4] = v4;
      float4 g4 = *(const float4*)&g[ch0 + j4 * 4];
      float4 b4 = *(const float4*)&be[ch0 + j4 * 4];
      Tb[row][ch0 + j4 * 4 + 0] = f2b((v4.x - m) * rs * g4.x + b4.x);
      Tb[row][ch0 + j4 * 4 + 1] = f2b((v4.y - m) * rs * g4.y + b4.y);
      Tb[row][ch0 + j4 * 4 + 2] = f2b((v4.z - m) * rs * g4.z + b4.z);
      Tb[row][ch0 + j4 * 4 + 3] = f2b((v4.w - m) * rs * g4.w + b4.w);
    }
  }
  __syncthreads();
  int lane = threadIdx.x & 63;
  int wv = threadIdx.x >> 6;
  int lr = lane & 15, kg = lane >> 4;
  int m0 = wv * 16;
  int rowg0 = blockIdx.x * 64 + m0;
  bf16x8 a0 = *(const bf16x8*)&Tb[m0 + lr][kg * 8];
  bf16x8 a1 = *(const bf16x8*)&Tb[m0 + lr][32 + kg * 8];
  #pragma unroll
  for (int nt = 0; nt < 16; ++nt) {
    bf16x8 b0 = *(const bf16x8*)&w_b[(size_t)(nt * 16 + lr) * CC + kg * 8];
    bf16x8 b1 = *(const bf16x8*)&w_b[(size_t)(nt * 16 + lr) * CC + 32 + kg * 8];
    fx4 c = {0.f, 0.f, 0.f, 0.f};
    c = MFMA16(a0, b0, c, 0, 0, 0);
    c = MFMA16(a1, b1, c, 0, 0, 0);
    #pragma unroll
    for (int r = 0; r < 4; ++r) {
      int row = rowg0 + kg * 4 + r, col = nt * 16 + lr;
      if (col < 128) xin_b[(size_t)row * DI + col] = f2b(c[r]);
      else           sz_b[(size_t)row * DI + col - 128] = f2b(silu_f(c[r]));
    }
  }
}

// ---- scanAX: split-K x-proj MFMA (conv once) + local scan + y1/dtpre emission ----
__global__ __launch_bounds__(128) void k_scanAX(const unsigned short* __restrict__ xin_b,
                                                const float* __restrict__ cw,
                                                const float* __restrict__ cb,
                                                const unsigned short* __restrict__ xpw_b,
                                                const float* __restrict__ Alog,
                                                const float* __restrict__ dtw,
                                                const float* __restrict__ dtbp,
                                                float* __restrict__ dblC,
                                                unsigned short* __restrict__ xc_b,
                                                float* __restrict__ dts,
                                                float* __restrict__ hl,
                                                float* __restrict__ y1G,
                                                float* __restrict__ dtpreG) {
  int g = blockIdx.x % GCH;
  int b = blockIdx.x / GCH;
  __shared__ float dblP[2][16][40];
  __shared__ unsigned short xcS[16][136];
  int wv = threadIdx.x >> 6, lane = threadIdx.x & 63;
  int lr = lane & 15, kg = lane >> 4;
  {
    int lloc = g * LCH + lr;
    size_t row = (size_t)b * LL + lloc;
    const bf16x8 zv8 = {0, 0, 0, 0, 0, 0, 0, 0};
    fx4 acc[3];
    #pragma unroll
    for (int nt = 0; nt < 3; ++nt) acc[nt] = (fx4){0.f, 0.f, 0.f, 0.f};
    #pragma unroll
    for (int kk = 0; kk < 2; ++kk) {
      int cbase = (wv * 2 + kk) * 32 + kg * 8;
      bf16x8 x3 = *(const bf16x8*)&xin_b[row * DI + cbase];
      bf16x8 x2 = (lloc >= 1) ? *(const bf16x8*)&xin_b[(row - 1) * DI + cbase] : zv8;
      bf16x8 x1 = (lloc >= 2) ? *(const bf16x8*)&xin_b[(row - 2) * DI + cbase] : zv8;
      bf16x8 x0 = (lloc >= 3) ? *(const bf16x8*)&xin_b[(row - 3) * DI + cbase] : zv8;
      bf16x8 a;
      #pragma unroll
      for (int e = 0; e < 8; ++e) {
        int dd = cbase + e;
        float4 w4 = *(const float4*)&cw[dd * 4];
        float v = cb[dd] + b2f((unsigned short)x0[e]) * w4.x + b2f((unsigned short)x1[e]) * w4.y
                + b2f((unsigned short)x2[e]) * w4.z + b2f((unsigned short)x3[e]) * w4.w;
        a[e] = (short)f2b(silu_f(v));
      }
      *(bf16x8*)&xcS[lr][cbase] = a;
      #pragma unroll
      for (int nt = 0; nt < 3; ++nt) {
        bf16x8 bfr = *(const bf16x8*)&xpw_b[(size_t)(nt * 16 + lr) * DI + cbase];
        acc[nt] = MFMA16(a, bfr, acc[nt], 0, 0, 0);
      }
    }
    #pragma unroll
    for (int nt = 0; nt < 3; ++nt)
      #pragma unroll
      for (int r = 0; r < 4; ++r) {
        int col = nt * 16 + lr;
        if (col < 36) dblP[wv][kg * 4 + r][col] = acc[nt][r];
      }
  }
  __syncthreads();
  // sum split-K partials into dblP[0]; write C cols + xc to global (coalesced)
  {
    for (int e = threadIdx.x; e < 576; e += 128) {
      int r = e / 36, c = e - r * 36;
      dblP[0][r][c] += dblP[1][r][c];
    }
  }
  __syncthreads();
  {
    size_t cbase16 = ((size_t)b * LL + g * LCH) * 16;
    #pragma unroll
    for (int j = 0; j < 2; ++j) {
      int e = threadIdx.x + 128 * j;   // < 256
      dblC[cbase16 + e] = dblP[0][e >> 4][20 + (e & 15)];
    }
    size_t xbase = ((size_t)b * LL + g * LCH) * DI;
    #pragma unroll
    for (int j = 0; j < 2; ++j) {
      int c = threadIdx.x + 128 * j;
      int row = c >> 4, col = (c & 15) * 8;
      *(bf16x8*)&xc_b[xbase + row * DI + col] = *(const bf16x8*)&xcS[row][col];
    }
  }
  // local scan per d (xc from LDS); emit y1 = C.h_local, dtpre
  int d = threadIdx.x;
  float A0 = -__expf(Alog[d * NS]);
  bool afast = true;
  #pragma unroll
  for (int n = 1; n < 16; ++n) {
    float An = -__expf(Alog[d * NS + n]);
    afast = afast && (fabsf(An - A0 * (float)(n + 1)) <= 1e-3f * (float)(n + 1) * fabsf(A0));
  }
  bool aone = afast && (A0 == -1.0f);
  float4 w4 = *(const float4*)&dtw[d * 4];
  float dtbv = dtbp[d];
  float h[16];
  #pragma unroll
  for (int n = 0; n < 16; ++n) h[n] = 0.f;
  float dtsum = 0.f;
  size_t sbase = ((size_t)b * LL + g * LCH) * DI + d;
  #pragma unroll 4
  for (int l = 0; l < LCH; ++l) {
    float xcv = b2f(xcS[l][d]);
    float4 qv = *(float4*)&dblP[0][l][0];
    float v = dtbv + qv.x * w4.x + qv.y * w4.y + qv.z * w4.z + qv.w * w4.w;
    float a[16];
    float dtv = dt_and_a(v, A0, aone, afast, Alog, d, a);
    float dx = dtv * xcv;
    dtsum += dtv;
    float4 b0 = *(float4*)&dblP[0][l][4];
    float4 b1 = *(float4*)&dblP[0][l][8];
    float4 b2 = *(float4*)&dblP[0][l][12];
    float4 b3 = *(float4*)&dblP[0][l][16];
    h[0]  = a[0]  * h[0]  + dx * b0.x;  h[1]  = a[1]  * h[1]  + dx * b0.y;
    h[2]  = a[2]  * h[2]  + dx * b0.z;  h[3]  = a[3]  * h[3]  + dx * b0.w;
    h[4]  = a[4]  * h[4]  + dx * b1.x;  h[5]  = a[5]  * h[5]  + dx * b1.y;
    h[6]  = a[6]  * h[6]  + dx * b1.z;  h[7]  = a[7]  * h[7]  + dx * b1.w;
    h[8]  = a[8]  * h[8]  + dx * b2.x;  h[9]  = a[9]  * h[9]  + dx * b2.y;
    h[10] = a[10] * h[10] + dx * b2.z;  h[11] = a[11] * h[11] + dx * b2.w;
    h[12] = a[12] * h[12] + dx * b3.x;  h[13] = a[13] * h[13] + dx * b3.y;
    h[14] = a[14] * h[14] + dx * b3.z;  h[15] = a[15] * h[15] + dx * b3.w;
    float4 cc0 = *(float4*)&dblP[0][l][20];
    float4 cc1 = *(float4*)&dblP[0][l][24];
    float4 cc2 = *(float4*)&dblP[0][l][28];
    float4 cc3 = *(float4*)&dblP[0][l][32];
    float y0 = h[0] * cc0.x + h[1] * cc0.y + h[2] * cc0.z + h[3] * cc0.w;
    float y1 = h[4] * cc1.x + h[5] * cc1.y + h[6] * cc1.z + h[7] * cc1.w;
    float y2 = h[8] * cc2.x + h[9] * cc2.y + h[10] * cc2.z + h[11] * cc2.w;
    float y3 = h[12] * cc3.x + h[13] * cc3.y + h[14] * cc3.z + h[15] * cc3.w;
    y1G[sbase + (size_t)l * DI] = (y0 + y1) + (y2 + y3);
    dtpreG[sbase + (size_t)l * DI] = dtsum;
  }
  dts[(size_t)g * SD + b * DI + d] = dtsum;
  size_t o = (size_t)g * NSEQ + ((size_t)b * DI + d) * NS;
  #pragma unroll
  for (int j = 0; j < 4; ++j)
    *(float4*)&hl[o + j * 4] = make_float4(h[j * 4], h[j * 4 + 1], h[j * 4 + 2], h[j * 4 + 3]);
}

// ---- scan2a: per-group aggregates (a recomputed from dtsum — exact) ----
__global__ __launch_bounds__(256) void k_scan2a(const float* __restrict__ dts,
                                                const float* __restrict__ hl,
                                                const float* __restrict__ Alog,
                                                float* __restrict__ gap,
                                                float* __restrict__ ghl) {
  int t = blockIdx.x * 256 + threadIdx.x;   // < NG*NSEQ
  int grp = t >> 13, seq = t & (NSEQ - 1);
  int sd = seq >> 4;
  float An = -__expf(Alog[seq & (DI * NS - 1)]);
  float A = 1.f, H = 0.f;
  int c0 = grp * GS;
  #pragma unroll 4
  for (int c = 0; c < GS; ++c) {
    float a = __expf(An * dts[(size_t)(c0 + c) * SD + sd]);
    H = a * H + hl[(size_t)(c0 + c) * NSEQ + seq];
    A *= a;
  }
  gap[t] = A;
  ghl[t] = H;
}

// ---- scan2bc: redundant group-prefix + chunk carries ----
__global__ __launch_bounds__(256) void k_scan2bc(const float* __restrict__ dts,
                                                 const float* __restrict__ hl,
                                                 const float* __restrict__ gap,
                                                 const float* __restrict__ ghl,
                                                 const float* __restrict__ Alog,
                                                 float* __restrict__ hi) {
  int t = blockIdx.x * 256 + threadIdx.x;   // < NG*NSEQ
  int grp = t >> 13, seq = t & (NSEQ - 1);
  int sd = seq >> 4;
  float An = -__expf(Alog[seq & (DI * NS - 1)]);
  float h = 0.f;
  for (int gg = 0; gg < grp; ++gg)
    h = gap[gg * NSEQ + seq] * h + ghl[gg * NSEQ + seq];
  int c0 = grp * GS;
  #pragma unroll 4
  for (int c = 0; c < GS; ++c) {
    float a = __expf(An * dts[(size_t)(c0 + c) * SD + sd]);
    hi[(size_t)(c0 + c) * NSEQ + seq] = h;
    h = a * h + hl[(size_t)(c0 + c) * NSEQ + seq];
  }
}

// ---- scanCO: y = y1 + C.diag(exp(A dtpre)).hi + D*xc; out/pr-proj (no serial scan) ----
__global__ __launch_bounds__(128) void k_scanCO(const float* __restrict__ dblC,
                                                const unsigned short* __restrict__ xc_b,
                                                const unsigned short* __restrict__ sz_b,
                                                const float* __restrict__ y1G,
                                                const float* __restrict__ dtpreG,
                                                const float* __restrict__ Alog,
                                                const float* __restrict__ Dp,
                                                const float* __restrict__ hi,
                                                const unsigned short* __restrict__ ow_b,
                                                const float* __restrict__ xf,
                                                const float* __restrict__ skipv,
                                                const unsigned short* __restrict__ pw_b,
                                                const float* __restrict__ pb,
                                                const float* __restrict__ ident,
                                                float* __restrict__ dst, int addid) {
  int g = blockIdx.x % GCH;
  int b = blockIdx.x / GCH;
  int d = threadIdx.x;
  __shared__ float Cms[LCH * NS];
  __shared__ unsigned short xcS[16][136];
  __shared__ unsigned short yS[16][136];
  __shared__ unsigned short tmpS[16][72];
  {
    int tid = threadIdx.x;
    size_t cb16 = ((size_t)b * LL + g * LCH) * 16;
    if (tid < 64) *(float4*)&Cms[tid * 4] = *(const float4*)&dblC[cb16 + tid * 4];
    size_t xbase = ((size_t)b * LL + g * LCH) * DI;
    #pragma unroll
    for (int j = 0; j < 2; ++j) {
      int c = tid + 128 * j;
      int row = c >> 4, col = (c & 15) * 8;
      *(bf16x8*)&xcS[row][col] = *(const bf16x8*)&xc_b[xbase + row * DI + col];
    }
  }
  float A0 = -__expf(Alog[d * NS]);
  bool afast = true;
  #pragma unroll
  for (int n = 1; n < 16; ++n) {
    float An = -__expf(Alog[d * NS + n]);
    afast = afast && (fabsf(An - A0 * (float)(n + 1)) <= 1e-3f * (float)(n + 1) * fabsf(A0));
  }
  float Dv = Dp[d];
  __syncthreads();
  size_t o = (size_t)g * NSEQ + ((size_t)b * DI + d) * NS;
  float hiR[16];
  #pragma unroll
  for (int j = 0; j < 4; ++j) {
    float4 hv = *(const float4*)&hi[o + j * 4];
    hiR[j * 4 + 0] = hv.x; hiR[j * 4 + 1] = hv.y; hiR[j * 4 + 2] = hv.z; hiR[j * 4 + 3] = hv.w;
  }
  size_t base = ((size_t)b * LL + g * LCH) * DI + d;
  #pragma unroll 4
  for (int l = 0; l < LCH; ++l) {
    float dtpre = dtpreG[base + (size_t)l * DI];
    float y1v = y1G[base + (size_t)l * DI];
    float xcv = b2f(xcS[l][d]);
    float sg = b2f(sz_b[base + (size_t)l * DI]);
    float pw[16];
    if (afast) {
      powers16(__expf(A0 * dtpre), pw);
    } else {
      #pragma unroll
      for (int n = 0; n < 16; ++n) pw[n] = __expf(-__expf(Alog[d * NS + n]) * dtpre);
    }
    float4 c0 = *(float4*)&Cms[l * 16];
    float4 c1 = *(float4*)&Cms[l * 16 + 4];
    float4 c2 = *(float4*)&Cms[l * 16 + 8];
    float4 c3 = *(float4*)&Cms[l * 16 + 12];
    float s0 = c0.x * pw[0] * hiR[0] + c0.y * pw[1] * hiR[1] + c0.z * pw[2] * hiR[2] + c0.w * pw[3] * hiR[3];
    float s1 = c1.x * pw[4] * hiR[4] + c1.y * pw[5] * hiR[5] + c1.z * pw[6] * hiR[6] + c1.w * pw[7] * hiR[7];
    float s2 = c2.x * pw[8] * hiR[8] + c2.y * pw[9] * hiR[9] + c2.z * pw[10] * hiR[10] + c2.w * pw[11] * hiR[11];
    float s3 = c3.x * pw[12] * hiR[12] + c3.y * pw[13] * hiR[13] + c3.z * pw[14] * hiR[14] + c3.w * pw[15] * hiR[15];
    float yv = y1v + Dv * xcv + ((s0 + s1) + (s2 + s3));
    yS[l][d] = f2b(yv * sg);
  }
  __syncthreads();
  // phase O: out-proj, full-K; wave lw computes output cols lw*32 .. lw*32+31
  int lane = threadIdx.x & 63;
  int lr = lane & 15, kg = lane >> 4;
  int lw = threadIdx.x >> 6;
  {
    fx4 oacc[2];
    oacc[0] = (fx4){0.f, 0.f, 0.f, 0.f};
    oacc[1] = (fx4){0.f, 0.f, 0.f, 0.f};
    #pragma unroll
    for (int ks = 0; ks < 4; ++ks) {
      int cbase = ks * 32 + kg * 8;
      bf16x8 a = *(const bf16x8*)&yS[lr][cbase];
      #pragma unroll
      for (int j = 0; j < 2; ++j) {
        int nt = lw * 2 + j;
        bf16x8 bfr = *(const bf16x8*)&ow_b[(size_t)(nt * 16 + lr) * DI + cbase];
        oacc[j] = MFMA16(a, bfr, oacc[j], 0, 0, 0);
      }
    }
    float sk = skipv[0];
    #pragma unroll
    for (int j = 0; j < 2; ++j) {
      int nt = lw * 2 + j;
      #pragma unroll
      for (int r = 0; r < 4; ++r) {
        int rowl = kg * 4 + r, col = nt * 16 + lr;
        size_t grow = (size_t)b * LL + g * LCH + rowl;
        tmpS[rowl][col] = f2b(oacc[j][r] + sk * xf[grow * CC + col]);
      }
    }
  }
  __syncthreads();
  // phase P: pr-proj, full-K; wave lw computes output channels lw*32 .. lw*32+31
  {
    fx4 pacc[2];
    pacc[0] = (fx4){0.f, 0.f, 0.f, 0.f};
    pacc[1] = (fx4){0.f, 0.f, 0.f, 0.f};
    #pragma unroll
    for (int ks = 0; ks < 2; ++ks) {
      int cbase = ks * 32 + kg * 8;
      bf16x8 bfrag = *(const bf16x8*)&tmpS[lr][cbase];
      #pragma unroll
      for (int j = 0; j < 2; ++j) {
        int ct = lw * 2 + j;
        bf16x8 a = *(const bf16x8*)&pw_b[(size_t)(ct * 16 + lr) * CC + cbase];
        pacc[j] = MFMA16(a, bfrag, pacc[j], 0, 0, 0);
      }
    }
    #pragma unroll
    for (int j = 0; j < 2; ++j) {
      int ct = lw * 2 + j;
      #pragma unroll
      for (int r = 0; r < 4; ++r) {
        int c = ct * 16 + kg * 4 + r;
        int lpos = g * LCH + lr;
        size_t off = ((size_t)(b * CC + c)) * LL + lpos;
        float val = pacc[j][r] + pb[c];
        if (addid) val += ident[off];
        dst[off] = val;
      }
    }
  }
}

extern "C" void kernel_launch(void* const* d_in, const int* in_sizes, int n_in,
                              void* d_out, int out_size, void* d_ws, size_t ws_size,
                              hipStream_t stream) {
  const float* x = (const float*)d_in[0];
  float* ws = (float*)d_ws;
  float* stats = ws;                                        //      1024 floats
  float* xf    = ws + 1024;                                 //  2359296
  unsigned short* xin_b = (unsigned short*)(ws + 2360320);  //  4718592 shorts
  unsigned short* sz_b  = (unsigned short*)(ws + 4719616);  //  4718592 shorts
  float* dblC  = ws + 7078912;                              //   589824
  float* dts   = ws + 7668736;                              //   294912
  float* hl    = ws + 7963648;                              //  4718592 (dead after scan2bc -> inter)
  float* hi    = ws + 12682240;                             //  4718592
  float* gap   = ws + 17400832;                             //   196608
  float* ghl   = ws + 17597440;                             //   196608
  unsigned short* wb = (unsigned short*)(ws + 17794048);    //    69632 shorts
  unsigned short* xc_b = (unsigned short*)(ws + 17828864);  //  4718592 shorts
  float* y1G   = ws + 20188160;                             //  4718592
  float* dtpreG = ws + 24906752;                            //  4718592
  float* inter = hl;   // hl dead after k_scan2bc; scanCO(L0) writes it; L1 consumes it
                       // in stats/fusein BEFORE scanAX(L1) rewrites hl.
  float* outp  = (float*)d_out;

  k_cvt<<<272, 256, 0, stream>>>((const float*)d_in[3], (const float*)d_in[6],
                                 (const float*)d_in[11], (const float*)d_in[13],
                                 (const float*)d_in[17], (const float*)d_in[20],
                                 (const float*)d_in[25], (const float*)d_in[27], wb);

  const float* cur = x;
  for (int layer = 0; layer < 2; ++layer) {
    const int p0 = 1 + 14 * layer;
    const float* ln_g   = (const float*)d_in[p0 + 0];
    const float* ln_b   = (const float*)d_in[p0 + 1];
    const float* conv_w = (const float*)d_in[p0 + 3];
    const float* conv_b = (const float*)d_in[p0 + 4];
    const float* dt_w   = (const float*)d_in[p0 + 6];
    const float* dt_b   = (const float*)d_in[p0 + 7];
    const float* A_log  = (const float*)d_in[p0 + 8];
    const float* Dp     = (const float*)d_in[p0 + 9];
    const float* skip   = (const float*)d_in[p0 + 11];
    const float* pr_b   = (const float*)d_in[p0 + 13];
    const unsigned short* inw_b = wb + (size_t)layer * 34816;
    const unsigned short* xpw_b = inw_b + 16384;
    const unsigned short* ow_b  = inw_b + 22528;
    const unsigned short* pw_b  = inw_b + 30720;
    float* dst = (layer == 0) ? inter : outp;

    k_stats  <<<BB * CC, 256, 0, stream>>>(cur, stats);
    k_fusein <<<BB * NT, 256, 0, stream>>>(cur, stats, ln_g, ln_b, inw_b, xf, xin_b, sz_b);
    k_scanAX <<<BB * GCH, 128, 0, stream>>>(xin_b, conv_w, conv_b, xpw_b, A_log,
                                            dt_w, dt_b, dblC, xc_b, dts, hl, y1G, dtpreG);
    k_scan2a <<<(NG * NSEQ) / 256, 256, 0, stream>>>(dts, hl, A_log, gap, ghl);
    k_scan2bc<<<(NG * NSEQ) / 256, 256, 0, stream>>>(dts, hl, gap, ghl, A_log, hi);
    k_scanCO <<<BB * GCH, 128, 0, stream>>>(dblC, xc_b, sz_b, y1G, dtpreG, A_log, Dp,
                                            hi, ow_b, xf, skip, pw_b, pr_b, x, dst, layer);
    cur = inter;
  }
}

// Round 14
// 223.350 us; speedup vs baseline: 1.2154x; 1.0333x over previous
//
#include <hip/hip_runtime.h>
#include <math.h>

#define BB 4
#define CC 64
#define DI 128
#define NS 16
#define LL 9216
#define NT (LL / 64)

// scan decomposition
#define GCH 576
#define LCH 16
#define NSEQ 8192      // B*DI*NS
#define SD  512        // B*DI
#define NG 24
#define GS 24          // NG*GS == GCH

typedef __attribute__((ext_vector_type(8))) short bf16x8;
typedef __attribute__((ext_vector_type(4))) float fx4;
#define MFMA16 __builtin_amdgcn_mfma_f32_16x16x32_bf16

static __device__ __forceinline__ unsigned short f2b(float f) {
  unsigned u = __float_as_uint(f);
  u += 0x7fffu + ((u >> 16) & 1u);
  return (unsigned short)(u >> 16);
}
static __device__ __forceinline__ float b2f(unsigned short s) {
  return __uint_as_float(((unsigned)s) << 16);
}
static __device__ __forceinline__ float silu_f(float x) {
  return x / (1.f + __expf(-x));
}

// powers of e1: a[n] = e1^(n+1)
static __device__ __forceinline__ void powers16(float e1, float* a) {
  float p2 = e1 * e1, p4 = p2 * p2, p8 = p4 * p4;
  a[0] = e1;      a[1] = p2;      a[2] = p2 * e1;      a[3] = p4;
  a[4] = p4 * e1; a[5] = p4 * p2; a[6] = p4 * p2 * e1; a[7] = p8;
  a[8] = p8 * e1; a[9] = p8 * p2; a[10] = p8 * p2 * e1; a[11] = p8 * p4;
  a[12] = p8 * p4 * e1; a[13] = p8 * p4 * p2; a[14] = p8 * p4 * p2 * e1; a[15] = p8 * p8;
}

// dtv = softplus(v); a[16] decay factors. aone: A0==-1 -> e1=sigmoid(-v) free.
static __device__ __forceinline__ float dt_and_a(float v, float A0, bool aone, bool afast,
                                                 const float* __restrict__ Alog, int d,
                                                 float* a) {
  float em = __expf(-fabsf(v));
  float t = 1.f + em;
  float dtv = fmaxf(v, 0.f) + __logf(t);
  if (aone) {
    float e1 = ((v >= 0.f) ? em : 1.f) / t;   // == exp(-dtv)
    powers16(e1, a);
  } else if (afast) {
    powers16(__expf(dtv * A0), a);
  } else {
    #pragma unroll
    for (int n = 0; n < 16; ++n) a[n] = __expf(dtv * -__expf(Alog[d * NS + n]));
  }
  return dtv;
}

// ---------------- weight bf16 conversion (once) ----------------
__global__ __launch_bounds__(256) void k_cvt(const float* __restrict__ inw1, const float* __restrict__ xpw1,
                                             const float* __restrict__ ow1, const float* __restrict__ pw1,
                                             const float* __restrict__ inw2, const float* __restrict__ xpw2,
                                             const float* __restrict__ ow2, const float* __restrict__ pw2,
                                             unsigned short* __restrict__ wb) {
  int idx = blockIdx.x * 256 + threadIdx.x;   // < 69632
  int layer = idx >= 34816;
  int e = idx - layer * 34816;
  const float* inw = layer ? inw2 : inw1;
  const float* xpw = layer ? xpw2 : xpw1;
  const float* ow = layer ? ow2 : ow1;
  const float* pw = layer ? pw2 : pw1;
  float v;
  if (e < 16384) v = inw[e];
  else if (e < 22528) { int t = e - 16384; int r = t >> 7, c = t & 127; v = (r < 36) ? xpw[r * 128 + c] : 0.f; }
  else if (e < 30720) v = ow[e - 22528];
  else v = pw[e - 30720];
  wb[idx] = f2b(v);
}

// ---------------- instance-norm moments per (b,c) ----------------
__global__ __launch_bounds__(256) void k_stats(const float* __restrict__ p,
                                               float* __restrict__ stats) {
  int bc = blockIdx.x;
  const float* row = p + (size_t)bc * LL;
  float s = 0.f, s2 = 0.f;
  for (int i = threadIdx.x; i < LL; i += 256) {
    float v = row[i];
    s += v; s2 += v * v;
  }
  #pragma unroll
  for (int o = 32; o > 0; o >>= 1) {
    s += __shfl_down(s, o);
    s2 += __shfl_down(s2, o);
  }
  __shared__ float red[8];
  int w = threadIdx.x >> 6;
  if ((threadIdx.x & 63) == 0) { red[w] = s; red[4 + w] = s2; }
  __syncthreads();
  if (threadIdx.x == 0) {
    float S = red[0] + red[1] + red[2] + red[3];
    float S2 = red[4] + red[5] + red[6] + red[7];
    float m = S * (1.f / LL);
    float var = S2 * (1.f / LL) - m * m;
    stats[bc * 2] = m;
    stats[bc * 2 + 1] = rsqrtf(var + 1e-5f);
  }
}

// ---- fused: transpose + IN + relu + LN + in-proj MFMA -> xf_b, xin_b, sz_b=silu(z) ----
__global__ __launch_bounds__(256) void k_fusein(const float* __restrict__ p,
                                                const float* __restrict__ stats,
                                                const float* __restrict__ g,
                                                const float* __restrict__ be,
                                                const unsigned short* __restrict__ w_b,
                                                unsigned short* __restrict__ xf_b,
                                                unsigned short* __restrict__ xin_b,
                                                unsigned short* __restrict__ sz_b) {
  int b = blockIdx.x / NT;
  int l0 = (blockIdx.x % NT) * 64;
  __shared__ float T[64][65];
  __shared__ unsigned short Tb[64][72];
  int li = threadIdx.x & 63;
  int c0 = threadIdx.x >> 6;
  #pragma unroll
  for (int j = 0; j < 16; ++j) {
    int c = c0 * 16 + j;
    float m = stats[(b * CC + c) * 2];
    float rs = stats[(b * CC + c) * 2 + 1];
    float v = p[((size_t)(b * CC + c)) * LL + l0 + li];
    T[li][c] = fmaxf((v - m) * rs, 0.f);
  }
  __syncthreads();
  // LN: 4 threads per row, each sums 16 channels; combine via 2 shfl_xor
  {
    int row = threadIdx.x >> 2, part = threadIdx.x & 3;
    int ch0 = part * 16;
    float s = 0.f, s2 = 0.f;
    #pragma unroll
    for (int j = 0; j < 16; ++j) {
      float v = T[row][ch0 + j];
      s += v; s2 += v * v;
    }
    s += __shfl_xor(s, 1); s2 += __shfl_xor(s2, 1);
    s += __shfl_xor(s, 2); s2 += __shfl_xor(s2, 2);
    float m = s * (1.f / 64.f);
    float var = s2 * (1.f / 64.f) - m * m;
    float rs = rsqrtf(var + 1e-5f);
    size_t off0 = ((size_t)b * LL + l0 + row) * CC + ch0;
    #pragma unroll
    for (int j4 = 0; j4 < 4; ++j4) {
      float4 v4 = *(float4*)&T[row][ch0 + j4 * 4];
      xf_b[off0 + j4 * 4 + 0] = f2b(v4.x);
      xf_b[off0 + j4 * 4 + 1] = f2b(v4.y);
      xf_b[off0 + j4 * 4 + 2] = f2b(v4.z);
      xf_b[off0 + j4 * 4 + 3] = f2b(v4.w);
      float4 g4 = *(const float4*)&g[ch0 + j4 * 4];
      float4 b4 = *(const float4*)&be[ch0 + j4 * 4];
      Tb[row][ch0 + j4 * 4 + 0] = f2b((v4.x - m) * rs * g4.x + b4.x);
      Tb[row][ch0 + j4 * 4 + 1] = f2b((v4.y - m) * rs * g4.y + b4.y);
      Tb[row][ch0 + j4 * 4 + 2] = f2b((v4.z - m) * rs * g4.z + b4.z);
      Tb[row][ch0 + j4 * 4 + 3] = f2b((v4.w - m) * rs * g4.w + b4.w);
    }
  }
  __syncthreads();
  int lane = threadIdx.x & 63;
  int wv = threadIdx.x >> 6;
  int lr = lane & 15, kg = lane >> 4;
  int m0 = wv * 16;
  int rowg0 = blockIdx.x * 64 + m0;
  bf16x8 a0 = *(const bf16x8*)&Tb[m0 + lr][kg * 8];
  bf16x8 a1 = *(const bf16x8*)&Tb[m0 + lr][32 + kg * 8];
  #pragma unroll
  for (int nt = 0; nt < 16; ++nt) {
    bf16x8 b0 = *(const bf16x8*)&w_b[(size_t)(nt * 16 + lr) * CC + kg * 8];
    bf16x8 b1 = *(const bf16x8*)&w_b[(size_t)(nt * 16 + lr) * CC + 32 + kg * 8];
    fx4 c = {0.f, 0.f, 0.f, 0.f};
    c = MFMA16(a0, b0, c, 0, 0, 0);
    c = MFMA16(a1, b1, c, 0, 0, 0);
    #pragma unroll
    for (int r = 0; r < 4; ++r) {
      int row = rowg0 + kg * 4 + r, col = nt * 16 + lr;
      if (col < 128) xin_b[(size_t)row * DI + col] = f2b(c[r]);
      else           sz_b[(size_t)row * DI + col - 128] = f2b(silu_f(c[r]));
    }
  }
}

// ---- scanAX: split-K x-proj MFMA (conv once) + local scan; emits dblC, dts, hl,
//      y1b = bf16(C.h_local + D*xc), dtpreG ----
__global__ __launch_bounds__(128) void k_scanAX(const unsigned short* __restrict__ xin_b,
                                                const float* __restrict__ cw,
                                                const float* __restrict__ cb,
                                                const unsigned short* __restrict__ xpw_b,
                                                const float* __restrict__ Alog,
                                                const float* __restrict__ dtw,
                                                const float* __restrict__ dtbp,
                                                const float* __restrict__ Dp,
                                                float* __restrict__ dblC,
                                                float* __restrict__ dts,
                                                float* __restrict__ hl,
                                                unsigned short* __restrict__ y1b,
                                                float* __restrict__ dtpreG) {
  int g = blockIdx.x % GCH;
  int b = blockIdx.x / GCH;
  __shared__ float dblP[2][16][40];
  __shared__ unsigned short xcS[16][136];
  int wv = threadIdx.x >> 6, lane = threadIdx.x & 63;
  int lr = lane & 15, kg = lane >> 4;
  {
    int lloc = g * LCH + lr;
    size_t row = (size_t)b * LL + lloc;
    const bf16x8 zv8 = {0, 0, 0, 0, 0, 0, 0, 0};
    fx4 acc[3];
    #pragma unroll
    for (int nt = 0; nt < 3; ++nt) acc[nt] = (fx4){0.f, 0.f, 0.f, 0.f};
    #pragma unroll
    for (int kk = 0; kk < 2; ++kk) {
      int cbase = (wv * 2 + kk) * 32 + kg * 8;
      bf16x8 x3 = *(const bf16x8*)&xin_b[row * DI + cbase];
      bf16x8 x2 = (lloc >= 1) ? *(const bf16x8*)&xin_b[(row - 1) * DI + cbase] : zv8;
      bf16x8 x1 = (lloc >= 2) ? *(const bf16x8*)&xin_b[(row - 2) * DI + cbase] : zv8;
      bf16x8 x0 = (lloc >= 3) ? *(const bf16x8*)&xin_b[(row - 3) * DI + cbase] : zv8;
      bf16x8 a;
      #pragma unroll
      for (int e = 0; e < 8; ++e) {
        int dd = cbase + e;
        float4 w4 = *(const float4*)&cw[dd * 4];
        float v = cb[dd] + b2f((unsigned short)x0[e]) * w4.x + b2f((unsigned short)x1[e]) * w4.y
                + b2f((unsigned short)x2[e]) * w4.z + b2f((unsigned short)x3[e]) * w4.w;
        a[e] = (short)f2b(silu_f(v));
      }
      *(bf16x8*)&xcS[lr][cbase] = a;
      #pragma unroll
      for (int nt = 0; nt < 3; ++nt) {
        bf16x8 bfr = *(const bf16x8*)&xpw_b[(size_t)(nt * 16 + lr) * DI + cbase];
        acc[nt] = MFMA16(a, bfr, acc[nt], 0, 0, 0);
      }
    }
    #pragma unroll
    for (int nt = 0; nt < 3; ++nt)
      #pragma unroll
      for (int r = 0; r < 4; ++r) {
        int col = nt * 16 + lr;
        if (col < 36) dblP[wv][kg * 4 + r][col] = acc[nt][r];
      }
  }
  __syncthreads();
  // sum split-K partials into dblP[0]
  for (int e = threadIdx.x; e < 576; e += 128) {
    int r = e / 36, c = e - r * 36;
    dblP[0][r][c] += dblP[1][r][c];
  }
  __syncthreads();
  // write C cols to global (coalesced)
  {
    size_t cbase16 = ((size_t)b * LL + g * LCH) * 16;
    #pragma unroll
    for (int j = 0; j < 2; ++j) {
      int e = threadIdx.x + 128 * j;   // < 256
      dblC[cbase16 + e] = dblP[0][e >> 4][20 + (e & 15)];
    }
  }
  // local scan per d (xc from LDS); emit y1 = C.h_local + D*xc (bf16), dtpre
  int d = threadIdx.x;
  float A0 = -__expf(Alog[d * NS]);
  bool afast = true;
  #pragma unroll
  for (int n = 1; n < 16; ++n) {
    float An = -__expf(Alog[d * NS + n]);
    afast = afast && (fabsf(An - A0 * (float)(n + 1)) <= 1e-3f * (float)(n + 1) * fabsf(A0));
  }
  bool aone = afast && (A0 == -1.0f);
  float4 w4 = *(const float4*)&dtw[d * 4];
  float dtbv = dtbp[d];
  float Dv = Dp[d];
  float h[16];
  #pragma unroll
  for (int n = 0; n < 16; ++n) h[n] = 0.f;
  float dtsum = 0.f;
  size_t sbase = ((size_t)b * LL + g * LCH) * DI + d;
  #pragma unroll 4
  for (int l = 0; l < LCH; ++l) {
    float xcv = b2f(xcS[l][d]);
    float4 qv = *(float4*)&dblP[0][l][0];
    float v = dtbv + qv.x * w4.x + qv.y * w4.y + qv.z * w4.z + qv.w * w4.w;
    float a[16];
    float dtv = dt_and_a(v, A0, aone, afast, Alog, d, a);
    float dx = dtv * xcv;
    dtsum += dtv;
    float4 b0 = *(float4*)&dblP[0][l][4];
    float4 b1 = *(float4*)&dblP[0][l][8];
    float4 b2 = *(float4*)&dblP[0][l][12];
    float4 b3 = *(float4*)&dblP[0][l][16];
    h[0]  = a[0]  * h[0]  + dx * b0.x;  h[1]  = a[1]  * h[1]  + dx * b0.y;
    h[2]  = a[2]  * h[2]  + dx * b0.z;  h[3]  = a[3]  * h[3]  + dx * b0.w;
    h[4]  = a[4]  * h[4]  + dx * b1.x;  h[5]  = a[5]  * h[5]  + dx * b1.y;
    h[6]  = a[6]  * h[6]  + dx * b1.z;  h[7]  = a[7]  * h[7]  + dx * b1.w;
    h[8]  = a[8]  * h[8]  + dx * b2.x;  h[9]  = a[9]  * h[9]  + dx * b2.y;
    h[10] = a[10] * h[10] + dx * b2.z;  h[11] = a[11] * h[11] + dx * b2.w;
    h[12] = a[12] * h[12] + dx * b3.x;  h[13] = a[13] * h[13] + dx * b3.y;
    h[14] = a[14] * h[14] + dx * b3.z;  h[15] = a[15] * h[15] + dx * b3.w;
    float4 cc0 = *(float4*)&dblP[0][l][20];
    float4 cc1 = *(float4*)&dblP[0][l][24];
    float4 cc2 = *(float4*)&dblP[0][l][28];
    float4 cc3 = *(float4*)&dblP[0][l][32];
    float y0 = h[0] * cc0.x + h[1] * cc0.y + h[2] * cc0.z + h[3] * cc0.w;
    float y1 = h[4] * cc1.x + h[5] * cc1.y + h[6] * cc1.z + h[7] * cc1.w;
    float y2 = h[8] * cc2.x + h[9] * cc2.y + h[10] * cc2.z + h[11] * cc2.w;
    float y3 = h[12] * cc3.x + h[13] * cc3.y + h[14] * cc3.z + h[15] * cc3.w;
    y1b[sbase + (size_t)l * DI] = f2b((y0 + y1) + (y2 + y3) + Dv * xcv);
    dtpreG[sbase + (size_t)l * DI] = dtsum;
  }
  dts[(size_t)g * SD + b * DI + d] = dtsum;
  size_t o = (size_t)g * NSEQ + ((size_t)b * DI + d) * NS;
  #pragma unroll
  for (int j = 0; j < 4; ++j)
    *(float4*)&hl[o + j * 4] = make_float4(h[j * 4], h[j * 4 + 1], h[j * 4 + 2], h[j * 4 + 3]);
}

// ---- scan2a: per-group aggregates (a recomputed from dtsum — exact) ----
__global__ __launch_bounds__(256) void k_scan2a(const float* __restrict__ dts,
                                                const float* __restrict__ hl,
                                                const float* __restrict__ Alog,
                                                float* __restrict__ gap,
                                                float* __restrict__ ghl) {
  int t = blockIdx.x * 256 + threadIdx.x;   // < NG*NSEQ
  int grp = t >> 13, seq = t & (NSEQ - 1);
  int sd = seq >> 4;
  float An = -__expf(Alog[seq & (DI * NS - 1)]);
  float A = 1.f, H = 0.f;
  int c0 = grp * GS;
  #pragma unroll 4
  for (int c = 0; c < GS; ++c) {
    float a = __expf(An * dts[(size_t)(c0 + c) * SD + sd]);
    H = a * H + hl[(size_t)(c0 + c) * NSEQ + seq];
    A *= a;
  }
  gap[t] = A;
  ghl[t] = H;
}

// ---- scan2bc: redundant group-prefix + chunk carries ----
__global__ __launch_bounds__(256) void k_scan2bc(const float* __restrict__ dts,
                                                 const float* __restrict__ hl,
                                                 const float* __restrict__ gap,
                                                 const float* __restrict__ ghl,
                                                 const float* __restrict__ Alog,
                                                 float* __restrict__ hi) {
  int t = blockIdx.x * 256 + threadIdx.x;   // < NG*NSEQ
  int grp = t >> 13, seq = t & (NSEQ - 1);
  int sd = seq >> 4;
  float An = -__expf(Alog[seq & (DI * NS - 1)]);
  float h = 0.f;
  for (int gg = 0; gg < grp; ++gg)
    h = gap[gg * NSEQ + seq] * h + ghl[gg * NSEQ + seq];
  int c0 = grp * GS;
  #pragma unroll 4
  for (int c = 0; c < GS; ++c) {
    float a = __expf(An * dts[(size_t)(c0 + c) * SD + sd]);
    hi[(size_t)(c0 + c) * NSEQ + seq] = h;
    h = a * h + hl[(size_t)(c0 + c) * NSEQ + seq];
  }
}

// ---- scanCO: y = y1 + C.diag(exp(A dtpre)).hi; *silu(z); out/pr-proj (no serial scan) ----
__global__ __launch_bounds__(128) void k_scanCO(const float* __restrict__ dblC,
                                                const unsigned short* __restrict__ sz_b,
                                                const unsigned short* __restrict__ y1b,
                                                const float* __restrict__ dtpreG,
                                                const float* __restrict__ Alog,
                                                const float* __restrict__ hi,
                                                const unsigned short* __restrict__ ow_b,
                                                const unsigned short* __restrict__ xf_b,
                                                const float* __restrict__ skipv,
                                                const unsigned short* __restrict__ pw_b,
                                                const float* __restrict__ pb,
                                                const float* __restrict__ ident,
                                                float* __restrict__ dst, int addid) {
  int g = blockIdx.x % GCH;
  int b = blockIdx.x / GCH;
  int d = threadIdx.x;
  __shared__ float Cms[LCH * NS];
  __shared__ unsigned short yS[16][136];
  __shared__ unsigned short tmpS[16][72];
  {
    int tid = threadIdx.x;
    size_t cb16 = ((size_t)b * LL + g * LCH) * 16;
    if (tid < 64) *(float4*)&Cms[tid * 4] = *(const float4*)&dblC[cb16 + tid * 4];
  }
  float A0 = -__expf(Alog[d * NS]);
  bool afast = true;
  #pragma unroll
  for (int n = 1; n < 16; ++n) {
    float An = -__expf(Alog[d * NS + n]);
    afast = afast && (fabsf(An - A0 * (float)(n + 1)) <= 1e-3f * (float)(n + 1) * fabsf(A0));
  }
  __syncthreads();
  size_t o = (size_t)g * NSEQ + ((size_t)b * DI + d) * NS;
  float hiR[16];
  #pragma unroll
  for (int j = 0; j < 4; ++j) {
    float4 hv = *(const float4*)&hi[o + j * 4];
    hiR[j * 4 + 0] = hv.x; hiR[j * 4 + 1] = hv.y; hiR[j * 4 + 2] = hv.z; hiR[j * 4 + 3] = hv.w;
  }
  size_t base = ((size_t)b * LL + g * LCH) * DI + d;
  #pragma unroll 4
  for (int l = 0; l < LCH; ++l) {
    float dtpre = dtpreG[base + (size_t)l * DI];
    float y1v = b2f(y1b[base + (size_t)l * DI]);
    float sg = b2f(sz_b[base + (size_t)l * DI]);
    float pw[16];
    if (afast) {
      powers16(__expf(A0 * dtpre), pw);
    } else {
      #pragma unroll
      for (int n = 0; n < 16; ++n) pw[n] = __expf(-__expf(Alog[d * NS + n]) * dtpre);
    }
    float4 c0 = *(float4*)&Cms[l * 16];
    float4 c1 = *(float4*)&Cms[l * 16 + 4];
    float4 c2 = *(float4*)&Cms[l * 16 + 8];
    float4 c3 = *(float4*)&Cms[l * 16 + 12];
    float s0 = c0.x * pw[0] * hiR[0] + c0.y * pw[1] * hiR[1] + c0.z * pw[2] * hiR[2] + c0.w * pw[3] * hiR[3];
    float s1 = c1.x * pw[4] * hiR[4] + c1.y * pw[5] * hiR[5] + c1.z * pw[6] * hiR[6] + c1.w * pw[7] * hiR[7];
    float s2 = c2.x * pw[8] * hiR[8] + c2.y * pw[9] * hiR[9] + c2.z * pw[10] * hiR[10] + c2.w * pw[11] * hiR[11];
    float s3 = c3.x * pw[12] * hiR[12] + c3.y * pw[13] * hiR[13] + c3.z * pw[14] * hiR[14] + c3.w * pw[15] * hiR[15];
    float yv = y1v + ((s0 + s1) + (s2 + s3));
    yS[l][d] = f2b(yv * sg);
  }
  __syncthreads();
  // phase O: out-proj, full-K; wave lw computes output cols lw*32 .. lw*32+31
  int lane = threadIdx.x & 63;
  int lr = lane & 15, kg = lane >> 4;
  int lw = threadIdx.x >> 6;
  {
    fx4 oacc[2];
    oacc[0] = (fx4){0.f, 0.f, 0.f, 0.f};
    oacc[1] = (fx4){0.f, 0.f, 0.f, 0.f};
    #pragma unroll
    for (int ks = 0; ks < 4; ++ks) {
      int cbase = ks * 32 + kg * 8;
      bf16x8 a = *(const bf16x8*)&yS[lr][cbase];
      #pragma unroll
      for (int j = 0; j < 2; ++j) {
        int nt = lw * 2 + j;
        bf16x8 bfr = *(const bf16x8*)&ow_b[(size_t)(nt * 16 + lr) * DI + cbase];
        oacc[j] = MFMA16(a, bfr, oacc[j], 0, 0, 0);
      }
    }
    float sk = skipv[0];
    #pragma unroll
    for (int j = 0; j < 2; ++j) {
      int nt = lw * 2 + j;
      #pragma unroll
      for (int r = 0; r < 4; ++r) {
        int rowl = kg * 4 + r, col = nt * 16 + lr;
        size_t grow = (size_t)b * LL + g * LCH + rowl;
        tmpS[rowl][col] = f2b(oacc[j][r] + sk * b2f(xf_b[grow * CC + col]));
      }
    }
  }
  __syncthreads();
  // phase P: pr-proj, full-K; wave lw computes output channels lw*32 .. lw*32+31
  {
    fx4 pacc[2];
    pacc[0] = (fx4){0.f, 0.f, 0.f, 0.f};
    pacc[1] = (fx4){0.f, 0.f, 0.f, 0.f};
    #pragma unroll
    for (int ks = 0; ks < 2; ++ks) {
      int cbase = ks * 32 + kg * 8;
      bf16x8 bfrag = *(const bf16x8*)&tmpS[lr][cbase];
      #pragma unroll
      for (int j = 0; j < 2; ++j) {
        int ct = lw * 2 + j;
        bf16x8 a = *(const bf16x8*)&pw_b[(size_t)(ct * 16 + lr) * CC + cbase];
        pacc[j] = MFMA16(a, bfrag, pacc[j], 0, 0, 0);
      }
    }
    #pragma unroll
    for (int j = 0; j < 2; ++j) {
      int ct = lw * 2 + j;
      #pragma unroll
      for (int r = 0; r < 4; ++r) {
        int c = ct * 16 + kg * 4 + r;
        int lpos = g * LCH + lr;
        size_t off = ((size_t)(b * CC + c)) * LL + lpos;
        float val = pacc[j][r] + pb[c];
        if (addid) val += ident[off];
        dst[off] = val;
      }
    }
  }
}

extern "C" void kernel_launch(void* const* d_in, const int* in_sizes, int n_in,
                              void* d_out, int out_size, void* d_ws, size_t ws_size,
                              hipStream_t stream) {
  const float* x = (const float*)d_in[0];
  float* ws = (float*)d_ws;
  float* stats = ws;                                        //     1024 floats
  unsigned short* xf_b  = (unsigned short*)(ws + 1024);     //  2359296 shorts (1179648 f)
  unsigned short* xin_b = (unsigned short*)(ws + 1180672);  //  4718592 shorts (2359296 f)
  unsigned short* sz_b  = (unsigned short*)(ws + 3539968);  //  4718592 shorts (2359296 f)
  float* dblC  = ws + 5899264;                              //   589824 f
  float* dts   = ws + 6489088;                              //   294912 f
  float* hl    = ws + 6784000;                              //  4718592 f (dead after scan2bc -> inter)
  float* hi    = ws + 11502592;                             //  4718592 f
  float* gap   = ws + 16221184;                             //   196608 f
  float* ghl   = ws + 16417792;                             //   196608 f
  unsigned short* wb = (unsigned short*)(ws + 16614400);    //    69632 shorts (34816 f)
  unsigned short* y1b = (unsigned short*)(ws + 16649216);   //  4718592 shorts (2359296 f)
  float* dtpreG = ws + 19008512;                            //  4718592 f
  float* inter = hl;   // hl dead after k_scan2bc; scanCO(L0) writes it; L1 consumes it
                       // in stats/fusein BEFORE scanAX(L1) rewrites hl.
  float* outp  = (float*)d_out;

  k_cvt<<<272, 256, 0, stream>>>((const float*)d_in[3], (const float*)d_in[6],
                                 (const float*)d_in[11], (const float*)d_in[13],
                                 (const float*)d_in[17], (const float*)d_in[20],
                                 (const float*)d_in[25], (const float*)d_in[27], wb);

  const float* cur = x;
  for (int layer = 0; layer < 2; ++layer) {
    const int p0 = 1 + 14 * layer;
    const float* ln_g   = (const float*)d_in[p0 + 0];
    const float* ln_b   = (const float*)d_in[p0 + 1];
    const float* conv_w = (const float*)d_in[p0 + 3];
    const float* conv_b = (const float*)d_in[p0 + 4];
    const float* dt_w   = (const float*)d_in[p0 + 6];
    const float* dt_b   = (const float*)d_in[p0 + 7];
    const float* A_log  = (const float*)d_in[p0 + 8];
    const float* Dp     = (const float*)d_in[p0 + 9];
    const float* skip   = (const float*)d_in[p0 + 11];
    const float* pr_b   = (const float*)d_in[p0 + 13];
    const unsigned short* inw_b = wb + (size_t)layer * 34816;
    const unsigned short* xpw_b = inw_b + 16384;
    const unsigned short* ow_b  = inw_b + 22528;
    const unsigned short* pw_b  = inw_b + 30720;
    float* dst = (layer == 0) ? inter : outp;

    k_stats  <<<BB * CC, 256, 0, stream>>>(cur, stats);
    k_fusein <<<BB * NT, 256, 0, stream>>>(cur, stats, ln_g, ln_b, inw_b, xf_b, xin_b, sz_b);
    k_scanAX <<<BB * GCH, 128, 0, stream>>>(xin_b, conv_w, conv_b, xpw_b, A_log,
                                            dt_w, dt_b, Dp, dblC, dts, hl, y1b, dtpreG);
    k_scan2a <<<(NG * NSEQ) / 256, 256, 0, stream>>>(dts, hl, A_log, gap, ghl);
    k_scan2bc<<<(NG * NSEQ) / 256, 256, 0, stream>>>(dts, hl, gap, ghl, A_log, hi);
    k_scanCO <<<BB * GCH, 128, 0, stream>>>(dblC, sz_b, y1b, dtpreG, A_log, hi, ow_b,
                                            xf_b, skip, pw_b, pr_b, x, dst, layer);
    cur = inter;
  }
}

// Round 15
// 210.276 us; speedup vs baseline: 1.2910x; 1.0622x over previous
//
#include <hip/hip_runtime.h>
#include <math.h>

#define BB 4
#define CC 64
#define DI 128
#define NS 16
#define LL 9216
#define NT (LL / 64)

// scan decomposition
#define GCH 576
#define LCH 16
#define NSEQ 8192      // B*DI*NS
#define SD  512        // B*DI
#define NG 24
#define GS 24          // NG*GS == GCH

typedef __attribute__((ext_vector_type(8))) short bf16x8;
typedef __attribute__((ext_vector_type(4))) float fx4;
#define MFMA16 __builtin_amdgcn_mfma_f32_16x16x32_bf16

static __device__ __forceinline__ unsigned short f2b(float f) {
  unsigned u = __float_as_uint(f);
  u += 0x7fffu + ((u >> 16) & 1u);
  return (unsigned short)(u >> 16);
}
static __device__ __forceinline__ float b2f(unsigned short s) {
  return __uint_as_float(((unsigned)s) << 16);
}
static __device__ __forceinline__ float silu_f(float x) {
  return x / (1.f + __expf(-x));
}

// powers of e1: a[n] = e1^(n+1)
static __device__ __forceinline__ void powers16(float e1, float* a) {
  float p2 = e1 * e1, p4 = p2 * p2, p8 = p4 * p4;
  a[0] = e1;      a[1] = p2;      a[2] = p2 * e1;      a[3] = p4;
  a[4] = p4 * e1; a[5] = p4 * p2; a[6] = p4 * p2 * e1; a[7] = p8;
  a[8] = p8 * e1; a[9] = p8 * p2; a[10] = p8 * p2 * e1; a[11] = p8 * p4;
  a[12] = p8 * p4 * e1; a[13] = p8 * p4 * p2; a[14] = p8 * p4 * p2 * e1; a[15] = p8 * p8;
}

// dtv = softplus(v); a[16] decay factors. aone: A0==-1 -> e1=sigmoid(-v) free.
static __device__ __forceinline__ float dt_and_a(float v, float A0, bool aone, bool afast,
                                                 const float* __restrict__ Alog, int d,
                                                 float* a) {
  float em = __expf(-fabsf(v));
  float t = 1.f + em;
  float dtv = fmaxf(v, 0.f) + __logf(t);
  if (aone) {
    float e1 = ((v >= 0.f) ? em : 1.f) / t;   // == exp(-dtv)
    powers16(e1, a);
  } else if (afast) {
    powers16(__expf(dtv * A0), a);
  } else {
    #pragma unroll
    for (int n = 0; n < 16; ++n) a[n] = __expf(dtv * -__expf(Alog[d * NS + n]));
  }
  return dtv;
}

// ---------------- weight bf16 conversion (once) ----------------
__global__ __launch_bounds__(256) void k_cvt(const float* __restrict__ inw1, const float* __restrict__ xpw1,
                                             const float* __restrict__ ow1, const float* __restrict__ pw1,
                                             const float* __restrict__ inw2, const float* __restrict__ xpw2,
                                             const float* __restrict__ ow2, const float* __restrict__ pw2,
                                             unsigned short* __restrict__ wb) {
  int idx = blockIdx.x * 256 + threadIdx.x;   // < 69632
  int layer = idx >= 34816;
  int e = idx - layer * 34816;
  const float* inw = layer ? inw2 : inw1;
  const float* xpw = layer ? xpw2 : xpw1;
  const float* ow = layer ? ow2 : ow1;
  const float* pw = layer ? pw2 : pw1;
  float v;
  if (e < 16384) v = inw[e];
  else if (e < 22528) { int t = e - 16384; int r = t >> 7, c = t & 127; v = (r < 36) ? xpw[r * 128 + c] : 0.f; }
  else if (e < 30720) v = ow[e - 22528];
  else v = pw[e - 30720];
  wb[idx] = f2b(v);
}

// ---------------- instance-norm moments per (b,c) ----------------
__global__ __launch_bounds__(256) void k_stats(const float* __restrict__ p,
                                               float* __restrict__ stats) {
  int bc = blockIdx.x;
  const float* row = p + (size_t)bc * LL;
  float s = 0.f, s2 = 0.f;
  for (int i = threadIdx.x; i < LL; i += 256) {
    float v = row[i];
    s += v; s2 += v * v;
  }
  #pragma unroll
  for (int o = 32; o > 0; o >>= 1) {
    s += __shfl_down(s, o);
    s2 += __shfl_down(s2, o);
  }
  __shared__ float red[8];
  int w = threadIdx.x >> 6;
  if ((threadIdx.x & 63) == 0) { red[w] = s; red[4 + w] = s2; }
  __syncthreads();
  if (threadIdx.x == 0) {
    float S = red[0] + red[1] + red[2] + red[3];
    float S2 = red[4] + red[5] + red[6] + red[7];
    float m = S * (1.f / LL);
    float var = S2 * (1.f / LL) - m * m;
    stats[bc * 2] = m;
    stats[bc * 2 + 1] = rsqrtf(var + 1e-5f);
  }
}

// ---- fused: transpose + IN + relu + LN + in-proj MFMA -> xf_b, xin_b, sz_b=silu(z) ----
__global__ __launch_bounds__(256) void k_fusein(const float* __restrict__ p,
                                                const float* __restrict__ stats,
                                                const float* __restrict__ g,
                                                const float* __restrict__ be,
                                                const unsigned short* __restrict__ w_b,
                                                unsigned short* __restrict__ xf_b,
                                                unsigned short* __restrict__ xin_b,
                                                unsigned short* __restrict__ sz_b) {
  int b = blockIdx.x / NT;
  int l0 = (blockIdx.x % NT) * 64;
  __shared__ float T[64][65];
  __shared__ unsigned short Tb[64][72];
  int li = threadIdx.x & 63;
  int c0 = threadIdx.x >> 6;
  #pragma unroll
  for (int j = 0; j < 16; ++j) {
    int c = c0 * 16 + j;
    float m = stats[(b * CC + c) * 2];
    float rs = stats[(b * CC + c) * 2 + 1];
    float v = p[((size_t)(b * CC + c)) * LL + l0 + li];
    T[li][c] = fmaxf((v - m) * rs, 0.f);
  }
  __syncthreads();
  // LN: 4 threads per row, each sums 16 channels; combine via 2 shfl_xor
  {
    int row = threadIdx.x >> 2, part = threadIdx.x & 3;
    int ch0 = part * 16;
    float s = 0.f, s2 = 0.f;
    #pragma unroll
    for (int j = 0; j < 16; ++j) {
      float v = T[row][ch0 + j];
      s += v; s2 += v * v;
    }
    s += __shfl_xor(s, 1); s2 += __shfl_xor(s2, 1);
    s += __shfl_xor(s, 2); s2 += __shfl_xor(s2, 2);
    float m = s * (1.f / 64.f);
    float var = s2 * (1.f / 64.f) - m * m;
    float rs = rsqrtf(var + 1e-5f);
    size_t off0 = ((size_t)b * LL + l0 + row) * CC + ch0;
    #pragma unroll
    for (int j4 = 0; j4 < 4; ++j4) {
      float4 v4 = *(float4*)&T[row][ch0 + j4 * 4];
      xf_b[off0 + j4 * 4 + 0] = f2b(v4.x);
      xf_b[off0 + j4 * 4 + 1] = f2b(v4.y);
      xf_b[off0 + j4 * 4 + 2] = f2b(v4.z);
      xf_b[off0 + j4 * 4 + 3] = f2b(v4.w);
      float4 g4 = *(const float4*)&g[ch0 + j4 * 4];
      float4 b4 = *(const float4*)&be[ch0 + j4 * 4];
      Tb[row][ch0 + j4 * 4 + 0] = f2b((v4.x - m) * rs * g4.x + b4.x);
      Tb[row][ch0 + j4 * 4 + 1] = f2b((v4.y - m) * rs * g4.y + b4.y);
      Tb[row][ch0 + j4 * 4 + 2] = f2b((v4.z - m) * rs * g4.z + b4.z);
      Tb[row][ch0 + j4 * 4 + 3] = f2b((v4.w - m) * rs * g4.w + b4.w);
    }
  }
  __syncthreads();
  int lane = threadIdx.x & 63;
  int wv = threadIdx.x >> 6;
  int lr = lane & 15, kg = lane >> 4;
  int m0 = wv * 16;
  int rowg0 = blockIdx.x * 64 + m0;
  bf16x8 a0 = *(const bf16x8*)&Tb[m0 + lr][kg * 8];
  bf16x8 a1 = *(const bf16x8*)&Tb[m0 + lr][32 + kg * 8];
  #pragma unroll
  for (int nt = 0; nt < 16; ++nt) {
    bf16x8 b0 = *(const bf16x8*)&w_b[(size_t)(nt * 16 + lr) * CC + kg * 8];
    bf16x8 b1 = *(const bf16x8*)&w_b[(size_t)(nt * 16 + lr) * CC + 32 + kg * 8];
    fx4 c = {0.f, 0.f, 0.f, 0.f};
    c = MFMA16(a0, b0, c, 0, 0, 0);
    c = MFMA16(a1, b1, c, 0, 0, 0);
    #pragma unroll
    for (int r = 0; r < 4; ++r) {
      int row = rowg0 + kg * 4 + r, col = nt * 16 + lr;
      if (col < 128) xin_b[(size_t)row * DI + col] = f2b(c[r]);
      else           sz_b[(size_t)row * DI + col - 128] = f2b(silu_f(c[r]));
    }
  }
}

// ---- scanAX: split-K x-proj MFMA (conv once) + local scan; emits dblC, dts,
//      hlb (bf16), y1b = bf16(C.h_local + D*xc), dtpreb (bf16) ----
__global__ __launch_bounds__(128) void k_scanAX(const unsigned short* __restrict__ xin_b,
                                                const float* __restrict__ cw,
                                                const float* __restrict__ cb,
                                                const unsigned short* __restrict__ xpw_b,
                                                const float* __restrict__ Alog,
                                                const float* __restrict__ dtw,
                                                const float* __restrict__ dtbp,
                                                const float* __restrict__ Dp,
                                                float* __restrict__ dblC,
                                                float* __restrict__ dts,
                                                unsigned short* __restrict__ hlb,
                                                unsigned short* __restrict__ y1b,
                                                unsigned short* __restrict__ dtpreb) {
  int g = blockIdx.x % GCH;
  int b = blockIdx.x / GCH;
  __shared__ float dblP[2][16][40];
  __shared__ unsigned short xcS[16][136];
  int wv = threadIdx.x >> 6, lane = threadIdx.x & 63;
  int lr = lane & 15, kg = lane >> 4;
  {
    int lloc = g * LCH + lr;
    size_t row = (size_t)b * LL + lloc;
    const bf16x8 zv8 = {0, 0, 0, 0, 0, 0, 0, 0};
    fx4 acc[3];
    #pragma unroll
    for (int nt = 0; nt < 3; ++nt) acc[nt] = (fx4){0.f, 0.f, 0.f, 0.f};
    #pragma unroll
    for (int kk = 0; kk < 2; ++kk) {
      int cbase = (wv * 2 + kk) * 32 + kg * 8;
      bf16x8 x3 = *(const bf16x8*)&xin_b[row * DI + cbase];
      bf16x8 x2 = (lloc >= 1) ? *(const bf16x8*)&xin_b[(row - 1) * DI + cbase] : zv8;
      bf16x8 x1 = (lloc >= 2) ? *(const bf16x8*)&xin_b[(row - 2) * DI + cbase] : zv8;
      bf16x8 x0 = (lloc >= 3) ? *(const bf16x8*)&xin_b[(row - 3) * DI + cbase] : zv8;
      bf16x8 a;
      #pragma unroll
      for (int e = 0; e < 8; ++e) {
        int dd = cbase + e;
        float4 w4 = *(const float4*)&cw[dd * 4];
        float v = cb[dd] + b2f((unsigned short)x0[e]) * w4.x + b2f((unsigned short)x1[e]) * w4.y
                + b2f((unsigned short)x2[e]) * w4.z + b2f((unsigned short)x3[e]) * w4.w;
        a[e] = (short)f2b(silu_f(v));
      }
      *(bf16x8*)&xcS[lr][cbase] = a;
      #pragma unroll
      for (int nt = 0; nt < 3; ++nt) {
        bf16x8 bfr = *(const bf16x8*)&xpw_b[(size_t)(nt * 16 + lr) * DI + cbase];
        acc[nt] = MFMA16(a, bfr, acc[nt], 0, 0, 0);
      }
    }
    #pragma unroll
    for (int nt = 0; nt < 3; ++nt)
      #pragma unroll
      for (int r = 0; r < 4; ++r) {
        int col = nt * 16 + lr;
        if (col < 36) dblP[wv][kg * 4 + r][col] = acc[nt][r];
      }
  }
  __syncthreads();
  // sum split-K partials into dblP[0]
  for (int e = threadIdx.x; e < 576; e += 128) {
    int r = e / 36, c = e - r * 36;
    dblP[0][r][c] += dblP[1][r][c];
  }
  __syncthreads();
  // write C cols to global (coalesced)
  {
    size_t cbase16 = ((size_t)b * LL + g * LCH) * 16;
    #pragma unroll
    for (int j = 0; j < 2; ++j) {
      int e = threadIdx.x + 128 * j;   // < 256
      dblC[cbase16 + e] = dblP[0][e >> 4][20 + (e & 15)];
    }
  }
  // local scan per d (xc from LDS); emit y1 = C.h_local + D*xc (bf16), dtpre (bf16)
  int d = threadIdx.x;
  float A0 = -__expf(Alog[d * NS]);
  bool afast = true;
  #pragma unroll
  for (int n = 1; n < 16; ++n) {
    float An = -__expf(Alog[d * NS + n]);
    afast = afast && (fabsf(An - A0 * (float)(n + 1)) <= 1e-3f * (float)(n + 1) * fabsf(A0));
  }
  bool aone = afast && (A0 == -1.0f);
  float4 w4 = *(const float4*)&dtw[d * 4];
  float dtbv = dtbp[d];
  float Dv = Dp[d];
  float h[16];
  #pragma unroll
  for (int n = 0; n < 16; ++n) h[n] = 0.f;
  float dtsum = 0.f;
  size_t sbase = ((size_t)b * LL + g * LCH) * DI + d;
  #pragma unroll 4
  for (int l = 0; l < LCH; ++l) {
    float xcv = b2f(xcS[l][d]);
    float4 qv = *(float4*)&dblP[0][l][0];
    float v = dtbv + qv.x * w4.x + qv.y * w4.y + qv.z * w4.z + qv.w * w4.w;
    float a[16];
    float dtv = dt_and_a(v, A0, aone, afast, Alog, d, a);
    float dx = dtv * xcv;
    dtsum += dtv;
    float4 b0 = *(float4*)&dblP[0][l][4];
    float4 b1 = *(float4*)&dblP[0][l][8];
    float4 b2 = *(float4*)&dblP[0][l][12];
    float4 b3 = *(float4*)&dblP[0][l][16];
    h[0]  = a[0]  * h[0]  + dx * b0.x;  h[1]  = a[1]  * h[1]  + dx * b0.y;
    h[2]  = a[2]  * h[2]  + dx * b0.z;  h[3]  = a[3]  * h[3]  + dx * b0.w;
    h[4]  = a[4]  * h[4]  + dx * b1.x;  h[5]  = a[5]  * h[5]  + dx * b1.y;
    h[6]  = a[6]  * h[6]  + dx * b1.z;  h[7]  = a[7]  * h[7]  + dx * b1.w;
    h[8]  = a[8]  * h[8]  + dx * b2.x;  h[9]  = a[9]  * h[9]  + dx * b2.y;
    h[10] = a[10] * h[10] + dx * b2.z;  h[11] = a[11] * h[11] + dx * b2.w;
    h[12] = a[12] * h[12] + dx * b3.x;  h[13] = a[13] * h[13] + dx * b3.y;
    h[14] = a[14] * h[14] + dx * b3.z;  h[15] = a[15] * h[15] + dx * b3.w;
    float4 cc0 = *(float4*)&dblP[0][l][20];
    float4 cc1 = *(float4*)&dblP[0][l][24];
    float4 cc2 = *(float4*)&dblP[0][l][28];
    float4 cc3 = *(float4*)&dblP[0][l][32];
    float y0 = h[0] * cc0.x + h[1] * cc0.y + h[2] * cc0.z + h[3] * cc0.w;
    float y1 = h[4] * cc1.x + h[5] * cc1.y + h[6] * cc1.z + h[7] * cc1.w;
    float y2 = h[8] * cc2.x + h[9] * cc2.y + h[10] * cc2.z + h[11] * cc2.w;
    float y3 = h[12] * cc3.x + h[13] * cc3.y + h[14] * cc3.z + h[15] * cc3.w;
    y1b[sbase + (size_t)l * DI] = f2b((y0 + y1) + (y2 + y3) + Dv * xcv);
    dtpreb[sbase + (size_t)l * DI] = f2b(dtsum);
  }
  dts[(size_t)g * SD + b * DI + d] = dtsum;
  size_t o = (size_t)g * NSEQ + ((size_t)b * DI + d) * NS;
  bf16x8 hv0, hv1;
  #pragma unroll
  for (int n = 0; n < 8; ++n) { hv0[n] = (short)f2b(h[n]); hv1[n] = (short)f2b(h[8 + n]); }
  *(bf16x8*)&hlb[o] = hv0;
  *(bf16x8*)&hlb[o + 8] = hv1;
}

// ---- scan2a: per-group aggregates (a recomputed from dtsum — exact) ----
__global__ __launch_bounds__(256) void k_scan2a(const float* __restrict__ dts,
                                                const unsigned short* __restrict__ hlb,
                                                const float* __restrict__ Alog,
                                                float* __restrict__ gap,
                                                float* __restrict__ ghl) {
  int t = blockIdx.x * 256 + threadIdx.x;   // < NG*NSEQ
  int grp = t >> 13, seq = t & (NSEQ - 1);
  int sd = seq >> 4;
  float An = -__expf(Alog[seq & (DI * NS - 1)]);
  float A = 1.f, H = 0.f;
  int c0 = grp * GS;
  #pragma unroll 4
  for (int c = 0; c < GS; ++c) {
    float a = __expf(An * dts[(size_t)(c0 + c) * SD + sd]);
    H = a * H + b2f(hlb[(size_t)(c0 + c) * NSEQ + seq]);
    A *= a;
  }
  gap[t] = A;
  ghl[t] = H;
}

// ---- scan2bc: redundant group-prefix + chunk carries (hi out bf16) ----
__global__ __launch_bounds__(256) void k_scan2bc(const float* __restrict__ dts,
                                                 const unsigned short* __restrict__ hlb,
                                                 const float* __restrict__ gap,
                                                 const float* __restrict__ ghl,
                                                 const float* __restrict__ Alog,
                                                 unsigned short* __restrict__ hib) {
  int t = blockIdx.x * 256 + threadIdx.x;   // < NG*NSEQ
  int grp = t >> 13, seq = t & (NSEQ - 1);
  int sd = seq >> 4;
  float An = -__expf(Alog[seq & (DI * NS - 1)]);
  float h = 0.f;
  for (int gg = 0; gg < grp; ++gg)
    h = gap[gg * NSEQ + seq] * h + ghl[gg * NSEQ + seq];
  int c0 = grp * GS;
  #pragma unroll 4
  for (int c = 0; c < GS; ++c) {
    float a = __expf(An * dts[(size_t)(c0 + c) * SD + sd]);
    hib[(size_t)(c0 + c) * NSEQ + seq] = f2b(h);
    h = a * h + b2f(hlb[(size_t)(c0 + c) * NSEQ + seq]);
  }
}

// ---- scanCO: y = y1 + C.diag(exp(A dtpre)).hi; *silu(z); out/pr-proj (no serial scan) ----
__global__ __launch_bounds__(128) void k_scanCO(const float* __restrict__ dblC,
                                                const unsigned short* __restrict__ sz_b,
                                                const unsigned short* __restrict__ y1b,
                                                const unsigned short* __restrict__ dtpreb,
                                                const float* __restrict__ Alog,
                                                const unsigned short* __restrict__ hib,
                                                const unsigned short* __restrict__ ow_b,
                                                const unsigned short* __restrict__ xf_b,
                                                const float* __restrict__ skipv,
                                                const unsigned short* __restrict__ pw_b,
                                                const float* __restrict__ pb,
                                                const float* __restrict__ ident,
                                                float* __restrict__ dst, int addid) {
  int g = blockIdx.x % GCH;
  int b = blockIdx.x / GCH;
  int d = threadIdx.x;
  __shared__ float Cms[LCH * NS];
  __shared__ unsigned short yS[16][136];
  __shared__ unsigned short tmpS[16][72];
  {
    int tid = threadIdx.x;
    size_t cb16 = ((size_t)b * LL + g * LCH) * 16;
    if (tid < 64) *(float4*)&Cms[tid * 4] = *(const float4*)&dblC[cb16 + tid * 4];
  }
  float A0 = -__expf(Alog[d * NS]);
  bool afast = true;
  #pragma unroll
  for (int n = 1; n < 16; ++n) {
    float An = -__expf(Alog[d * NS + n]);
    afast = afast && (fabsf(An - A0 * (float)(n + 1)) <= 1e-3f * (float)(n + 1) * fabsf(A0));
  }
  __syncthreads();
  size_t o = (size_t)g * NSEQ + ((size_t)b * DI + d) * NS;
  float hiR[16];
  {
    bf16x8 h0 = *(const bf16x8*)&hib[o];
    bf16x8 h1 = *(const bf16x8*)&hib[o + 8];
    #pragma unroll
    for (int n = 0; n < 8; ++n) {
      hiR[n] = b2f((unsigned short)h0[n]);
      hiR[8 + n] = b2f((unsigned short)h1[n]);
    }
  }
  size_t base = ((size_t)b * LL + g * LCH) * DI + d;
  #pragma unroll 4
  for (int l = 0; l < LCH; ++l) {
    float dtpre = b2f(dtpreb[base + (size_t)l * DI]);
    float y1v = b2f(y1b[base + (size_t)l * DI]);
    float sg = b2f(sz_b[base + (size_t)l * DI]);
    float pw[16];
    if (afast) {
      powers16(__expf(A0 * dtpre), pw);
    } else {
      #pragma unroll
      for (int n = 0; n < 16; ++n) pw[n] = __expf(-__expf(Alog[d * NS + n]) * dtpre);
    }
    float4 c0 = *(float4*)&Cms[l * 16];
    float4 c1 = *(float4*)&Cms[l * 16 + 4];
    float4 c2 = *(float4*)&Cms[l * 16 + 8];
    float4 c3 = *(float4*)&Cms[l * 16 + 12];
    float s0 = c0.x * pw[0] * hiR[0] + c0.y * pw[1] * hiR[1] + c0.z * pw[2] * hiR[2] + c0.w * pw[3] * hiR[3];
    float s1 = c1.x * pw[4] * hiR[4] + c1.y * pw[5] * hiR[5] + c1.z * pw[6] * hiR[6] + c1.w * pw[7] * hiR[7];
    float s2 = c2.x * pw[8] * hiR[8] + c2.y * pw[9] * hiR[9] + c2.z * pw[10] * hiR[10] + c2.w * pw[11] * hiR[11];
    float s3 = c3.x * pw[12] * hiR[12] + c3.y * pw[13] * hiR[13] + c3.z * pw[14] * hiR[14] + c3.w * pw[15] * hiR[15];
    float yv = y1v + ((s0 + s1) + (s2 + s3));
    yS[l][d] = f2b(yv * sg);
  }
  __syncthreads();
  // phase O: out-proj, full-K; wave lw computes output cols lw*32 .. lw*32+31
  int lane = threadIdx.x & 63;
  int lr = lane & 15, kg = lane >> 4;
  int lw = threadIdx.x >> 6;
  {
    fx4 oacc[2];
    oacc[0] = (fx4){0.f, 0.f, 0.f, 0.f};
    oacc[1] = (fx4){0.f, 0.f, 0.f, 0.f};
    #pragma unroll
    for (int ks = 0; ks < 4; ++ks) {
      int cbase = ks * 32 + kg * 8;
      bf16x8 a = *(const bf16x8*)&yS[lr][cbase];
      #pragma unroll
      for (int j = 0; j < 2; ++j) {
        int nt = lw * 2 + j;
        bf16x8 bfr = *(const bf16x8*)&ow_b[(size_t)(nt * 16 + lr) * DI + cbase];
        oacc[j] = MFMA16(a, bfr, oacc[j], 0, 0, 0);
      }
    }
    float sk = skipv[0];
    #pragma unroll
    for (int j = 0; j < 2; ++j) {
      int nt = lw * 2 + j;
      #pragma unroll
      for (int r = 0; r < 4; ++r) {
        int rowl = kg * 4 + r, col = nt * 16 + lr;
        size_t grow = (size_t)b * LL + g * LCH + rowl;
        tmpS[rowl][col] = f2b(oacc[j][r] + sk * b2f(xf_b[grow * CC + col]));
      }
    }
  }
  __syncthreads();
  // phase P: pr-proj, full-K; wave lw computes output channels lw*32 .. lw*32+31
  {
    fx4 pacc[2];
    pacc[0] = (fx4){0.f, 0.f, 0.f, 0.f};
    pacc[1] = (fx4){0.f, 0.f, 0.f, 0.f};
    #pragma unroll
    for (int ks = 0; ks < 2; ++ks) {
      int cbase = ks * 32 + kg * 8;
      bf16x8 bfrag = *(const bf16x8*)&tmpS[lr][cbase];
      #pragma unroll
      for (int j = 0; j < 2; ++j) {
        int ct = lw * 2 + j;
        bf16x8 a = *(const bf16x8*)&pw_b[(size_t)(ct * 16 + lr) * CC + cbase];
        pacc[j] = MFMA16(a, bfrag, pacc[j], 0, 0, 0);
      }
    }
    #pragma unroll
    for (int j = 0; j < 2; ++j) {
      int ct = lw * 2 + j;
      #pragma unroll
      for (int r = 0; r < 4; ++r) {
        int c = ct * 16 + kg * 4 + r;
        int lpos = g * LCH + lr;
        size_t off = ((size_t)(b * CC + c)) * LL + lpos;
        float val = pacc[j][r] + pb[c];
        if (addid) val += ident[off];
        dst[off] = val;
      }
    }
  }
}

extern "C" void kernel_launch(void* const* d_in, const int* in_sizes, int n_in,
                              void* d_out, int out_size, void* d_ws, size_t ws_size,
                              hipStream_t stream) {
  const float* x = (const float*)d_in[0];
  float* ws = (float*)d_ws;
  float* stats = ws;                                         //     1024 floats
  unsigned short* xf_b   = (unsigned short*)(ws + 1024);     //  2359296 shorts (1179648 f)
  unsigned short* xin_b  = (unsigned short*)(ws + 1180672);  //  4718592 shorts (2359296 f)
  unsigned short* sz_b   = (unsigned short*)(ws + 3539968);  //  4718592 shorts (2359296 f)
  float* dblC  = ws + 5899264;                               //   589824 f
  float* dts   = ws + 6489088;                               //   294912 f
  unsigned short* hlb    = (unsigned short*)(ws + 6784000);  //  4718592 shorts (2359296 f); dead after scan2bc -> inter
  unsigned short* hib    = (unsigned short*)(ws + 9143296);  //  4718592 shorts (2359296 f)
  float* gap   = ws + 11502592;                              //   196608 f
  float* ghl   = ws + 11699200;                               //   196608 f
  unsigned short* wb     = (unsigned short*)(ws + 11895808); //    69632 shorts (34816 f)
  unsigned short* y1b    = (unsigned short*)(ws + 11930624); //  4718592 shorts (2359296 f)
  unsigned short* dtpreb = (unsigned short*)(ws + 14289920); //  4718592 shorts (2359296 f)
  float* inter = (float*)hlb;  // hlb dead after k_scan2bc; scanCO(L0) writes it; L1 consumes
                               // it in stats/fusein BEFORE scanAX(L1) rewrites hlb.
  float* outp  = (float*)d_out;

  k_cvt<<<272, 256, 0, stream>>>((const float*)d_in[3], (const float*)d_in[6],
                                 (const float*)d_in[11], (const float*)d_in[13],
                                 (const float*)d_in[17], (const float*)d_in[20],
                                 (const float*)d_in[25], (const float*)d_in[27], wb);

  const float* cur = x;
  for (int layer = 0; layer < 2; ++layer) {
    const int p0 = 1 + 14 * layer;
    const float* ln_g   = (const float*)d_in[p0 + 0];
    const float* ln_b   = (const float*)d_in[p0 + 1];
    const float* conv_w = (const float*)d_in[p0 + 3];
    const float* conv_b = (const float*)d_in[p0 + 4];
    const float* dt_w   = (const float*)d_in[p0 + 6];
    const float* dt_b   = (const float*)d_in[p0 + 7];
    const float* A_log  = (const float*)d_in[p0 + 8];
    const float* Dp     = (const float*)d_in[p0 + 9];
    const float* skip   = (const float*)d_in[p0 + 11];
    const float* pr_b   = (const float*)d_in[p0 + 13];
    const unsigned short* inw_b = wb + (size_t)layer * 34816;
    const unsigned short* xpw_b = inw_b + 16384;
    const unsigned short* ow_b  = inw_b + 22528;
    const unsigned short* pw_b  = inw_b + 30720;
    float* dst = (layer == 0) ? inter : outp;

    k_stats  <<<BB * CC, 256, 0, stream>>>(cur, stats);
    k_fusein <<<BB * NT, 256, 0, stream>>>(cur, stats, ln_g, ln_b, inw_b, xf_b, xin_b, sz_b);
    k_scanAX <<<BB * GCH, 128, 0, stream>>>(xin_b, conv_w, conv_b, xpw_b, A_log,
                                            dt_w, dt_b, Dp, dblC, dts, hlb, y1b, dtpreb);
    k_scan2a <<<(NG * NSEQ) / 256, 256, 0, stream>>>(dts, hlb, A_log, gap, ghl);
    k_scan2bc<<<(NG * NSEQ) / 256, 256, 0, stream>>>(dts, hlb, gap, ghl, A_log, hib);
    k_scanCO <<<BB * GCH, 128, 0, stream>>>(dblC, sz_b, y1b, dtpreb, A_log, hib, ow_b,
                                            xf_b, skip, pw_b, pr_b, x, dst, layer);
    cur = inter;
  }
}